// Round 1
// baseline (6752.881 us; speedup 1.0000x reference)
//
#include <hip/hip_runtime.h>

#define NN 50000
#define NE 800000
#define FD 64
#define HD 64
#define NG 64
#define NC 10
#define BN_EPS 1e-5f

// ---------------- degree / norm precompute ----------------

__global__ void deg_count_kernel(const int* __restrict__ dst, float* __restrict__ deg) {
    int e = blockIdx.x * blockDim.x + threadIdx.x;
    if (e < NE) atomicAdd(&deg[dst[e]], 1.0f);
}

__global__ void dinv_kernel(float* __restrict__ dinv) {
    int n = blockIdx.x * blockDim.x + threadIdx.x;
    if (n < NN) dinv[n] = rsqrtf(dinv[n] + 1.0f);
}

__global__ void norm_kernel(const int* __restrict__ src, const int* __restrict__ dst,
                            const float* __restrict__ dinv, float* __restrict__ nrm) {
    int e = blockIdx.x * blockDim.x + threadIdx.x;
    if (e < NE) nrm[e] = dinv[src[e]] * dinv[dst[e]];
}

// ---------------- BN stats: sum & sumsq of prelu(h, a) over nodes, per channel (H=64) ----------------

__global__ __launch_bounds__(256) void bn_stats_kernel(const float* __restrict__ h,
                                                       const float* __restrict__ alpha_p,
                                                       float* __restrict__ stats) {
    float alpha = alpha_p[0];
    int tid = threadIdx.x;
    int c4 = (tid & 15) * 4;   // channel group
    int rg = tid >> 4;         // row group 0..15
    float sx = 0, sy = 0, sz = 0, sw = 0;
    float qx = 0, qy = 0, qz = 0, qw = 0;
    for (int n = blockIdx.x * 16 + rg; n < NN; n += gridDim.x * 16) {
        float4 v = *(const float4*)&h[(size_t)n * 64 + c4];
        float a = v.x >= 0.f ? v.x : alpha * v.x;
        float b = v.y >= 0.f ? v.y : alpha * v.y;
        float c = v.z >= 0.f ? v.z : alpha * v.z;
        float d = v.w >= 0.f ? v.w : alpha * v.w;
        sx += a; sy += b; sz += c; sw += d;
        qx += a * a; qy += b * b; qz += c * c; qw += d * d;
    }
    __shared__ float ls[256 * 8];
    float* p = &ls[tid * 8];
    p[0] = sx; p[1] = sy; p[2] = sz; p[3] = sw;
    p[4] = qx; p[5] = qy; p[6] = qz; p[7] = qw;
    __syncthreads();
    if (tid < 128) {
        int cidx = tid >> 3;   // 0..15
        int j = tid & 7;       // 0..7
        float acc = 0.f;
        for (int r = 0; r < 16; ++r) acc += ls[(r * 16 + cidx) * 8 + j];
        int ch = cidx * 4 + (j & 3);
        if (j < 4) atomicAdd(&stats[ch], acc);
        else       atomicAdd(&stats[64 + ch], acc);
    }
}

// ---------------- generic small-K GEMM: out[N,M] = f(A[N,K]) @ W[K,M] ----------------
// MODE 0: out = A@W + bias
// MODE 1: out = BN(prelu(A, alpha)) @ W      (stats: sum at [0..K), sumsq at [64..64+K))
// MODE 2: out = prelu(A, alpha) @ W

template <int K, int M, int MODE>
__global__ __launch_bounds__(256) void gemm_kernel(const float* __restrict__ A,
                                                   const float* __restrict__ W,
                                                   float* __restrict__ out,
                                                   const float* __restrict__ bias,
                                                   const float* __restrict__ alpha_p,
                                                   const float* __restrict__ stats,
                                                   const float* __restrict__ gamma,
                                                   const float* __restrict__ beta) {
    constexpr int TPR = M / 4;        // threads per row
    constexpr int RPB = 256 / TPR;    // rows per block
    __shared__ float Wlds[K * M];
    __shared__ float scaleS[K];
    __shared__ float shiftS[K];
    int tid = threadIdx.x;
    for (int i = tid * 4; i < K * M; i += 1024) {
        *(float4*)&Wlds[i] = *(const float4*)&W[i];
    }
    float alpha = 0.f;
    if constexpr (MODE == 1 || MODE == 2) alpha = alpha_p[0];
    if constexpr (MODE == 1) {
        for (int k = tid; k < K; k += 256) {
            float mean = stats[k] * (1.0f / NN);
            float var  = stats[64 + k] * (1.0f / NN) - mean * mean;
            float sc = gamma[k] * rsqrtf(var + BN_EPS);
            scaleS[k] = sc;
            shiftS[k] = beta[k] - mean * sc;
        }
    }
    __syncthreads();
    int r = blockIdx.x * RPB + tid / TPR;
    int c = (tid % TPR) * 4;
    if (r >= NN) return;
    const float* Arow = A + (size_t)r * K;
    float ax = 0, ay = 0, az = 0, aw = 0;
#pragma unroll 8
    for (int k = 0; k < K; ++k) {
        float a = Arow[k];
        if constexpr (MODE == 1) {
            a = a >= 0.f ? a : alpha * a;
            a = a * scaleS[k] + shiftS[k];
        }
        if constexpr (MODE == 2) {
            a = a >= 0.f ? a : alpha * a;
        }
        float4 w = *(const float4*)&Wlds[k * M + c];
        ax += a * w.x; ay += a * w.y; az += a * w.z; aw += a * w.w;
    }
    if constexpr (MODE == 0) {
        ax += bias[c]; ay += bias[c + 1]; az += bias[c + 2]; aw += bias[c + 3];
    }
    float4 o = {ax, ay, az, aw};
    *(float4*)&out[(size_t)r * M + c] = o;
}

// ---------------- self-loop + bias init:  agg[n][c] = hh[n][c]*dinv[n]^2 + bias[c] ----------------

template <int M>
__global__ void self_bias_kernel(const float* __restrict__ hh, const float* __restrict__ dinv,
                                 const float* __restrict__ bias, float* __restrict__ agg) {
    constexpr int C4 = M / 4;
    int idx = blockIdx.x * blockDim.x + threadIdx.x;
    if (idx >= NN * C4) return;
    int n = idx / C4;
    int c = (idx % C4) * 4;
    float d = dinv[n];
    float d2 = d * d;
    float4 v = *(const float4*)&hh[(size_t)n * M + c];
    float4 b = *(const float4*)&bias[c];
    float4 o = {v.x * d2 + b.x, v.y * d2 + b.y, v.z * d2 + b.z, v.w * d2 + b.w};
    *(float4*)&agg[(size_t)n * M + c] = o;
}

// ---------------- edge scatter:  agg[dst] += hh[src] * norm[e] ----------------

template <int M>
__global__ void edge_agg_kernel(const int* __restrict__ src, const int* __restrict__ dst,
                                const float* __restrict__ nrm, const float* __restrict__ hh,
                                float* __restrict__ agg) {
    constexpr int C4 = M / 4;
    int idx = blockIdx.x * blockDim.x + threadIdx.x;
    if (idx >= NE * C4) return;
    int e = idx / C4;
    int c = (idx % C4) * 4;
    int s = src[e];
    int d = dst[e];
    float nm = nrm[e];
    float4 v = *(const float4*)&hh[(size_t)s * M + c];
    float* ap = &agg[(size_t)d * M + c];
    atomicAdd(ap + 0, v.x * nm);
    atomicAdd(ap + 1, v.y * nm);
    atomicAdd(ap + 2, v.z * nm);
    atomicAdd(ap + 3, v.w * nm);
}

// ---------------- pool: per-graph sums + counts ----------------

__global__ void pool_kernel(const float* __restrict__ h, const int* __restrict__ batch,
                            float* __restrict__ psum, float* __restrict__ pcnt) {
    int idx = blockIdx.x * blockDim.x + threadIdx.x;
    if (idx >= NN * 16) return;
    int n = idx >> 4;
    int c = (idx & 15) * 4;
    int b = batch[n];
    float4 v = *(const float4*)&h[(size_t)n * 64 + c];
    atomicAdd(&psum[b * 64 + c + 0], v.x);
    atomicAdd(&psum[b * 64 + c + 1], v.y);
    atomicAdd(&psum[b * 64 + c + 2], v.z);
    atomicAdd(&psum[b * 64 + c + 3], v.w);
    if ((idx & 15) == 0) atomicAdd(&pcnt[b], 1.0f);
}

// ---------------- head: pooled -> BN(G) -> fc1 -> prelu -> fc2 ----------------

__global__ __launch_bounds__(256) void final_kernel(const float* __restrict__ psum,
                                                    const float* __restrict__ pcnt,
                                                    const float* __restrict__ gamma,
                                                    const float* __restrict__ beta,
                                                    const float* __restrict__ fc1w,
                                                    const float* __restrict__ fc1b,
                                                    const float* __restrict__ prelu_p,
                                                    const float* __restrict__ fc2w,
                                                    const float* __restrict__ fc2b,
                                                    float* __restrict__ o1ws,
                                                    float* __restrict__ out) {
    __shared__ float pooled[64 * 64];
    __shared__ float scaleS[64];
    __shared__ float shiftS[64];
    int tid = threadIdx.x;
    for (int i = tid; i < 64 * 64; i += 256) {
        int g = i >> 6;
        float cnt = fmaxf(pcnt[g], 1.0f);
        pooled[i] = psum[i] / cnt;
    }
    __syncthreads();
    if (tid < 64) {
        float s = 0.f, q = 0.f;
        for (int g = 0; g < 64; ++g) {
            float v = pooled[g * 64 + tid];
            s += v; q += v * v;
        }
        float mean = s * (1.0f / 64.0f);
        float var = q * (1.0f / 64.0f) - mean * mean;
        float sc = gamma[tid] * rsqrtf(var + BN_EPS);
        scaleS[tid] = sc;
        shiftS[tid] = beta[tid] - mean * sc;
    }
    __syncthreads();
    for (int i = tid; i < 64 * 64; i += 256) {
        int c = i & 63;
        pooled[i] = pooled[i] * scaleS[c] + shiftS[c];
    }
    __syncthreads();
    float alpha = prelu_p[0];
    for (int i = tid; i < 64 * 256; i += 256) {
        int g = i >> 8;
        int j = i & 255;
        float acc = fc1b[j];
        for (int k = 0; k < 64; ++k) acc += pooled[g * 64 + k] * fc1w[k * 256 + j];
        o1ws[i] = acc >= 0.f ? acc : alpha * acc;
    }
    __syncthreads();
    for (int i = tid; i < NG * NC; i += 256) {
        int g = i / NC;
        int c = i % NC;
        float acc = fc2b[c];
        for (int j = 0; j < 256; ++j) acc += o1ws[g * 256 + j] * fc2w[j * NC + c];
        out[i] = acc;
    }
}

// ---------------- launch ----------------

extern "C" void kernel_launch(void* const* d_in, const int* in_sizes, int n_in,
                              void* d_out, int out_size, void* d_ws, size_t ws_size,
                              hipStream_t stream) {
    const float* x       = (const float*)d_in[0];
    const int*   ei      = (const int*)d_in[1];
    const int*   batch   = (const int*)d_in[2];
    const float* pre_w   = (const float*)d_in[3];
    const float* pre_b   = (const float*)d_in[4];
    const float* bp1     = (const float*)d_in[5];   // [3]
    const float* bng     = (const float*)d_in[6];   // [3,64]
    const float* bnb     = (const float*)d_in[7];   // [3,64]
    const float* bw1     = (const float*)d_in[8];   // [3,64,128]
    const float* bb1     = (const float*)d_in[9];   // [3,128]
    const float* bp2     = (const float*)d_in[10];  // [3]
    const float* bw2     = (const float*)d_in[11];  // [3,128,64]
    const float* bb2     = (const float*)d_in[12];  // [3,64]
    const float* pgamma  = (const float*)d_in[13];
    const float* pbeta   = (const float*)d_in[14];
    const float* fc1w    = (const float*)d_in[15];
    const float* fc1b    = (const float*)d_in[16];
    const float* pprelu  = (const float*)d_in[17];
    const float* fc2w    = (const float*)d_in[18];
    const float* fc2b    = (const float*)d_in[19];

    const int* src = ei;
    const int* dst = ei + NE;

    float* ws   = (float*)d_ws;
    float* hA   = ws;                              // [NN,128]
    float* hB   = hA + (size_t)NN * 128;           // [NN,128]
    float* dinv = hB + (size_t)NN * 128;           // [NN]
    float* nrm  = dinv + NN;                       // [NE]
    float* stats = nrm + NE;                       // [3*128]
    float* psum = stats + 3 * 128;                 // [64*64]
    float* pcnt = psum + 64 * 64;                  // [64]
    float* o1ws = pcnt + 64;                       // [64*256]

    // zero: dinv .. end of o1ws
    size_t zero_floats = (size_t)NN + NE + 3 * 128 + 64 * 64 + 64 + 64 * 256;
    hipMemsetAsync(dinv, 0, zero_floats * sizeof(float), stream);

    deg_count_kernel<<<(NE + 255) / 256, 256, 0, stream>>>(dst, dinv);
    dinv_kernel<<<(NN + 255) / 256, 256, 0, stream>>>(dinv);
    norm_kernel<<<(NE + 255) / 256, 256, 0, stream>>>(src, dst, dinv, nrm);

    // pre-linear: hA = x @ pre_w + pre_b   [NN,64]
    gemm_kernel<64, 64, 0><<<(NN + 15) / 16, 256, 0, stream>>>(
        x, pre_w, hA, pre_b, nullptr, nullptr, nullptr, nullptr);

    for (int i = 0; i < 3; ++i) {
        const float* a1 = bp1 + i;
        const float* a2 = bp2 + i;
        const float* g  = bng + i * 64;
        const float* bt = bnb + i * 64;
        const float* w1 = bw1 + (size_t)i * 64 * 128;
        const float* b1 = bb1 + i * 128;
        const float* w2 = bw2 + (size_t)i * 128 * 64;
        const float* b2 = bb2 + i * 64;
        float* st = stats + i * 128;

        bn_stats_kernel<<<256, 256, 0, stream>>>(hA, a1, st);
        // hB[N,128] = BN(prelu(hA)) @ w1
        gemm_kernel<64, 128, 1><<<(NN + 7) / 8, 256, 0, stream>>>(
            hA, w1, hB, nullptr, a1, st, g, bt);
        // hA = self + bias, then scatter edges
        self_bias_kernel<128><<<(NN * 32 + 255) / 256, 256, 0, stream>>>(hB, dinv, b1, hA);
        edge_agg_kernel<128><<<(NE * 32 + 255) / 256, 256, 0, stream>>>(src, dst, nrm, hB, hA);
        // hB[N,64] = prelu(hA) @ w2
        gemm_kernel<128, 64, 2><<<(NN + 15) / 16, 256, 0, stream>>>(
            hA, w2, hB, nullptr, a2, nullptr, nullptr, nullptr);
        self_bias_kernel<64><<<(NN * 16 + 255) / 256, 256, 0, stream>>>(hB, dinv, b2, hA);
        edge_agg_kernel<64><<<(NE * 16 + 255) / 256, 256, 0, stream>>>(src, dst, nrm, hB, hA);
    }

    pool_kernel<<<(NN * 16 + 255) / 256, 256, 0, stream>>>(hA, batch, psum, pcnt);
    final_kernel<<<1, 256, 0, stream>>>(psum, pcnt, pgamma, pbeta, fc1w, fc1b,
                                        pprelu, fc2w, fc2b, o1ws, (float*)d_out);
}

// Round 2
// 1192.157 us; speedup vs baseline: 5.6644x; 5.6644x over previous
//
#include <hip/hip_runtime.h>

#define NN 50000
#define NE 800000
#define FD 64
#define HD 64
#define NG 64
#define NC 10
#define BN_EPS 1e-5f

// ---------------- CSR build ----------------

__global__ void deg_count_kernel(const int* __restrict__ dst, int* __restrict__ deg) {
    int e = blockIdx.x * blockDim.x + threadIdx.x;
    if (e < NE) atomicAdd(&deg[dst[e]], 1);
}

// single-block scan: deg -> row_off (exclusive), cursor copy, dinv = rsqrt(deg+1)
__global__ __launch_bounds__(1024) void scan_kernel(const int* __restrict__ deg,
                                                    int* __restrict__ row_off,
                                                    int* __restrict__ cursor,
                                                    float* __restrict__ dinv) {
    __shared__ int part[1024];
    int tid = threadIdx.x;
    const int CH = (NN + 1023) / 1024;
    int base = tid * CH;
    int s = 0;
    for (int i = 0; i < CH; ++i) {
        int n = base + i;
        if (n < NN) s += deg[n];
    }
    part[tid] = s;
    __syncthreads();
    for (int off = 1; off < 1024; off <<= 1) {
        int v = part[tid];
        int add = (tid >= off) ? part[tid - off] : 0;
        __syncthreads();
        part[tid] = v + add;
        __syncthreads();
    }
    int run = (tid == 0) ? 0 : part[tid - 1];
    for (int i = 0; i < CH; ++i) {
        int n = base + i;
        if (n < NN) {
            int d = deg[n];
            row_off[n] = run;
            cursor[n] = run;
            dinv[n] = rsqrtf((float)d + 1.0f);
            run += d;
        }
    }
    if (tid == 1023) row_off[NN] = part[1023];
}

__global__ void scatter_csr_kernel(const int* __restrict__ src, const int* __restrict__ dst,
                                   const float* __restrict__ dinv, int* __restrict__ cursor,
                                   int* __restrict__ csr_src, float* __restrict__ csr_nrm) {
    int e = blockIdx.x * blockDim.x + threadIdx.x;
    if (e >= NE) return;
    int s = src[e];
    int d = dst[e];
    int pos = atomicAdd(&cursor[d], 1);
    csr_src[pos] = s;
    csr_nrm[pos] = dinv[s] * dinv[d];
}

// ---------------- BN stats: sum & sumsq of prelu(h, a) over nodes, per channel (H=64) ----------------

__global__ __launch_bounds__(256) void bn_stats_kernel(const float* __restrict__ h,
                                                       const float* __restrict__ alpha_p,
                                                       float* __restrict__ stats) {
    float alpha = alpha_p[0];
    int tid = threadIdx.x;
    int c4 = (tid & 15) * 4;
    int rg = tid >> 4;
    float sx = 0, sy = 0, sz = 0, sw = 0;
    float qx = 0, qy = 0, qz = 0, qw = 0;
    for (int n = blockIdx.x * 16 + rg; n < NN; n += gridDim.x * 16) {
        float4 v = *(const float4*)&h[(size_t)n * 64 + c4];
        float a = v.x >= 0.f ? v.x : alpha * v.x;
        float b = v.y >= 0.f ? v.y : alpha * v.y;
        float c = v.z >= 0.f ? v.z : alpha * v.z;
        float d = v.w >= 0.f ? v.w : alpha * v.w;
        sx += a; sy += b; sz += c; sw += d;
        qx += a * a; qy += b * b; qz += c * c; qw += d * d;
    }
    __shared__ float ls[256 * 8];
    float* p = &ls[tid * 8];
    p[0] = sx; p[1] = sy; p[2] = sz; p[3] = sw;
    p[4] = qx; p[5] = qy; p[6] = qz; p[7] = qw;
    __syncthreads();
    if (tid < 128) {
        int cidx = tid >> 3;
        int j = tid & 7;
        float acc = 0.f;
        for (int r = 0; r < 16; ++r) acc += ls[(r * 16 + cidx) * 8 + j];
        int ch = cidx * 4 + (j & 3);
        if (j < 4) atomicAdd(&stats[ch], acc);
        else       atomicAdd(&stats[64 + ch], acc);
    }
}

// ---------------- generic small-K GEMM: out[N,M] = f(A[N,K]) @ W[K,M] ----------------
// MODE 0: out = A@W + bias
// MODE 1: out = BN(prelu(A, alpha)) @ W
// MODE 2: out = prelu(A, alpha) @ W

template <int K, int M, int MODE>
__global__ __launch_bounds__(256) void gemm_kernel(const float* __restrict__ A,
                                                   const float* __restrict__ W,
                                                   float* __restrict__ out,
                                                   const float* __restrict__ bias,
                                                   const float* __restrict__ alpha_p,
                                                   const float* __restrict__ stats,
                                                   const float* __restrict__ gamma,
                                                   const float* __restrict__ beta) {
    constexpr int TPR = M / 4;
    constexpr int RPB = 256 / TPR;
    __shared__ float Wlds[K * M];
    __shared__ float scaleS[K];
    __shared__ float shiftS[K];
    int tid = threadIdx.x;
    for (int i = tid * 4; i < K * M; i += 1024) {
        *(float4*)&Wlds[i] = *(const float4*)&W[i];
    }
    float alpha = 0.f;
    if constexpr (MODE == 1 || MODE == 2) alpha = alpha_p[0];
    if constexpr (MODE == 1) {
        for (int k = tid; k < K; k += 256) {
            float mean = stats[k] * (1.0f / NN);
            float var  = stats[64 + k] * (1.0f / NN) - mean * mean;
            float sc = gamma[k] * rsqrtf(var + BN_EPS);
            scaleS[k] = sc;
            shiftS[k] = beta[k] - mean * sc;
        }
    }
    __syncthreads();
    int r = blockIdx.x * RPB + tid / TPR;
    int c = (tid % TPR) * 4;
    if (r >= NN) return;
    const float* Arow = A + (size_t)r * K;
    float ax = 0, ay = 0, az = 0, aw = 0;
#pragma unroll 8
    for (int k = 0; k < K; ++k) {
        float a = Arow[k];
        if constexpr (MODE == 1) {
            a = a >= 0.f ? a : alpha * a;
            a = a * scaleS[k] + shiftS[k];
        }
        if constexpr (MODE == 2) {
            a = a >= 0.f ? a : alpha * a;
        }
        float4 w = *(const float4*)&Wlds[k * M + c];
        ax += a * w.x; ay += a * w.y; az += a * w.z; aw += a * w.w;
    }
    if constexpr (MODE == 0) {
        ax += bias[c]; ay += bias[c + 1]; az += bias[c + 2]; aw += bias[c + 3];
    }
    float4 o = {ax, ay, az, aw};
    *(float4*)&out[(size_t)r * M + c] = o;
}

// ---------------- CSR gather aggregation (fused self-loop + bias) ----------------
// agg[n][c] = hh[n][c]*dinv[n]^2 + bias[c] + sum_{i in bucket(n)} hh[csr_src[i]][c] * csr_nrm[i]

template <int M>
__global__ __launch_bounds__(256) void gather_agg_kernel(const int* __restrict__ row_off,
                                                         const int* __restrict__ csr_src,
                                                         const float* __restrict__ csr_nrm,
                                                         const float* __restrict__ dinv,
                                                         const float* __restrict__ bias,
                                                         const float* __restrict__ hh,
                                                         float* __restrict__ agg) {
    constexpr int TPR = M / 4;
    constexpr int RPB = 256 / TPR;
    int tid = threadIdx.x;
    int r = blockIdx.x * RPB + tid / TPR;
    int c = (tid % TPR) * 4;
    if (r >= NN) return;
    float dv = dinv[r];
    float d2 = dv * dv;
    float4 h0 = *(const float4*)&hh[(size_t)r * M + c];
    float4 b = *(const float4*)&bias[c];
    float ax = h0.x * d2 + b.x;
    float ay = h0.y * d2 + b.y;
    float az = h0.z * d2 + b.z;
    float aw = h0.w * d2 + b.w;
    int beg = row_off[r];
    int end = row_off[r + 1];
    int i = beg;
    for (; i + 1 < end; i += 2) {
        int s0 = csr_src[i];
        int s1 = csr_src[i + 1];
        float w0 = csr_nrm[i];
        float w1 = csr_nrm[i + 1];
        float4 v0 = *(const float4*)&hh[(size_t)s0 * M + c];
        float4 v1 = *(const float4*)&hh[(size_t)s1 * M + c];
        ax += v0.x * w0 + v1.x * w1;
        ay += v0.y * w0 + v1.y * w1;
        az += v0.z * w0 + v1.z * w1;
        aw += v0.w * w0 + v1.w * w1;
    }
    if (i < end) {
        int s0 = csr_src[i];
        float w0 = csr_nrm[i];
        float4 v0 = *(const float4*)&hh[(size_t)s0 * M + c];
        ax += v0.x * w0; ay += v0.y * w0; az += v0.z * w0; aw += v0.w * w0;
    }
    float4 o = {ax, ay, az, aw};
    *(float4*)&agg[(size_t)r * M + c] = o;
}

// ---------------- pool: per-graph sums + counts ----------------

__global__ void pool_kernel(const float* __restrict__ h, const int* __restrict__ batch,
                            float* __restrict__ psum, float* __restrict__ pcnt) {
    int idx = blockIdx.x * blockDim.x + threadIdx.x;
    if (idx >= NN * 16) return;
    int n = idx >> 4;
    int c = (idx & 15) * 4;
    int b = batch[n];
    float4 v = *(const float4*)&h[(size_t)n * 64 + c];
    atomicAdd(&psum[b * 64 + c + 0], v.x);
    atomicAdd(&psum[b * 64 + c + 1], v.y);
    atomicAdd(&psum[b * 64 + c + 2], v.z);
    atomicAdd(&psum[b * 64 + c + 3], v.w);
    if ((idx & 15) == 0) atomicAdd(&pcnt[b], 1.0f);
}

// ---------------- head ----------------

__global__ __launch_bounds__(256) void final_kernel(const float* __restrict__ psum,
                                                    const float* __restrict__ pcnt,
                                                    const float* __restrict__ gamma,
                                                    const float* __restrict__ beta,
                                                    const float* __restrict__ fc1w,
                                                    const float* __restrict__ fc1b,
                                                    const float* __restrict__ prelu_p,
                                                    const float* __restrict__ fc2w,
                                                    const float* __restrict__ fc2b,
                                                    float* __restrict__ o1ws,
                                                    float* __restrict__ out) {
    __shared__ float pooled[64 * 64];
    __shared__ float scaleS[64];
    __shared__ float shiftS[64];
    int tid = threadIdx.x;
    for (int i = tid; i < 64 * 64; i += 256) {
        int g = i >> 6;
        float cnt = fmaxf(pcnt[g], 1.0f);
        pooled[i] = psum[i] / cnt;
    }
    __syncthreads();
    if (tid < 64) {
        float s = 0.f, q = 0.f;
        for (int g = 0; g < 64; ++g) {
            float v = pooled[g * 64 + tid];
            s += v; q += v * v;
        }
        float mean = s * (1.0f / 64.0f);
        float var = q * (1.0f / 64.0f) - mean * mean;
        float sc = gamma[tid] * rsqrtf(var + BN_EPS);
        scaleS[tid] = sc;
        shiftS[tid] = beta[tid] - mean * sc;
    }
    __syncthreads();
    for (int i = tid; i < 64 * 64; i += 256) {
        int c = i & 63;
        pooled[i] = pooled[i] * scaleS[c] + shiftS[c];
    }
    __syncthreads();
    float alpha = prelu_p[0];
    for (int i = tid; i < 64 * 256; i += 256) {
        int g = i >> 8;
        int j = i & 255;
        float acc = fc1b[j];
        for (int k = 0; k < 64; ++k) acc += pooled[g * 64 + k] * fc1w[k * 256 + j];
        o1ws[i] = acc >= 0.f ? acc : alpha * acc;
    }
    __syncthreads();
    for (int i = tid; i < NG * NC; i += 256) {
        int g = i / NC;
        int c = i % NC;
        float acc = fc2b[c];
        for (int j = 0; j < 256; ++j) acc += o1ws[g * 256 + j] * fc2w[j * NC + c];
        out[i] = acc;
    }
}

// ---------------- launch ----------------

extern "C" void kernel_launch(void* const* d_in, const int* in_sizes, int n_in,
                              void* d_out, int out_size, void* d_ws, size_t ws_size,
                              hipStream_t stream) {
    const float* x       = (const float*)d_in[0];
    const int*   ei      = (const int*)d_in[1];
    const int*   batch   = (const int*)d_in[2];
    const float* pre_w   = (const float*)d_in[3];
    const float* pre_b   = (const float*)d_in[4];
    const float* bp1     = (const float*)d_in[5];
    const float* bng     = (const float*)d_in[6];
    const float* bnb     = (const float*)d_in[7];
    const float* bw1     = (const float*)d_in[8];
    const float* bb1     = (const float*)d_in[9];
    const float* bp2     = (const float*)d_in[10];
    const float* bw2     = (const float*)d_in[11];
    const float* bb2     = (const float*)d_in[12];
    const float* pgamma  = (const float*)d_in[13];
    const float* pbeta   = (const float*)d_in[14];
    const float* fc1w    = (const float*)d_in[15];
    const float* fc1b    = (const float*)d_in[16];
    const float* pprelu  = (const float*)d_in[17];
    const float* fc2w    = (const float*)d_in[18];
    const float* fc2b    = (const float*)d_in[19];

    const int* src = ei;
    const int* dst = ei + NE;

    float* ws      = (float*)d_ws;
    float* hA      = ws;                               // [NN,128]
    float* hB      = hA + (size_t)NN * 128;            // [NN,128]
    float* dinv    = hB + (size_t)NN * 128;            // [NN]
    float* csr_nrm = dinv + NN;                        // [NE]
    int*   row_off = (int*)(csr_nrm + NE);             // [NN+1]
    int*   cursor  = row_off + NN + 1;                 // [NN]
    int*   csr_src = cursor + NN;                      // [NE]
    int*   deg     = csr_src + NE;                     // [NN]   (zeroed)
    float* stats   = (float*)(deg + NN);               // [3*128] (zeroed)
    float* psum    = stats + 3 * 128;                  // [64*64] (zeroed)
    float* pcnt    = psum + 64 * 64;                   // [64]    (zeroed)
    float* o1ws    = pcnt + 64;                        // [64*256]

    size_t zero_bytes = ((size_t)NN + 3 * 128 + 64 * 64 + 64) * 4;
    hipMemsetAsync(deg, 0, zero_bytes, stream);

    deg_count_kernel<<<(NE + 255) / 256, 256, 0, stream>>>(dst, deg);
    scan_kernel<<<1, 1024, 0, stream>>>(deg, row_off, cursor, dinv);
    scatter_csr_kernel<<<(NE + 255) / 256, 256, 0, stream>>>(src, dst, dinv, cursor,
                                                             csr_src, csr_nrm);

    // pre-linear: hA = x @ pre_w + pre_b   [NN,64]
    gemm_kernel<64, 64, 0><<<(NN + 15) / 16, 256, 0, stream>>>(
        x, pre_w, hA, pre_b, nullptr, nullptr, nullptr, nullptr);

    for (int i = 0; i < 3; ++i) {
        const float* a1 = bp1 + i;
        const float* a2 = bp2 + i;
        const float* g  = bng + i * 64;
        const float* bt = bnb + i * 64;
        const float* w1 = bw1 + (size_t)i * 64 * 128;
        const float* b1 = bb1 + i * 128;
        const float* w2 = bw2 + (size_t)i * 128 * 64;
        const float* b2 = bb2 + i * 64;
        float* st = stats + i * 128;

        bn_stats_kernel<<<256, 256, 0, stream>>>(hA, a1, st);
        // hB[N,128] = BN(prelu(hA)) @ w1
        gemm_kernel<64, 128, 1><<<(NN + 7) / 8, 256, 0, stream>>>(
            hA, w1, hB, nullptr, a1, st, g, bt);
        // hA = self + bias + CSR gather from hB
        gather_agg_kernel<128><<<(NN + 7) / 8, 256, 0, stream>>>(
            row_off, csr_src, csr_nrm, dinv, b1, hB, hA);
        // hB[N,64] = prelu(hA) @ w2
        gemm_kernel<128, 64, 2><<<(NN + 15) / 16, 256, 0, stream>>>(
            hA, w2, hB, nullptr, a2, nullptr, nullptr, nullptr);
        gather_agg_kernel<64><<<(NN + 15) / 16, 256, 0, stream>>>(
            row_off, csr_src, csr_nrm, dinv, b2, hB, hA);
    }

    pool_kernel<<<(NN * 16 + 255) / 256, 256, 0, stream>>>(hA, batch, psum, pcnt);
    final_kernel<<<1, 256, 0, stream>>>(psum, pcnt, pgamma, pbeta, fc1w, fc1b,
                                        pprelu, fc2w, fc2b, o1ws, (float*)d_out);
}

// Round 3
// 820.520 us; speedup vs baseline: 8.2300x; 1.4529x over previous
//
#include <hip/hip_runtime.h>

#define NN 50000
#define NE 800000
#define FD 64
#define HD 64
#define NG 64
#define NC 10
#define BN_EPS 1e-5f

// ---------------- CSR build ----------------

__global__ void deg_count_kernel(const int* __restrict__ dst, int* __restrict__ deg) {
    int e = blockIdx.x * blockDim.x + threadIdx.x;
    if (e < NE) atomicAdd(&deg[dst[e]], 1);
}

// single-block scan: deg -> row_off (exclusive), cursor copy, dinv = rsqrt(deg+1)
__global__ __launch_bounds__(1024) void scan_kernel(const int* __restrict__ deg,
                                                    int* __restrict__ row_off,
                                                    int* __restrict__ cursor,
                                                    float* __restrict__ dinv) {
    __shared__ int part[1024];
    int tid = threadIdx.x;
    const int CH = (NN + 1023) / 1024;
    int base = tid * CH;
    int s = 0;
    for (int i = 0; i < CH; ++i) {
        int n = base + i;
        if (n < NN) s += deg[n];
    }
    part[tid] = s;
    __syncthreads();
    for (int off = 1; off < 1024; off <<= 1) {
        int v = part[tid];
        int add = (tid >= off) ? part[tid - off] : 0;
        __syncthreads();
        part[tid] = v + add;
        __syncthreads();
    }
    int run = (tid == 0) ? 0 : part[tid - 1];
    for (int i = 0; i < CH; ++i) {
        int n = base + i;
        if (n < NN) {
            int d = deg[n];
            row_off[n] = run;
            cursor[n] = run;
            dinv[n] = rsqrtf((float)d + 1.0f);
            run += d;
        }
    }
    if (tid == 1023) row_off[NN] = part[1023];
}

__global__ void scatter_csr_kernel(const int* __restrict__ src, const int* __restrict__ dst,
                                   const float* __restrict__ dinv, int* __restrict__ cursor,
                                   int* __restrict__ csr_src, float* __restrict__ csr_nrm) {
    int e = blockIdx.x * blockDim.x + threadIdx.x;
    if (e >= NE) return;
    int s = src[e];
    int d = dst[e];
    int pos = atomicAdd(&cursor[d], 1);
    csr_src[pos] = s;
    csr_nrm[pos] = dinv[s] * dinv[d];
}

// ---------------- BN stats ----------------

__global__ __launch_bounds__(256) void bn_stats_kernel(const float* __restrict__ h,
                                                       const float* __restrict__ alpha_p,
                                                       float* __restrict__ stats) {
    float alpha = alpha_p[0];
    int tid = threadIdx.x;
    int c4 = (tid & 15) * 4;
    int rg = tid >> 4;
    float sx = 0, sy = 0, sz = 0, sw = 0;
    float qx = 0, qy = 0, qz = 0, qw = 0;
    for (int n = blockIdx.x * 16 + rg; n < NN; n += gridDim.x * 16) {
        float4 v = *(const float4*)&h[(size_t)n * 64 + c4];
        float a = v.x >= 0.f ? v.x : alpha * v.x;
        float b = v.y >= 0.f ? v.y : alpha * v.y;
        float c = v.z >= 0.f ? v.z : alpha * v.z;
        float d = v.w >= 0.f ? v.w : alpha * v.w;
        sx += a; sy += b; sz += c; sw += d;
        qx += a * a; qy += b * b; qz += c * c; qw += d * d;
    }
    __shared__ float ls[256 * 8];
    float* p = &ls[tid * 8];
    p[0] = sx; p[1] = sy; p[2] = sz; p[3] = sw;
    p[4] = qx; p[5] = qy; p[6] = qz; p[7] = qw;
    __syncthreads();
    if (tid < 128) {
        int cidx = tid >> 3;
        int j = tid & 7;
        float acc = 0.f;
        for (int r = 0; r < 16; ++r) acc += ls[(r * 16 + cidx) * 8 + j];
        int ch = cidx * 4 + (j & 3);
        if (j < 4) atomicAdd(&stats[ch], acc);
        else       atomicAdd(&stats[64 + ch], acc);
    }
}

// ---------------- generic small-K GEMM ----------------
// MODE 0: out = A@W + bias ; MODE 1: BN(prelu(A)) @ W ; MODE 2: prelu(A) @ W

template <int K, int M, int MODE>
__global__ __launch_bounds__(256) void gemm_kernel(const float* __restrict__ A,
                                                   const float* __restrict__ W,
                                                   float* __restrict__ out,
                                                   const float* __restrict__ bias,
                                                   const float* __restrict__ alpha_p,
                                                   const float* __restrict__ stats,
                                                   const float* __restrict__ gamma,
                                                   const float* __restrict__ beta) {
    constexpr int TPR = M / 4;
    constexpr int RPB = 256 / TPR;
    __shared__ float Wlds[K * M];
    __shared__ float scaleS[K];
    __shared__ float shiftS[K];
    int tid = threadIdx.x;
    for (int i = tid * 4; i < K * M; i += 1024) {
        *(float4*)&Wlds[i] = *(const float4*)&W[i];
    }
    float alpha = 0.f;
    if constexpr (MODE == 1 || MODE == 2) alpha = alpha_p[0];
    if constexpr (MODE == 1) {
        for (int k = tid; k < K; k += 256) {
            float mean = stats[k] * (1.0f / NN);
            float var  = stats[64 + k] * (1.0f / NN) - mean * mean;
            float sc = gamma[k] * rsqrtf(var + BN_EPS);
            scaleS[k] = sc;
            shiftS[k] = beta[k] - mean * sc;
        }
    }
    __syncthreads();
    int r = blockIdx.x * RPB + tid / TPR;
    int c = (tid % TPR) * 4;
    if (r >= NN) return;
    const float* Arow = A + (size_t)r * K;
    float ax = 0, ay = 0, az = 0, aw = 0;
#pragma unroll 8
    for (int k = 0; k < K; ++k) {
        float a = Arow[k];
        if constexpr (MODE == 1) {
            a = a >= 0.f ? a : alpha * a;
            a = a * scaleS[k] + shiftS[k];
        }
        if constexpr (MODE == 2) {
            a = a >= 0.f ? a : alpha * a;
        }
        float4 w = *(const float4*)&Wlds[k * M + c];
        ax += a * w.x; ay += a * w.y; az += a * w.z; aw += a * w.w;
    }
    if constexpr (MODE == 0) {
        ax += bias[c]; ay += bias[c + 1]; az += bias[c + 2]; aw += bias[c + 3];
    }
    float4 o = {ax, ay, az, aw};
    *(float4*)&out[(size_t)r * M + c] = o;
}

// ---------------- CSR gather aggregation (fused self-loop + bias) ----------------

template <int M>
__global__ __launch_bounds__(256) void gather_agg_kernel(const int* __restrict__ row_off,
                                                         const int* __restrict__ csr_src,
                                                         const float* __restrict__ csr_nrm,
                                                         const float* __restrict__ dinv,
                                                         const float* __restrict__ bias,
                                                         const float* __restrict__ hh,
                                                         float* __restrict__ agg) {
    constexpr int TPR = M / 4;
    constexpr int RPB = 256 / TPR;
    int tid = threadIdx.x;
    int r = blockIdx.x * RPB + tid / TPR;
    int c = (tid % TPR) * 4;
    if (r >= NN) return;
    float dv = dinv[r];
    float d2 = dv * dv;
    float4 h0 = *(const float4*)&hh[(size_t)r * M + c];
    float4 b = *(const float4*)&bias[c];
    float ax = h0.x * d2 + b.x;
    float ay = h0.y * d2 + b.y;
    float az = h0.z * d2 + b.z;
    float aw = h0.w * d2 + b.w;
    int beg = row_off[r];
    int end = row_off[r + 1];
    int i = beg;
    for (; i + 1 < end; i += 2) {
        int s0 = csr_src[i];
        int s1 = csr_src[i + 1];
        float w0 = csr_nrm[i];
        float w1 = csr_nrm[i + 1];
        float4 v0 = *(const float4*)&hh[(size_t)s0 * M + c];
        float4 v1 = *(const float4*)&hh[(size_t)s1 * M + c];
        ax += v0.x * w0 + v1.x * w1;
        ay += v0.y * w0 + v1.y * w1;
        az += v0.z * w0 + v1.z * w1;
        aw += v0.w * w0 + v1.w * w1;
    }
    if (i < end) {
        int s0 = csr_src[i];
        float w0 = csr_nrm[i];
        float4 v0 = *(const float4*)&hh[(size_t)s0 * M + c];
        ax += v0.x * w0; ay += v0.y * w0; az += v0.z * w0; aw += v0.w * w0;
    }
    float4 o = {ax, ay, az, aw};
    *(float4*)&agg[(size_t)r * M + c] = o;
}

// ---------------- pool: one block per graph, segmented reduction (batch is sorted) ----------------

__global__ __launch_bounds__(256) void pool_seg_kernel(const float* __restrict__ h,
                                                       const int* __restrict__ batch,
                                                       float* __restrict__ pooled) {
    int g = blockIdx.x;
    __shared__ int sbeg, send;
    int tid = threadIdx.x;
    if (tid == 0) {
        int lo = 0, hi = NN;
        while (lo < hi) { int mid = (lo + hi) >> 1; if (batch[mid] < g) lo = mid + 1; else hi = mid; }
        sbeg = lo;
        lo = 0; hi = NN;
        while (lo < hi) { int mid = (lo + hi) >> 1; if (batch[mid] < g + 1) lo = mid + 1; else hi = mid; }
        send = lo;
    }
    __syncthreads();
    int beg = sbeg, end = send;
    int c4 = (tid & 15) * 4;
    int rg = tid >> 4;
    float sx = 0, sy = 0, sz = 0, sw = 0;
    for (int n = beg + rg; n < end; n += 16) {
        float4 v = *(const float4*)&h[(size_t)n * 64 + c4];
        sx += v.x; sy += v.y; sz += v.z; sw += v.w;
    }
    __shared__ float red[256 * 4];
    float* p = &red[tid * 4];
    p[0] = sx; p[1] = sy; p[2] = sz; p[3] = sw;
    __syncthreads();
    if (tid < 64) {
        int cg = tid >> 2;   // channel-4 group 0..15
        int j = tid & 3;
        float acc = 0.f;
        for (int r = 0; r < 16; ++r) acc += red[(r * 16 + cg) * 4 + j];
        float cnt = fmaxf((float)(end - beg), 1.0f);
        pooled[g * 64 + cg * 4 + j] = acc / cnt;
    }
}

// ---------------- head: pooled -> BN(G) -> fc1 -> prelu -> fc2 ----------------

__global__ __launch_bounds__(256) void final_kernel(const float* __restrict__ pooled_g,
                                                    const float* __restrict__ gamma,
                                                    const float* __restrict__ beta,
                                                    const float* __restrict__ fc1w,
                                                    const float* __restrict__ fc1b,
                                                    const float* __restrict__ prelu_p,
                                                    const float* __restrict__ fc2w,
                                                    const float* __restrict__ fc2b,
                                                    float* __restrict__ o1ws,
                                                    float* __restrict__ out) {
    __shared__ float pooled[64 * 64];
    __shared__ float scaleS[64];
    __shared__ float shiftS[64];
    int tid = threadIdx.x;
    for (int i = tid; i < 64 * 64; i += 256) pooled[i] = pooled_g[i];
    __syncthreads();
    if (tid < 64) {
        float s = 0.f, q = 0.f;
        for (int g = 0; g < 64; ++g) {
            float v = pooled[g * 64 + tid];
            s += v; q += v * v;
        }
        float mean = s * (1.0f / 64.0f);
        float var = q * (1.0f / 64.0f) - mean * mean;
        float sc = gamma[tid] * rsqrtf(var + BN_EPS);
        scaleS[tid] = sc;
        shiftS[tid] = beta[tid] - mean * sc;
    }
    __syncthreads();
    for (int i = tid; i < 64 * 64; i += 256) {
        int c = i & 63;
        pooled[i] = pooled[i] * scaleS[c] + shiftS[c];
    }
    __syncthreads();
    float alpha = prelu_p[0];
    for (int i = tid; i < 64 * 256; i += 256) {
        int g = i >> 8;
        int j = i & 255;
        float acc = fc1b[j];
        for (int k = 0; k < 64; ++k) acc += pooled[g * 64 + k] * fc1w[k * 256 + j];
        o1ws[i] = acc >= 0.f ? acc : alpha * acc;
    }
    __syncthreads();
    for (int i = tid; i < NG * NC; i += 256) {
        int g = i / NC;
        int c = i % NC;
        float acc = fc2b[c];
        for (int j = 0; j < 256; ++j) acc += o1ws[g * 256 + j] * fc2w[j * NC + c];
        out[i] = acc;
    }
}

// ---------------- launch ----------------

extern "C" void kernel_launch(void* const* d_in, const int* in_sizes, int n_in,
                              void* d_out, int out_size, void* d_ws, size_t ws_size,
                              hipStream_t stream) {
    const float* x       = (const float*)d_in[0];
    const int*   ei      = (const int*)d_in[1];
    const int*   batch   = (const int*)d_in[2];
    const float* pre_w   = (const float*)d_in[3];
    const float* pre_b   = (const float*)d_in[4];
    const float* bp1     = (const float*)d_in[5];
    const float* bng     = (const float*)d_in[6];
    const float* bnb     = (const float*)d_in[7];
    const float* bw1     = (const float*)d_in[8];
    const float* bb1     = (const float*)d_in[9];
    const float* bp2     = (const float*)d_in[10];
    const float* bw2     = (const float*)d_in[11];
    const float* bb2     = (const float*)d_in[12];
    const float* pgamma  = (const float*)d_in[13];
    const float* pbeta   = (const float*)d_in[14];
    const float* fc1w    = (const float*)d_in[15];
    const float* fc1b    = (const float*)d_in[16];
    const float* pprelu  = (const float*)d_in[17];
    const float* fc2w    = (const float*)d_in[18];
    const float* fc2b    = (const float*)d_in[19];

    const int* src = ei;
    const int* dst = ei + NE;

    float* ws      = (float*)d_ws;
    float* hA      = ws;                               // [NN,128]
    float* hB      = hA + (size_t)NN * 128;            // [NN,128]
    float* dinv    = hB + (size_t)NN * 128;            // [NN]
    float* csr_nrm = dinv + NN;                        // [NE]
    int*   row_off = (int*)(csr_nrm + NE);             // [NN+1]
    int*   cursor  = row_off + NN + 1;                 // [NN]
    int*   csr_src = cursor + NN;                      // [NE]
    int*   deg     = csr_src + NE;                     // [NN]    (zeroed)
    float* stats   = (float*)(deg + NN);               // [3*128] (zeroed)
    float* pooledg = stats + 3 * 128;                  // [64*64]
    float* o1ws    = pooledg + 64 * 64;                // [64*256]

    size_t zero_bytes = ((size_t)NN + 3 * 128) * 4;
    hipMemsetAsync(deg, 0, zero_bytes, stream);

    deg_count_kernel<<<(NE + 255) / 256, 256, 0, stream>>>(dst, deg);
    scan_kernel<<<1, 1024, 0, stream>>>(deg, row_off, cursor, dinv);
    scatter_csr_kernel<<<(NE + 255) / 256, 256, 0, stream>>>(src, dst, dinv, cursor,
                                                             csr_src, csr_nrm);

    // pre-linear: hA = x @ pre_w + pre_b   [NN,64]
    gemm_kernel<64, 64, 0><<<(NN + 15) / 16, 256, 0, stream>>>(
        x, pre_w, hA, pre_b, nullptr, nullptr, nullptr, nullptr);

    for (int i = 0; i < 3; ++i) {
        const float* a1 = bp1 + i;
        const float* a2 = bp2 + i;
        const float* g  = bng + i * 64;
        const float* bt = bnb + i * 64;
        const float* w1 = bw1 + (size_t)i * 64 * 128;
        const float* b1 = bb1 + i * 128;
        const float* w2 = bw2 + (size_t)i * 128 * 64;
        const float* b2 = bb2 + i * 64;
        float* st = stats + i * 128;

        bn_stats_kernel<<<256, 256, 0, stream>>>(hA, a1, st);
        gemm_kernel<64, 128, 1><<<(NN + 7) / 8, 256, 0, stream>>>(
            hA, w1, hB, nullptr, a1, st, g, bt);
        gather_agg_kernel<128><<<(NN + 7) / 8, 256, 0, stream>>>(
            row_off, csr_src, csr_nrm, dinv, b1, hB, hA);
        gemm_kernel<128, 64, 2><<<(NN + 15) / 16, 256, 0, stream>>>(
            hA, w2, hB, nullptr, a2, nullptr, nullptr, nullptr);
        gather_agg_kernel<64><<<(NN + 15) / 16, 256, 0, stream>>>(
            row_off, csr_src, csr_nrm, dinv, b2, hB, hA);
    }

    pool_seg_kernel<<<NG, 256, 0, stream>>>(hA, batch, pooledg);
    final_kernel<<<1, 256, 0, stream>>>(pooledg, pgamma, pbeta, fc1w, fc1b,
                                        pprelu, fc2w, fc2b, o1ws, (float*)d_out);
}

// Round 4
// 704.479 us; speedup vs baseline: 9.5856x; 1.1647x over previous
//
#include <hip/hip_runtime.h>

#define NN 50000
#define NE 800000
#define FD 64
#define HD 64
#define NG 64
#define NC 10
#define BN_EPS 1e-5f
#define NSB 196   // ceil(NN/256)

// ---------------- CSR build ----------------

__global__ void deg_count_kernel(const int* __restrict__ dst, int* __restrict__ deg) {
    int e = blockIdx.x * blockDim.x + threadIdx.x;
    if (e < NE) atomicAdd(&deg[dst[e]], 1);
}

// phase 1: per-block (256-elem chunk) sums of deg
__global__ __launch_bounds__(256) void block_sum_kernel(const int* __restrict__ deg,
                                                        int* __restrict__ bsum) {
    int b = blockIdx.x, t = threadIdx.x;
    int n = b * 256 + t;
    int v = (n < NN) ? deg[n] : 0;
    __shared__ int red[256];
    red[t] = v;
    __syncthreads();
    for (int off = 128; off > 0; off >>= 1) {
        if (t < off) red[t] += red[t + off];
        __syncthreads();
    }
    if (t == 0) bsum[b] = red[0];
}

// phase 2: single-block exclusive scan of bsum[NSB] -> boff[NSB]
__global__ __launch_bounds__(256) void bsum_scan_kernel(const int* __restrict__ bsum,
                                                        int* __restrict__ boff) {
    __shared__ int s[256];
    int t = threadIdx.x;
    int v = (t < NSB) ? bsum[t] : 0;
    s[t] = v;
    __syncthreads();
    for (int off = 1; off < 256; off <<= 1) {
        int cur = s[t];
        int add = (t >= off) ? s[t - off] : 0;
        __syncthreads();
        s[t] = cur + add;
        __syncthreads();
    }
    if (t < NSB) boff[t] = s[t] - v;   // exclusive
}

// phase 3: intra-block scan + block offset -> row_off, cursor, dinv
__global__ __launch_bounds__(256) void csr_setup_kernel(const int* __restrict__ deg,
                                                        const int* __restrict__ boff,
                                                        int* __restrict__ row_off,
                                                        int* __restrict__ cursor,
                                                        float* __restrict__ dinv) {
    int b = blockIdx.x, t = threadIdx.x;
    int n = b * 256 + t;
    int v = (n < NN) ? deg[n] : 0;
    __shared__ int s[256];
    s[t] = v;
    __syncthreads();
    for (int off = 1; off < 256; off <<= 1) {
        int cur = s[t];
        int add = (t >= off) ? s[t - off] : 0;
        __syncthreads();
        s[t] = cur + add;
        __syncthreads();
    }
    int excl = s[t] - v + boff[b];
    if (n < NN) {
        row_off[n] = excl;
        cursor[n] = excl;
        dinv[n] = rsqrtf((float)v + 1.0f);
    }
    if (n == NN - 1) row_off[NN] = NE;
}

__global__ void scatter_csr_kernel(const int* __restrict__ src, const int* __restrict__ dst,
                                   const float* __restrict__ dinv, int* __restrict__ cursor,
                                   int* __restrict__ csr_src, float* __restrict__ csr_nrm) {
    int e = blockIdx.x * blockDim.x + threadIdx.x;
    if (e >= NE) return;
    int s = src[e];
    int d = dst[e];
    int pos = atomicAdd(&cursor[d], 1);
    csr_src[pos] = s;
    csr_nrm[pos] = dinv[s] * dinv[d];
}

// ---------------- BN stats ----------------

__global__ __launch_bounds__(256) void bn_stats_kernel(const float* __restrict__ h,
                                                       const float* __restrict__ alpha_p,
                                                       float* __restrict__ stats) {
    float alpha = alpha_p[0];
    int tid = threadIdx.x;
    int c4 = (tid & 15) * 4;
    int rg = tid >> 4;
    float sx = 0, sy = 0, sz = 0, sw = 0;
    float qx = 0, qy = 0, qz = 0, qw = 0;
    for (int n = blockIdx.x * 16 + rg; n < NN; n += gridDim.x * 16) {
        float4 v = *(const float4*)&h[(size_t)n * 64 + c4];
        float a = v.x >= 0.f ? v.x : alpha * v.x;
        float b = v.y >= 0.f ? v.y : alpha * v.y;
        float c = v.z >= 0.f ? v.z : alpha * v.z;
        float d = v.w >= 0.f ? v.w : alpha * v.w;
        sx += a; sy += b; sz += c; sw += d;
        qx += a * a; qy += b * b; qz += c * c; qw += d * d;
    }
    __shared__ float ls[256 * 8];
    float* p = &ls[tid * 8];
    p[0] = sx; p[1] = sy; p[2] = sz; p[3] = sw;
    p[4] = qx; p[5] = qy; p[6] = qz; p[7] = qw;
    __syncthreads();
    if (tid < 128) {
        int cidx = tid >> 3;
        int j = tid & 7;
        float acc = 0.f;
        for (int r = 0; r < 16; ++r) acc += ls[(r * 16 + cidx) * 8 + j];
        int ch = cidx * 4 + (j & 3);
        if (j < 4) atomicAdd(&stats[ch], acc);
        else       atomicAdd(&stats[64 + ch], acc);
    }
}

// ---------------- generic small-K GEMM ----------------
// MODE 0: out = A@W + bias ; MODE 1: BN(prelu(A)) @ W ; MODE 2: prelu(A) @ W

template <int K, int M, int MODE>
__global__ __launch_bounds__(256) void gemm_kernel(const float* __restrict__ A,
                                                   const float* __restrict__ W,
                                                   float* __restrict__ out,
                                                   const float* __restrict__ bias,
                                                   const float* __restrict__ alpha_p,
                                                   const float* __restrict__ stats,
                                                   const float* __restrict__ gamma,
                                                   const float* __restrict__ beta) {
    constexpr int TPR = M / 4;
    constexpr int RPB = 256 / TPR;
    __shared__ float Wlds[K * M];
    __shared__ float scaleS[K];
    __shared__ float shiftS[K];
    int tid = threadIdx.x;
    for (int i = tid * 4; i < K * M; i += 1024) {
        *(float4*)&Wlds[i] = *(const float4*)&W[i];
    }
    float alpha = 0.f;
    if constexpr (MODE == 1 || MODE == 2) alpha = alpha_p[0];
    if constexpr (MODE == 1) {
        for (int k = tid; k < K; k += 256) {
            float mean = stats[k] * (1.0f / NN);
            float var  = stats[64 + k] * (1.0f / NN) - mean * mean;
            float sc = gamma[k] * rsqrtf(var + BN_EPS);
            scaleS[k] = sc;
            shiftS[k] = beta[k] - mean * sc;
        }
    }
    __syncthreads();
    int r = blockIdx.x * RPB + tid / TPR;
    int c = (tid % TPR) * 4;
    if (r >= NN) return;
    const float* Arow = A + (size_t)r * K;
    float ax = 0, ay = 0, az = 0, aw = 0;
#pragma unroll 8
    for (int k = 0; k < K; ++k) {
        float a = Arow[k];
        if constexpr (MODE == 1) {
            a = a >= 0.f ? a : alpha * a;
            a = a * scaleS[k] + shiftS[k];
        }
        if constexpr (MODE == 2) {
            a = a >= 0.f ? a : alpha * a;
        }
        float4 w = *(const float4*)&Wlds[k * M + c];
        ax += a * w.x; ay += a * w.y; az += a * w.z; aw += a * w.w;
    }
    if constexpr (MODE == 0) {
        ax += bias[c]; ay += bias[c + 1]; az += bias[c + 2]; aw += bias[c + 3];
    }
    float4 o = {ax, ay, az, aw};
    *(float4*)&out[(size_t)r * M + c] = o;
}

// ---------------- CSR gather aggregation (fused self-loop + bias) ----------------

template <int M>
__global__ __launch_bounds__(256) void gather_agg_kernel(const int* __restrict__ row_off,
                                                         const int* __restrict__ csr_src,
                                                         const float* __restrict__ csr_nrm,
                                                         const float* __restrict__ dinv,
                                                         const float* __restrict__ bias,
                                                         const float* __restrict__ hh,
                                                         float* __restrict__ agg) {
    constexpr int TPR = M / 4;
    constexpr int RPB = 256 / TPR;
    int tid = threadIdx.x;
    int r = blockIdx.x * RPB + tid / TPR;
    int c = (tid % TPR) * 4;
    if (r >= NN) return;
    float dv = dinv[r];
    float d2 = dv * dv;
    float4 h0 = *(const float4*)&hh[(size_t)r * M + c];
    float4 b = *(const float4*)&bias[c];
    float ax = h0.x * d2 + b.x;
    float ay = h0.y * d2 + b.y;
    float az = h0.z * d2 + b.z;
    float aw = h0.w * d2 + b.w;
    int beg = row_off[r];
    int end = row_off[r + 1];
    int i = beg;
    for (; i + 1 < end; i += 2) {
        int s0 = csr_src[i];
        int s1 = csr_src[i + 1];
        float w0 = csr_nrm[i];
        float w1 = csr_nrm[i + 1];
        float4 v0 = *(const float4*)&hh[(size_t)s0 * M + c];
        float4 v1 = *(const float4*)&hh[(size_t)s1 * M + c];
        ax += v0.x * w0 + v1.x * w1;
        ay += v0.y * w0 + v1.y * w1;
        az += v0.z * w0 + v1.z * w1;
        aw += v0.w * w0 + v1.w * w1;
    }
    if (i < end) {
        int s0 = csr_src[i];
        float w0 = csr_nrm[i];
        float4 v0 = *(const float4*)&hh[(size_t)s0 * M + c];
        ax += v0.x * w0; ay += v0.y * w0; az += v0.z * w0; aw += v0.w * w0;
    }
    float4 o = {ax, ay, az, aw};
    *(float4*)&agg[(size_t)r * M + c] = o;
}

// ---------------- pool: one block per graph (batch sorted) ----------------

__global__ __launch_bounds__(256) void pool_seg_kernel(const float* __restrict__ h,
                                                       const int* __restrict__ batch,
                                                       float* __restrict__ pooled) {
    int g = blockIdx.x;
    __shared__ int sbeg, send;
    int tid = threadIdx.x;
    if (tid == 0) {
        int lo = 0, hi = NN;
        while (lo < hi) { int mid = (lo + hi) >> 1; if (batch[mid] < g) lo = mid + 1; else hi = mid; }
        sbeg = lo;
        lo = 0; hi = NN;
        while (lo < hi) { int mid = (lo + hi) >> 1; if (batch[mid] < g + 1) lo = mid + 1; else hi = mid; }
        send = lo;
    }
    __syncthreads();
    int beg = sbeg, end = send;
    int c4 = (tid & 15) * 4;
    int rg = tid >> 4;
    float sx = 0, sy = 0, sz = 0, sw = 0;
    for (int n = beg + rg; n < end; n += 16) {
        float4 v = *(const float4*)&h[(size_t)n * 64 + c4];
        sx += v.x; sy += v.y; sz += v.z; sw += v.w;
    }
    __shared__ float red[256 * 4];
    float* p = &red[tid * 4];
    p[0] = sx; p[1] = sy; p[2] = sz; p[3] = sw;
    __syncthreads();
    if (tid < 64) {
        int cg = tid >> 2;
        int j = tid & 3;
        float acc = 0.f;
        for (int r = 0; r < 16; ++r) acc += red[(r * 16 + cg) * 4 + j];
        float cnt = fmaxf((float)(end - beg), 1.0f);
        pooled[g * 64 + cg * 4 + j] = acc / cnt;
    }
}

// ---------------- head ----------------

__global__ __launch_bounds__(256) void final_kernel(const float* __restrict__ pooled_g,
                                                    const float* __restrict__ gamma,
                                                    const float* __restrict__ beta,
                                                    const float* __restrict__ fc1w,
                                                    const float* __restrict__ fc1b,
                                                    const float* __restrict__ prelu_p,
                                                    const float* __restrict__ fc2w,
                                                    const float* __restrict__ fc2b,
                                                    float* __restrict__ o1ws,
                                                    float* __restrict__ out) {
    __shared__ float pooled[64 * 64];
    __shared__ float scaleS[64];
    __shared__ float shiftS[64];
    int tid = threadIdx.x;
    for (int i = tid; i < 64 * 64; i += 256) pooled[i] = pooled_g[i];
    __syncthreads();
    if (tid < 64) {
        float s = 0.f, q = 0.f;
        for (int g = 0; g < 64; ++g) {
            float v = pooled[g * 64 + tid];
            s += v; q += v * v;
        }
        float mean = s * (1.0f / 64.0f);
        float var = q * (1.0f / 64.0f) - mean * mean;
        float sc = gamma[tid] * rsqrtf(var + BN_EPS);
        scaleS[tid] = sc;
        shiftS[tid] = beta[tid] - mean * sc;
    }
    __syncthreads();
    for (int i = tid; i < 64 * 64; i += 256) {
        int c = i & 63;
        pooled[i] = pooled[i] * scaleS[c] + shiftS[c];
    }
    __syncthreads();
    float alpha = prelu_p[0];
    for (int i = tid; i < 64 * 256; i += 256) {
        int g = i >> 8;
        int j = i & 255;
        float acc = fc1b[j];
        for (int k = 0; k < 64; ++k) acc += pooled[g * 64 + k] * fc1w[k * 256 + j];
        o1ws[i] = acc >= 0.f ? acc : alpha * acc;
    }
    __syncthreads();
    for (int i = tid; i < NG * NC; i += 256) {
        int g = i / NC;
        int c = i % NC;
        float acc = fc2b[c];
        for (int j = 0; j < 256; ++j) acc += o1ws[g * 256 + j] * fc2w[j * NC + c];
        out[i] = acc;
    }
}

// ---------------- launch ----------------

extern "C" void kernel_launch(void* const* d_in, const int* in_sizes, int n_in,
                              void* d_out, int out_size, void* d_ws, size_t ws_size,
                              hipStream_t stream) {
    const float* x       = (const float*)d_in[0];
    const int*   ei      = (const int*)d_in[1];
    const int*   batch   = (const int*)d_in[2];
    const float* pre_w   = (const float*)d_in[3];
    const float* pre_b   = (const float*)d_in[4];
    const float* bp1     = (const float*)d_in[5];
    const float* bng     = (const float*)d_in[6];
    const float* bnb     = (const float*)d_in[7];
    const float* bw1     = (const float*)d_in[8];
    const float* bb1     = (const float*)d_in[9];
    const float* bp2     = (const float*)d_in[10];
    const float* bw2     = (const float*)d_in[11];
    const float* bb2     = (const float*)d_in[12];
    const float* pgamma  = (const float*)d_in[13];
    const float* pbeta   = (const float*)d_in[14];
    const float* fc1w    = (const float*)d_in[15];
    const float* fc1b    = (const float*)d_in[16];
    const float* pprelu  = (const float*)d_in[17];
    const float* fc2w    = (const float*)d_in[18];
    const float* fc2b    = (const float*)d_in[19];

    const int* src = ei;
    const int* dst = ei + NE;

    float* ws      = (float*)d_ws;
    float* hA      = ws;                               // [NN,128]
    float* hB      = hA + (size_t)NN * 128;            // [NN,128]
    float* dinv    = hB + (size_t)NN * 128;            // [NN]
    float* csr_nrm = dinv + NN;                        // [NE]
    int*   row_off = (int*)(csr_nrm + NE);             // [NN+1]
    int*   cursor  = row_off + NN + 1;                 // [NN]
    int*   csr_src = cursor + NN;                      // [NE]
    int*   deg     = csr_src + NE;                     // [NN]    (zeroed)
    int*   bsum    = deg + NN;                         // [NSB]
    int*   boff    = bsum + NSB;                       // [NSB]
    float* stats   = (float*)(boff + NSB);             // [3*128] (zeroed)
    float* pooledg = stats + 3 * 128;                  // [64*64]
    float* o1ws    = pooledg + 64 * 64;                // [64*256]

    hipMemsetAsync(deg, 0, (size_t)NN * 4, stream);
    hipMemsetAsync(stats, 0, (size_t)3 * 128 * 4, stream);

    deg_count_kernel<<<(NE + 255) / 256, 256, 0, stream>>>(dst, deg);
    block_sum_kernel<<<NSB, 256, 0, stream>>>(deg, bsum);
    bsum_scan_kernel<<<1, 256, 0, stream>>>(bsum, boff);
    csr_setup_kernel<<<NSB, 256, 0, stream>>>(deg, boff, row_off, cursor, dinv);
    scatter_csr_kernel<<<(NE + 255) / 256, 256, 0, stream>>>(src, dst, dinv, cursor,
                                                             csr_src, csr_nrm);

    // pre-linear: hA = x @ pre_w + pre_b   [NN,64]
    gemm_kernel<64, 64, 0><<<(NN + 15) / 16, 256, 0, stream>>>(
        x, pre_w, hA, pre_b, nullptr, nullptr, nullptr, nullptr);

    for (int i = 0; i < 3; ++i) {
        const float* a1 = bp1 + i;
        const float* a2 = bp2 + i;
        const float* g  = bng + i * 64;
        const float* bt = bnb + i * 64;
        const float* w1 = bw1 + (size_t)i * 64 * 128;
        const float* b1 = bb1 + i * 128;
        const float* w2 = bw2 + (size_t)i * 128 * 64;
        const float* b2 = bb2 + i * 64;
        float* st = stats + i * 128;

        bn_stats_kernel<<<256, 256, 0, stream>>>(hA, a1, st);
        gemm_kernel<64, 128, 1><<<(NN + 7) / 8, 256, 0, stream>>>(
            hA, w1, hB, nullptr, a1, st, g, bt);
        gather_agg_kernel<128><<<(NN + 7) / 8, 256, 0, stream>>>(
            row_off, csr_src, csr_nrm, dinv, b1, hB, hA);
        gemm_kernel<128, 64, 2><<<(NN + 15) / 16, 256, 0, stream>>>(
            hA, w2, hB, nullptr, a2, nullptr, nullptr, nullptr);
        gather_agg_kernel<64><<<(NN + 15) / 16, 256, 0, stream>>>(
            row_off, csr_src, csr_nrm, dinv, b2, hB, hA);
    }

    pool_seg_kernel<<<NG, 256, 0, stream>>>(hA, batch, pooledg);
    final_kernel<<<1, 256, 0, stream>>>(pooledg, pgamma, pbeta, fc1w, fc1b,
                                        pprelu, fc2w, fc2b, o1ws, (float*)d_out);
}

// Round 5
// 558.912 us; speedup vs baseline: 12.0822x; 1.2604x over previous
//
#include <hip/hip_runtime.h>

#define NN 50000
#define NE 800000
#define NG 64
#define NC 10
#define BN_EPS 1e-5f
#define NSB 196   // ceil(NN/256)

// ---------------- CSR build ----------------

__global__ void deg_count_kernel(const int* __restrict__ dst, int* __restrict__ deg) {
    int e = blockIdx.x * blockDim.x + threadIdx.x;
    if (e < NE) atomicAdd(&deg[dst[e]], 1);
}

__global__ __launch_bounds__(256) void block_sum_kernel(const int* __restrict__ deg,
                                                        int* __restrict__ bsum) {
    int b = blockIdx.x, t = threadIdx.x;
    int n = b * 256 + t;
    int v = (n < NN) ? deg[n] : 0;
    __shared__ int red[256];
    red[t] = v;
    __syncthreads();
    for (int off = 128; off > 0; off >>= 1) {
        if (t < off) red[t] += red[t + off];
        __syncthreads();
    }
    if (t == 0) bsum[b] = red[0];
}

__global__ __launch_bounds__(256) void bsum_scan_kernel(const int* __restrict__ bsum,
                                                        int* __restrict__ boff) {
    __shared__ int s[256];
    int t = threadIdx.x;
    int v = (t < NSB) ? bsum[t] : 0;
    s[t] = v;
    __syncthreads();
    for (int off = 1; off < 256; off <<= 1) {
        int cur = s[t];
        int add = (t >= off) ? s[t - off] : 0;
        __syncthreads();
        s[t] = cur + add;
        __syncthreads();
    }
    if (t < NSB) boff[t] = s[t] - v;
}

__global__ __launch_bounds__(256) void csr_setup_kernel(const int* __restrict__ deg,
                                                        const int* __restrict__ boff,
                                                        int* __restrict__ row_off,
                                                        int* __restrict__ cursor,
                                                        float* __restrict__ dinv) {
    int b = blockIdx.x, t = threadIdx.x;
    int n = b * 256 + t;
    int v = (n < NN) ? deg[n] : 0;
    __shared__ int s[256];
    s[t] = v;
    __syncthreads();
    for (int off = 1; off < 256; off <<= 1) {
        int cur = s[t];
        int add = (t >= off) ? s[t - off] : 0;
        __syncthreads();
        s[t] = cur + add;
        __syncthreads();
    }
    int excl = s[t] - v + boff[b];
    if (n < NN) {
        row_off[n] = excl;
        cursor[n] = excl;
        dinv[n] = rsqrtf((float)v + 1.0f);
    }
    if (n == NN - 1) row_off[NN] = NE;
}

// interleaved CSR entry: {src, bitcast(norm)} -> one 8B write per edge
__global__ void scatter_csr_kernel(const int* __restrict__ src, const int* __restrict__ dst,
                                   const float* __restrict__ dinv, int* __restrict__ cursor,
                                   int2* __restrict__ csr_ent) {
    int e = blockIdx.x * blockDim.x + threadIdx.x;
    if (e >= NE) return;
    int s = src[e];
    int d = dst[e];
    int pos = atomicAdd(&cursor[d], 1);
    int2 ent;
    ent.x = s;
    ent.y = __float_as_int(dinv[s] * dinv[d]);
    csr_ent[pos] = ent;
}

// ---------------- BN stats: sum & sumsq of prelu(h, a), per channel (64-wide h) ----------------

__global__ __launch_bounds__(256) void bn_stats_kernel(const float* __restrict__ h,
                                                       const float* __restrict__ alpha_p,
                                                       float* __restrict__ stats) {
    float alpha = alpha_p[0];
    int tid = threadIdx.x;
    int c4 = (tid & 15) * 4;
    int rg = tid >> 4;
    float sx = 0, sy = 0, sz = 0, sw = 0;
    float qx = 0, qy = 0, qz = 0, qw = 0;
    for (int n = blockIdx.x * 16 + rg; n < NN; n += gridDim.x * 16) {
        float4 v = *(const float4*)&h[(size_t)n * 64 + c4];
        float a = v.x >= 0.f ? v.x : alpha * v.x;
        float b = v.y >= 0.f ? v.y : alpha * v.y;
        float c = v.z >= 0.f ? v.z : alpha * v.z;
        float d = v.w >= 0.f ? v.w : alpha * v.w;
        sx += a; sy += b; sz += c; sw += d;
        qx += a * a; qy += b * b; qz += c * c; qw += d * d;
    }
    __shared__ float ls[256 * 8];
    float* p = &ls[tid * 8];
    p[0] = sx; p[1] = sy; p[2] = sz; p[3] = sw;
    p[4] = qx; p[5] = qy; p[6] = qz; p[7] = qw;
    __syncthreads();
    if (tid < 128) {
        int cidx = tid >> 3;
        int j = tid & 7;
        float acc = 0.f;
        for (int r = 0; r < 16; ++r) acc += ls[(r * 16 + cidx) * 8 + j];
        int ch = cidx * 4 + (j & 3);
        if (j < 4) atomicAdd(&stats[ch], acc);
        else       atomicAdd(&stats[64 + ch], acc);
    }
}

// ---------------- BN apply: g = BN(prelu(h, alpha)) ----------------

__global__ __launch_bounds__(256) void bn_apply_kernel(const float* __restrict__ h,
                                                       const float* __restrict__ stats,
                                                       const float* __restrict__ gamma,
                                                       const float* __restrict__ beta,
                                                       const float* __restrict__ alpha_p,
                                                       float* __restrict__ g) {
    int idx = blockIdx.x * blockDim.x + threadIdx.x;
    if (idx >= NN * 16) return;
    float alpha = alpha_p[0];
    int ch = (idx & 15) * 4;
    float4 v = *(const float4*)&h[(size_t)idx * 4];
    float4 o;
    {
        float m = stats[ch + 0] * (1.0f / NN);
        float sc = gamma[ch + 0] * rsqrtf(stats[64 + ch + 0] * (1.0f / NN) - m * m + BN_EPS);
        float a = v.x >= 0.f ? v.x : alpha * v.x;
        o.x = (a - m) * sc + beta[ch + 0];
    }
    {
        float m = stats[ch + 1] * (1.0f / NN);
        float sc = gamma[ch + 1] * rsqrtf(stats[64 + ch + 1] * (1.0f / NN) - m * m + BN_EPS);
        float a = v.y >= 0.f ? v.y : alpha * v.y;
        o.y = (a - m) * sc + beta[ch + 1];
    }
    {
        float m = stats[ch + 2] * (1.0f / NN);
        float sc = gamma[ch + 2] * rsqrtf(stats[64 + ch + 2] * (1.0f / NN) - m * m + BN_EPS);
        float a = v.z >= 0.f ? v.z : alpha * v.z;
        o.z = (a - m) * sc + beta[ch + 2];
    }
    {
        float m = stats[ch + 3] * (1.0f / NN);
        float sc = gamma[ch + 3] * rsqrtf(stats[64 + ch + 3] * (1.0f / NN) - m * m + BN_EPS);
        float a = v.w >= 0.f ? v.w : alpha * v.w;
        o.w = (a - m) * sc + beta[ch + 3];
    }
    *(float4*)&g[(size_t)idx * 4] = o;
}

// ---------------- register-tiled GEMM: out[N,M] = f(A[N,K]) @ W[K,M] (+bias) ----------------
// MODE 0: f = identity, add bias.  MODE 2: f = prelu(alpha), no bias.
// BM rows per block; each thread: 4 rows x 4 cols.

template <int K, int M, int BM, int MODE>
__global__ __launch_bounds__(256) void gemm_kernel(const float* __restrict__ A,
                                                   const float* __restrict__ W,
                                                   float* __restrict__ out,
                                                   const float* __restrict__ bias,
                                                   const float* __restrict__ alpha_p) {
    constexpr int CG = M / 4;        // col groups (16 or 32)
    constexpr int RG = 256 / CG;     // row groups
    constexpr int R  = BM / RG;      // rows per thread (=4)
    static_assert(R == 4, "tile assumes 4 rows/thread");
    __shared__ float Wlds[K * M];
    __shared__ float Alds[BM][68];   // 64 k-tile + 4 pad (float4-aligned rows)
    int tid = threadIdx.x;
    for (int i = tid * 4; i < K * M; i += 1024)
        *(float4*)&Wlds[i] = *(const float4*)&W[i];
    float alpha = 0.f;
    if constexpr (MODE == 2) alpha = alpha_p[0];
    int r0 = blockIdx.x * BM;
    int cg = tid % CG, rg = tid / CG;
    int c = cg * 4;
    float4 acc[4];
#pragma unroll
    for (int r = 0; r < 4; ++r) acc[r] = {0.f, 0.f, 0.f, 0.f};

    for (int kt = 0; kt < K; kt += 64) {
        __syncthreads();
        // stage A tile [BM][64] with optional prelu
        for (int i = tid; i < BM * 16; i += 256) {
            int row = i >> 4;
            int k4 = (i & 15) * 4;
            int rr = r0 + row;
            if (rr > NN - 1) rr = NN - 1;
            float4 v = *(const float4*)&A[(size_t)rr * K + kt + k4];
            if constexpr (MODE == 2) {
                v.x = v.x >= 0.f ? v.x : alpha * v.x;
                v.y = v.y >= 0.f ? v.y : alpha * v.y;
                v.z = v.z >= 0.f ? v.z : alpha * v.z;
                v.w = v.w >= 0.f ? v.w : alpha * v.w;
            }
            *(float4*)&Alds[row][k4] = v;
        }
        __syncthreads();
#pragma unroll 4
        for (int k4 = 0; k4 < 64; k4 += 4) {
            float4 a0 = *(const float4*)&Alds[rg + 0 * RG][k4];
            float4 a1 = *(const float4*)&Alds[rg + 1 * RG][k4];
            float4 a2 = *(const float4*)&Alds[rg + 2 * RG][k4];
            float4 a3 = *(const float4*)&Alds[rg + 3 * RG][k4];
            const float* wp = &Wlds[(kt + k4) * M + c];
            float4 w0 = *(const float4*)(wp);
            float4 w1 = *(const float4*)(wp + M);
            float4 w2 = *(const float4*)(wp + 2 * M);
            float4 w3 = *(const float4*)(wp + 3 * M);
            acc[0].x += a0.x * w0.x; acc[0].y += a0.x * w0.y; acc[0].z += a0.x * w0.z; acc[0].w += a0.x * w0.w;
            acc[1].x += a1.x * w0.x; acc[1].y += a1.x * w0.y; acc[1].z += a1.x * w0.z; acc[1].w += a1.x * w0.w;
            acc[2].x += a2.x * w0.x; acc[2].y += a2.x * w0.y; acc[2].z += a2.x * w0.z; acc[2].w += a2.x * w0.w;
            acc[3].x += a3.x * w0.x; acc[3].y += a3.x * w0.y; acc[3].z += a3.x * w0.z; acc[3].w += a3.x * w0.w;
            acc[0].x += a0.y * w1.x; acc[0].y += a0.y * w1.y; acc[0].z += a0.y * w1.z; acc[0].w += a0.y * w1.w;
            acc[1].x += a1.y * w1.x; acc[1].y += a1.y * w1.y; acc[1].z += a1.y * w1.z; acc[1].w += a1.y * w1.w;
            acc[2].x += a2.y * w1.x; acc[2].y += a2.y * w1.y; acc[2].z += a2.y * w1.z; acc[2].w += a2.y * w1.w;
            acc[3].x += a3.y * w1.x; acc[3].y += a3.y * w1.y; acc[3].z += a3.y * w1.z; acc[3].w += a3.y * w1.w;
            acc[0].x += a0.z * w2.x; acc[0].y += a0.z * w2.y; acc[0].z += a0.z * w2.z; acc[0].w += a0.z * w2.w;
            acc[1].x += a1.z * w2.x; acc[1].y += a1.z * w2.y; acc[1].z += a1.z * w2.z; acc[1].w += a1.z * w2.w;
            acc[2].x += a2.z * w2.x; acc[2].y += a2.z * w2.y; acc[2].z += a2.z * w2.z; acc[2].w += a2.z * w2.w;
            acc[3].x += a3.z * w2.x; acc[3].y += a3.z * w2.y; acc[3].z += a3.z * w2.z; acc[3].w += a3.z * w2.w;
            acc[0].x += a0.w * w3.x; acc[0].y += a0.w * w3.y; acc[0].z += a0.w * w3.z; acc[0].w += a0.w * w3.w;
            acc[1].x += a1.w * w3.x; acc[1].y += a1.w * w3.y; acc[1].z += a1.w * w3.z; acc[1].w += a1.w * w3.w;
            acc[2].x += a2.w * w3.x; acc[2].y += a2.w * w3.y; acc[2].z += a2.w * w3.z; acc[2].w += a2.w * w3.w;
            acc[3].x += a3.w * w3.x; acc[3].y += a3.w * w3.y; acc[3].z += a3.w * w3.z; acc[3].w += a3.w * w3.w;
        }
    }
    float4 b = {0.f, 0.f, 0.f, 0.f};
    if constexpr (MODE == 0) b = *(const float4*)&bias[c];
#pragma unroll
    for (int r = 0; r < 4; ++r) {
        int row = r0 + rg + r * RG;
        if (row < NN) {
            float4 o = {acc[r].x + b.x, acc[r].y + b.y, acc[r].z + b.z, acc[r].w + b.w};
            *(float4*)&out[(size_t)row * M + c] = o;
        }
    }
}

// ---------------- CSR gather aggregation, 64-wide (fused self-loop, optional bias) ----------------

template <bool BIAS>
__global__ __launch_bounds__(256) void gather_agg_kernel(const int* __restrict__ row_off,
                                                         const int2* __restrict__ csr_ent,
                                                         const float* __restrict__ dinv,
                                                         const float* __restrict__ bias,
                                                         const float* __restrict__ hh,
                                                         float* __restrict__ agg) {
    int tid = threadIdx.x;
    int r = blockIdx.x * 16 + (tid >> 4);
    int c = (tid & 15) * 4;
    if (r >= NN) return;
    float dv = dinv[r];
    float d2 = dv * dv;
    float4 h0 = *(const float4*)&hh[(size_t)r * 64 + c];
    float ax = h0.x * d2, ay = h0.y * d2, az = h0.z * d2, aw = h0.w * d2;
    if constexpr (BIAS) {
        float4 b = *(const float4*)&bias[c];
        ax += b.x; ay += b.y; az += b.z; aw += b.w;
    }
    int beg = row_off[r];
    int end = row_off[r + 1];
    int i = beg;
    for (; i + 1 < end; i += 2) {
        int2 e0 = csr_ent[i];
        int2 e1 = csr_ent[i + 1];
        float w0 = __int_as_float(e0.y);
        float w1 = __int_as_float(e1.y);
        float4 v0 = *(const float4*)&hh[(size_t)e0.x * 64 + c];
        float4 v1 = *(const float4*)&hh[(size_t)e1.x * 64 + c];
        ax += v0.x * w0 + v1.x * w1;
        ay += v0.y * w0 + v1.y * w1;
        az += v0.z * w0 + v1.z * w1;
        aw += v0.w * w0 + v1.w * w1;
    }
    if (i < end) {
        int2 e0 = csr_ent[i];
        float w0 = __int_as_float(e0.y);
        float4 v0 = *(const float4*)&hh[(size_t)e0.x * 64 + c];
        ax += v0.x * w0; ay += v0.y * w0; az += v0.z * w0; aw += v0.w * w0;
    }
    float4 o = {ax, ay, az, aw};
    *(float4*)&agg[(size_t)r * 64 + c] = o;
}

// ---------------- pool: one block per graph (batch sorted) ----------------

__global__ __launch_bounds__(256) void pool_seg_kernel(const float* __restrict__ h,
                                                       const int* __restrict__ batch,
                                                       float* __restrict__ pooled) {
    int g = blockIdx.x;
    __shared__ int sbeg, send;
    int tid = threadIdx.x;
    if (tid == 0) {
        int lo = 0, hi = NN;
        while (lo < hi) { int mid = (lo + hi) >> 1; if (batch[mid] < g) lo = mid + 1; else hi = mid; }
        sbeg = lo;
        lo = 0; hi = NN;
        while (lo < hi) { int mid = (lo + hi) >> 1; if (batch[mid] < g + 1) lo = mid + 1; else hi = mid; }
        send = lo;
    }
    __syncthreads();
    int beg = sbeg, end = send;
    int c4 = (tid & 15) * 4;
    int rg = tid >> 4;
    float sx = 0, sy = 0, sz = 0, sw = 0;
    for (int n = beg + rg; n < end; n += 16) {
        float4 v = *(const float4*)&h[(size_t)n * 64 + c4];
        sx += v.x; sy += v.y; sz += v.z; sw += v.w;
    }
    __shared__ float red[256 * 4];
    float* p = &red[tid * 4];
    p[0] = sx; p[1] = sy; p[2] = sz; p[3] = sw;
    __syncthreads();
    if (tid < 64) {
        int cg = tid >> 2;
        int j = tid & 3;
        float acc = 0.f;
        for (int r = 0; r < 16; ++r) acc += red[(r * 16 + cg) * 4 + j];
        float cnt = fmaxf((float)(end - beg), 1.0f);
        pooled[g * 64 + cg * 4 + j] = acc / cnt;
    }
}

// ---------------- head ----------------

__global__ __launch_bounds__(256) void final_kernel(const float* __restrict__ pooled_g,
                                                    const float* __restrict__ gamma,
                                                    const float* __restrict__ beta,
                                                    const float* __restrict__ fc1w,
                                                    const float* __restrict__ fc1b,
                                                    const float* __restrict__ prelu_p,
                                                    const float* __restrict__ fc2w,
                                                    const float* __restrict__ fc2b,
                                                    float* __restrict__ o1ws,
                                                    float* __restrict__ out) {
    __shared__ float pooled[64 * 64];
    __shared__ float scaleS[64];
    __shared__ float shiftS[64];
    int tid = threadIdx.x;
    for (int i = tid; i < 64 * 64; i += 256) pooled[i] = pooled_g[i];
    __syncthreads();
    if (tid < 64) {
        float s = 0.f, q = 0.f;
        for (int g = 0; g < 64; ++g) {
            float v = pooled[g * 64 + tid];
            s += v; q += v * v;
        }
        float mean = s * (1.0f / 64.0f);
        float var = q * (1.0f / 64.0f) - mean * mean;
        float sc = gamma[tid] * rsqrtf(var + BN_EPS);
        scaleS[tid] = sc;
        shiftS[tid] = beta[tid] - mean * sc;
    }
    __syncthreads();
    for (int i = tid; i < 64 * 64; i += 256) {
        int c = i & 63;
        pooled[i] = pooled[i] * scaleS[c] + shiftS[c];
    }
    __syncthreads();
    float alpha = prelu_p[0];
    for (int i = tid; i < 64 * 256; i += 256) {
        int g = i >> 8;
        int j = i & 255;
        float acc = fc1b[j];
        for (int k = 0; k < 64; ++k) acc += pooled[g * 64 + k] * fc1w[k * 256 + j];
        o1ws[i] = acc >= 0.f ? acc : alpha * acc;
    }
    __syncthreads();
    for (int i = tid; i < NG * NC; i += 256) {
        int g = i / NC;
        int c = i % NC;
        float acc = fc2b[c];
        for (int j = 0; j < 256; ++j) acc += o1ws[g * 256 + j] * fc2w[j * NC + c];
        out[i] = acc;
    }
}

// ---------------- launch ----------------

extern "C" void kernel_launch(void* const* d_in, const int* in_sizes, int n_in,
                              void* d_out, int out_size, void* d_ws, size_t ws_size,
                              hipStream_t stream) {
    const float* x       = (const float*)d_in[0];
    const int*   ei      = (const int*)d_in[1];
    const int*   batch   = (const int*)d_in[2];
    const float* pre_w   = (const float*)d_in[3];
    const float* pre_b   = (const float*)d_in[4];
    const float* bp1     = (const float*)d_in[5];
    const float* bng     = (const float*)d_in[6];
    const float* bnb     = (const float*)d_in[7];
    const float* bw1     = (const float*)d_in[8];
    const float* bb1     = (const float*)d_in[9];
    const float* bp2     = (const float*)d_in[10];
    const float* bw2     = (const float*)d_in[11];
    const float* bb2     = (const float*)d_in[12];
    const float* pgamma  = (const float*)d_in[13];
    const float* pbeta   = (const float*)d_in[14];
    const float* fc1w    = (const float*)d_in[15];
    const float* fc1b    = (const float*)d_in[16];
    const float* pprelu  = (const float*)d_in[17];
    const float* fc2w    = (const float*)d_in[18];
    const float* fc2b    = (const float*)d_in[19];

    const int* src = ei;
    const int* dst = ei + NE;

    float* ws      = (float*)d_ws;
    float* hA      = ws;                               // [NN,64]
    float* hB      = hA + (size_t)NN * 64;             // [NN,128]
    float* g       = hB + (size_t)NN * 128;            // [NN,64]
    float* dinv    = g + (size_t)NN * 64;              // [NN]
    int2*  csr_ent = (int2*)(dinv + NN);               // [NE] (8B each)
    int*   row_off = (int*)(csr_ent + NE);             // [NN+1]
    int*   cursor  = row_off + NN + 1;                 // [NN]
    int*   deg     = cursor + NN;                      // [NN]    (zeroed)
    float* stats   = (float*)(deg + NN);               // [3*128] (zeroed)
    int*   bsum    = (int*)(stats + 3 * 128);          // [NSB]
    int*   boff    = bsum + NSB;                       // [NSB]
    float* pooledg = (float*)(boff + NSB);             // [64*64]
    float* o1ws    = pooledg + 64 * 64;                // [64*256]

    hipMemsetAsync(deg, 0, ((size_t)NN + 3 * 128) * 4, stream);

    deg_count_kernel<<<(NE + 255) / 256, 256, 0, stream>>>(dst, deg);
    block_sum_kernel<<<NSB, 256, 0, stream>>>(deg, bsum);
    bsum_scan_kernel<<<1, 256, 0, stream>>>(bsum, boff);
    csr_setup_kernel<<<NSB, 256, 0, stream>>>(deg, boff, row_off, cursor, dinv);
    scatter_csr_kernel<<<(NE + 255) / 256, 256, 0, stream>>>(src, dst, dinv, cursor, csr_ent);

    // pre-linear: hA = x @ pre_w + pre_b   [NN,64]
    gemm_kernel<64, 64, 64, 0><<<(NN + 63) / 64, 256, 0, stream>>>(
        x, pre_w, hA, pre_b, nullptr);

    for (int i = 0; i < 3; ++i) {
        const float* a1 = bp1 + i;
        const float* a2 = bp2 + i;
        const float* gm = bng + i * 64;
        const float* bt = bnb + i * 64;
        const float* w1 = bw1 + (size_t)i * 64 * 128;
        const float* b1 = bb1 + i * 128;
        const float* w2 = bw2 + (size_t)i * 128 * 64;
        const float* b2 = bb2 + i * 64;
        float* st = stats + i * 128;

        bn_stats_kernel<<<256, 256, 0, stream>>>(hA, a1, st);
        bn_apply_kernel<<<(NN * 16 + 255) / 256, 256, 0, stream>>>(hA, st, gm, bt, a1, g);
        // aggregate in 64-wide domain (GCN norm commutes with the linear map)
        gather_agg_kernel<false><<<(NN + 15) / 16, 256, 0, stream>>>(
            row_off, csr_ent, dinv, nullptr, g, hA);
        // hB = hA @ w1 + b1   (64 -> 128)
        gemm_kernel<64, 128, 32, 0><<<(NN + 31) / 32, 256, 0, stream>>>(
            hA, w1, hB, b1, nullptr);
        // g = prelu(hB) @ w2   (128 -> 64, no bias)
        gemm_kernel<128, 64, 64, 2><<<(NN + 63) / 64, 256, 0, stream>>>(
            hB, w2, g, nullptr, a2);
        // hA = self + bias b2 + gather(g)
        gather_agg_kernel<true><<<(NN + 15) / 16, 256, 0, stream>>>(
            row_off, csr_ent, dinv, b2, g, hA);
    }

    pool_seg_kernel<<<NG, 256, 0, stream>>>(hA, batch, pooledg);
    final_kernel<<<1, 256, 0, stream>>>(pooledg, pgamma, pbeta, fc1w, fc1b,
                                        pprelu, fc2w, fc2b, o1ws, (float*)d_out);
}

// Round 6
// 444.719 us; speedup vs baseline: 15.1846x; 1.2568x over previous
//
#include <hip/hip_runtime.h>
#include <hip/hip_fp16.h>

#define NN 50000
#define NE 800000
#define NG 64
#define NC 10
#define BN_EPS 1e-5f
#define NSB 196   // ceil(NN/256)

// ---------------- fp16 pack/unpack helpers ----------------

__device__ __forceinline__ float2 up2(unsigned u) {
    __half2 h = *reinterpret_cast<__half2*>(&u);
    return __half22float2(h);
}
__device__ __forceinline__ unsigned pk2(float a, float b) {
    __half2 h = __floats2half2_rn(a, b);
    return *reinterpret_cast<unsigned*>(&h);
}

// ---------------- CSR build ----------------

__global__ void deg_count_kernel(const int* __restrict__ dst, int* __restrict__ deg) {
    int e = blockIdx.x * blockDim.x + threadIdx.x;
    if (e < NE) atomicAdd(&deg[dst[e]], 1);
}

__global__ __launch_bounds__(256) void block_sum_kernel(const int* __restrict__ deg,
                                                        int* __restrict__ bsum) {
    int b = blockIdx.x, t = threadIdx.x;
    int n = b * 256 + t;
    int v = (n < NN) ? deg[n] : 0;
    __shared__ int red[256];
    red[t] = v;
    __syncthreads();
    for (int off = 128; off > 0; off >>= 1) {
        if (t < off) red[t] += red[t + off];
        __syncthreads();
    }
    if (t == 0) bsum[b] = red[0];
}

__global__ __launch_bounds__(256) void bsum_scan_kernel(const int* __restrict__ bsum,
                                                        int* __restrict__ boff) {
    __shared__ int s[256];
    int t = threadIdx.x;
    int v = (t < NSB) ? bsum[t] : 0;
    s[t] = v;
    __syncthreads();
    for (int off = 1; off < 256; off <<= 1) {
        int cur = s[t];
        int add = (t >= off) ? s[t - off] : 0;
        __syncthreads();
        s[t] = cur + add;
        __syncthreads();
    }
    if (t < NSB) boff[t] = s[t] - v;
}

__global__ __launch_bounds__(256) void csr_setup_kernel(const int* __restrict__ deg,
                                                        const int* __restrict__ boff,
                                                        int* __restrict__ row_off,
                                                        int* __restrict__ cursor,
                                                        float* __restrict__ dinv) {
    int b = blockIdx.x, t = threadIdx.x;
    int n = b * 256 + t;
    int v = (n < NN) ? deg[n] : 0;
    __shared__ int s[256];
    s[t] = v;
    __syncthreads();
    for (int off = 1; off < 256; off <<= 1) {
        int cur = s[t];
        int add = (t >= off) ? s[t - off] : 0;
        __syncthreads();
        s[t] = cur + add;
        __syncthreads();
    }
    int excl = s[t] - v + boff[b];
    if (n < NN) {
        row_off[n] = excl;
        cursor[n] = excl;
        dinv[n] = rsqrtf((float)v + 1.0f);
    }
    if (n == NN - 1) row_off[NN] = NE;
}

__global__ void scatter_csr_kernel(const int* __restrict__ src, const int* __restrict__ dst,
                                   const float* __restrict__ dinv, int* __restrict__ cursor,
                                   int2* __restrict__ csr_ent) {
    int e = blockIdx.x * blockDim.x + threadIdx.x;
    if (e >= NE) return;
    int s = src[e];
    int d = dst[e];
    int pos = atomicAdd(&cursor[d], 1);
    int2 ent;
    ent.x = s;
    ent.y = __float_as_int(dinv[s] * dinv[d]);
    csr_ent[pos] = ent;
}

// arow[n] = dinv[n]^2 + sum of nrm over row n  (= row sum of normalized adjacency)
__global__ void arow_kernel(const int* __restrict__ row_off, const int2* __restrict__ csr_ent,
                            const float* __restrict__ dinv, float* __restrict__ arow) {
    int n = blockIdx.x * 256 + threadIdx.x;
    if (n >= NN) return;
    float dv = dinv[n];
    float s = dv * dv;
    int e0 = row_off[n], e1 = row_off[n + 1];
    for (int i = e0; i < e1; ++i) s += __int_as_float(csr_ent[i].y);
    arow[n] = s;
}

// ---------------- BN stats: sum & sumsq of prelu(h16, a), per channel ----------------

__global__ __launch_bounds__(256) void bn_stats_kernel(const __half* __restrict__ h,
                                                       const float* __restrict__ alpha_p,
                                                       float* __restrict__ stats) {
    float alpha = alpha_p[0];
    int tid = threadIdx.x;
    int c4 = (tid & 15) * 4;
    int rg = tid >> 4;
    float sx = 0, sy = 0, sz = 0, sw = 0;
    float qx = 0, qy = 0, qz = 0, qw = 0;
    for (int n = blockIdx.x * 16 + rg; n < NN; n += gridDim.x * 16) {
        uint2 u = *(const uint2*)&h[(size_t)n * 64 + c4];
        float2 lo = up2(u.x), hi = up2(u.y);
        float a = lo.x >= 0.f ? lo.x : alpha * lo.x;
        float b = lo.y >= 0.f ? lo.y : alpha * lo.y;
        float c = hi.x >= 0.f ? hi.x : alpha * hi.x;
        float d = hi.y >= 0.f ? hi.y : alpha * hi.y;
        sx += a; sy += b; sz += c; sw += d;
        qx += a * a; qy += b * b; qz += c * c; qw += d * d;
    }
    __shared__ float ls[256 * 8];
    float* p = &ls[tid * 8];
    p[0] = sx; p[1] = sy; p[2] = sz; p[3] = sw;
    p[4] = qx; p[5] = qy; p[6] = qz; p[7] = qw;
    __syncthreads();
    if (tid < 128) {
        int cidx = tid >> 3;
        int j = tid & 7;
        float acc = 0.f;
        for (int r = 0; r < 16; ++r) acc += ls[(r * 16 + cidx) * 8 + j];
        int ch = cidx * 4 + (j & 3);
        if (j < 4) atomicAdd(&stats[ch], acc);
        else       atomicAdd(&stats[64 + ch], acc);
    }
}

// ---------------- CSR gather, 64-wide fp16 in / fp16 out ----------------
// out[n] = selfw * f(h[n]) + sum_e nrm_e * f(h[src_e])  (+ bias), f = prelu if PRELU

template <bool PRELU, bool BIAS>
__global__ __launch_bounds__(256) void gather_kernel(const int* __restrict__ row_off,
                                                     const int2* __restrict__ csr_ent,
                                                     const float* __restrict__ dinv,
                                                     const float* __restrict__ bias,
                                                     const float* __restrict__ alpha_p,
                                                     const __half* __restrict__ hh,
                                                     __half* __restrict__ outp) {
    int tid = threadIdx.x;
    int r = blockIdx.x * 16 + (tid >> 4);
    int c = (tid & 15) * 4;
    if (r >= NN) return;
    float alpha = 0.f;
    if constexpr (PRELU) alpha = alpha_p[0];
    float dv = dinv[r];
    float d2 = dv * dv;
    uint2 u0 = *(const uint2*)&hh[(size_t)r * 64 + c];
    float2 slo = up2(u0.x), shi = up2(u0.y);
    float s0 = slo.x, s1 = slo.y, s2 = shi.x, s3 = shi.y;
    if constexpr (PRELU) {
        s0 = s0 >= 0.f ? s0 : alpha * s0;
        s1 = s1 >= 0.f ? s1 : alpha * s1;
        s2 = s2 >= 0.f ? s2 : alpha * s2;
        s3 = s3 >= 0.f ? s3 : alpha * s3;
    }
    float ax = s0 * d2, ay = s1 * d2, az = s2 * d2, aw = s3 * d2;
    if constexpr (BIAS) {
        float4 b = *(const float4*)&bias[c];
        ax += b.x; ay += b.y; az += b.z; aw += b.w;
    }
    int beg = row_off[r];
    int end = row_off[r + 1];
    int i = beg;
    for (; i + 1 < end; i += 2) {
        int2 e0 = csr_ent[i];
        int2 e1 = csr_ent[i + 1];
        float w0 = __int_as_float(e0.y);
        float w1 = __int_as_float(e1.y);
        uint2 v0 = *(const uint2*)&hh[(size_t)e0.x * 64 + c];
        uint2 v1 = *(const uint2*)&hh[(size_t)e1.x * 64 + c];
        float2 a0 = up2(v0.x), b0 = up2(v0.y);
        float2 a1 = up2(v1.x), b1 = up2(v1.y);
        if constexpr (PRELU) {
            a0.x = a0.x >= 0.f ? a0.x : alpha * a0.x;
            a0.y = a0.y >= 0.f ? a0.y : alpha * a0.y;
            b0.x = b0.x >= 0.f ? b0.x : alpha * b0.x;
            b0.y = b0.y >= 0.f ? b0.y : alpha * b0.y;
            a1.x = a1.x >= 0.f ? a1.x : alpha * a1.x;
            a1.y = a1.y >= 0.f ? a1.y : alpha * a1.y;
            b1.x = b1.x >= 0.f ? b1.x : alpha * b1.x;
            b1.y = b1.y >= 0.f ? b1.y : alpha * b1.y;
        }
        ax += a0.x * w0 + a1.x * w1;
        ay += a0.y * w0 + a1.y * w1;
        az += b0.x * w0 + b1.x * w1;
        aw += b0.y * w0 + b1.y * w1;
    }
    if (i < end) {
        int2 e0 = csr_ent[i];
        float w0 = __int_as_float(e0.y);
        uint2 v0 = *(const uint2*)&hh[(size_t)e0.x * 64 + c];
        float2 a0 = up2(v0.x), b0 = up2(v0.y);
        if constexpr (PRELU) {
            a0.x = a0.x >= 0.f ? a0.x : alpha * a0.x;
            a0.y = a0.y >= 0.f ? a0.y : alpha * a0.y;
            b0.x = b0.x >= 0.f ? b0.x : alpha * b0.x;
            b0.y = b0.y >= 0.f ? b0.y : alpha * b0.y;
        }
        ax += a0.x * w0;
        ay += a0.y * w0;
        az += b0.x * w0;
        aw += b0.y * w0;
    }
    uint2 o;
    o.x = pk2(ax, ay);
    o.y = pk2(az, aw);
    *(uint2*)&outp[(size_t)r * 64 + c] = o;
}

// ---------------- register-tiled GEMM: out16[N,M] = f(A[N,K]) @ W[K,M] (+bias) ----------------
// MODE 0: identity + bias.  MODE 1: (sc*a + sh*arow) + bias (BN commuted past aggregation).
// MODE 2: prelu, no bias.   AF32: A is float (else fp16).
// 4 rows x 8 cols per thread.

template <int K, int M, int BM, int MODE, bool AF32>
__global__ __launch_bounds__(256) void gemm_kernel(const float* __restrict__ Af,
                                                   const __half* __restrict__ Ah,
                                                   const float* __restrict__ W,
                                                   __half* __restrict__ outp,
                                                   const float* __restrict__ bias,
                                                   const float* __restrict__ alpha_p,
                                                   const float* __restrict__ stats,
                                                   const float* __restrict__ gamma,
                                                   const float* __restrict__ beta,
                                                   const float* __restrict__ arow) {
    static_assert(MODE != 1 || K == 64, "MODE 1 assumes K==64");
    constexpr int CG = M / 8;        // col groups
    constexpr int RG = 256 / CG;     // row groups
    static_assert(BM == 4 * RG, "4 rows per thread");
    __shared__ float Wlds[K * M];
    __shared__ float Alds[BM][68];
    __shared__ float scS[64], shS[64];
    int tid = threadIdx.x;
    for (int i = tid * 4; i < K * M; i += 1024)
        *(float4*)&Wlds[i] = *(const float4*)&W[i];
    float alpha = 0.f;
    if constexpr (MODE == 2) alpha = alpha_p[0];
    if constexpr (MODE == 1) {
        if (tid < 64) {
            float mean = stats[tid] * (1.0f / NN);
            float var  = stats[64 + tid] * (1.0f / NN) - mean * mean;
            float sc = gamma[tid] * rsqrtf(var + BN_EPS);
            scS[tid] = sc;
            shS[tid] = beta[tid] - mean * sc;
        }
    }
    int r0 = blockIdx.x * BM;
    int cg = tid % CG, rg = tid / CG;
    int c = cg * 8;
    float acc[4][8];
#pragma unroll
    for (int r = 0; r < 4; ++r)
#pragma unroll
        for (int j = 0; j < 8; ++j) acc[r][j] = 0.f;

    for (int kt = 0; kt < K; kt += 64) {
        __syncthreads();
        for (int i = tid; i < BM * 16; i += 256) {
            int row = i >> 4;
            int k4 = (i & 15) * 4;
            int rr = r0 + row;
            if (rr > NN - 1) rr = NN - 1;
            float4 v;
            if constexpr (AF32) {
                v = *(const float4*)&Af[(size_t)rr * K + kt + k4];
            } else {
                uint2 u = *(const uint2*)&Ah[(size_t)rr * K + kt + k4];
                float2 lo = up2(u.x), hi = up2(u.y);
                v.x = lo.x; v.y = lo.y; v.z = hi.x; v.w = hi.y;
            }
            if constexpr (MODE == 1) {
                float av = arow[rr];
                v.x = v.x * scS[k4 + 0] + shS[k4 + 0] * av;
                v.y = v.y * scS[k4 + 1] + shS[k4 + 1] * av;
                v.z = v.z * scS[k4 + 2] + shS[k4 + 2] * av;
                v.w = v.w * scS[k4 + 3] + shS[k4 + 3] * av;
            }
            if constexpr (MODE == 2) {
                v.x = v.x >= 0.f ? v.x : alpha * v.x;
                v.y = v.y >= 0.f ? v.y : alpha * v.y;
                v.z = v.z >= 0.f ? v.z : alpha * v.z;
                v.w = v.w >= 0.f ? v.w : alpha * v.w;
            }
            *(float4*)&Alds[row][k4] = v;
        }
        __syncthreads();
#pragma unroll 2
        for (int k4 = 0; k4 < 64; k4 += 4) {
            float4 ar[4];
#pragma unroll
            for (int r = 0; r < 4; ++r) ar[r] = *(const float4*)&Alds[rg + r * RG][k4];
#pragma unroll
            for (int kk = 0; kk < 4; ++kk) {
                const float* wp = &Wlds[(kt + k4 + kk) * M + c];
                float4 wlo = *(const float4*)wp;
                float4 whi = *(const float4*)(wp + 4);
#pragma unroll
                for (int r = 0; r < 4; ++r) {
                    float av = (&ar[r].x)[kk];
                    acc[r][0] += av * wlo.x; acc[r][1] += av * wlo.y;
                    acc[r][2] += av * wlo.z; acc[r][3] += av * wlo.w;
                    acc[r][4] += av * whi.x; acc[r][5] += av * whi.y;
                    acc[r][6] += av * whi.z; acc[r][7] += av * whi.w;
                }
            }
        }
    }
    float blo[8];
#pragma unroll
    for (int j = 0; j < 8; ++j) blo[j] = 0.f;
    if constexpr (MODE == 0 || MODE == 1) {
        float4 b0 = *(const float4*)&bias[c];
        float4 b1 = *(const float4*)&bias[c + 4];
        blo[0] = b0.x; blo[1] = b0.y; blo[2] = b0.z; blo[3] = b0.w;
        blo[4] = b1.x; blo[5] = b1.y; blo[6] = b1.z; blo[7] = b1.w;
    }
#pragma unroll
    for (int r = 0; r < 4; ++r) {
        int row = r0 + rg + r * RG;
        if (row < NN) {
            uint4 o;
            o.x = pk2(acc[r][0] + blo[0], acc[r][1] + blo[1]);
            o.y = pk2(acc[r][2] + blo[2], acc[r][3] + blo[3]);
            o.z = pk2(acc[r][4] + blo[4], acc[r][5] + blo[5]);
            o.w = pk2(acc[r][6] + blo[6], acc[r][7] + blo[7]);
            *(uint4*)&outp[(size_t)row * M + c] = o;
        }
    }
}

// ---------------- pool: one block per graph (batch sorted), fp16 in, f32 out ----------------

__global__ __launch_bounds__(256) void pool_seg_kernel(const __half* __restrict__ h,
                                                       const int* __restrict__ batch,
                                                       float* __restrict__ pooled) {
    int g = blockIdx.x;
    __shared__ int sbeg, send;
    int tid = threadIdx.x;
    if (tid == 0) {
        int lo = 0, hi = NN;
        while (lo < hi) { int mid = (lo + hi) >> 1; if (batch[mid] < g) lo = mid + 1; else hi = mid; }
        sbeg = lo;
        lo = 0; hi = NN;
        while (lo < hi) { int mid = (lo + hi) >> 1; if (batch[mid] < g + 1) lo = mid + 1; else hi = mid; }
        send = lo;
    }
    __syncthreads();
    int beg = sbeg, end = send;
    int c4 = (tid & 15) * 4;
    int rg = tid >> 4;
    float sx = 0, sy = 0, sz = 0, sw = 0;
    for (int n = beg + rg; n < end; n += 16) {
        uint2 u = *(const uint2*)&h[(size_t)n * 64 + c4];
        float2 lo = up2(u.x), hi = up2(u.y);
        sx += lo.x; sy += lo.y; sz += hi.x; sw += hi.y;
    }
    __shared__ float red[256 * 4];
    float* p = &red[tid * 4];
    p[0] = sx; p[1] = sy; p[2] = sz; p[3] = sw;
    __syncthreads();
    if (tid < 64) {
        int cg = tid >> 2;
        int j = tid & 3;
        float acc = 0.f;
        for (int r = 0; r < 16; ++r) acc += red[(r * 16 + cg) * 4 + j];
        float cnt = fmaxf((float)(end - beg), 1.0f);
        pooled[g * 64 + cg * 4 + j] = acc / cnt;
    }
}

// ---------------- head: BN stats over graphs ----------------

__global__ __launch_bounds__(64) void head_stats_kernel(const float* __restrict__ pooled,
                                                        const float* __restrict__ gamma,
                                                        const float* __restrict__ beta,
                                                        float* __restrict__ headsc) {
    int ch = threadIdx.x;
    float s = 0.f, q = 0.f;
    for (int g = 0; g < 64; ++g) {
        float v = pooled[g * 64 + ch];
        s += v; q += v * v;
    }
    float mean = s * (1.0f / 64.0f);
    float var = q * (1.0f / 64.0f) - mean * mean;
    float sc = gamma[ch] * rsqrtf(var + BN_EPS);
    headsc[ch] = sc;
    headsc[64 + ch] = beta[ch] - mean * sc;
}

// ---------------- head: per-graph fc1 + prelu + fc2 ----------------

__global__ __launch_bounds__(256) void head_fc_kernel(const float* __restrict__ pooled,
                                                      const float* __restrict__ headsc,
                                                      const float* __restrict__ fc1w,
                                                      const float* __restrict__ fc1b,
                                                      const float* __restrict__ prelu_p,
                                                      const float* __restrict__ fc2w,
                                                      const float* __restrict__ fc2b,
                                                      float* __restrict__ out) {
    int g = blockIdx.x;
    int tid = threadIdx.x;
    __shared__ float pr[64];
    __shared__ float red[256];
    if (tid < 64) pr[tid] = pooled[g * 64 + tid] * headsc[tid] + headsc[64 + tid];
    __syncthreads();
    float alpha = prelu_p[0];
    float o1 = fc1b[tid];
    for (int k = 0; k < 64; ++k) o1 += pr[k] * fc1w[k * 256 + tid];
    o1 = o1 >= 0.f ? o1 : alpha * o1;
    for (int c = 0; c < NC; ++c) {
        red[tid] = o1 * fc2w[tid * NC + c];
        __syncthreads();
        for (int off = 128; off > 0; off >>= 1) {
            if (tid < off) red[tid] += red[tid + off];
            __syncthreads();
        }
        if (tid == 0) out[g * NC + c] = red[0] + fc2b[c];
        __syncthreads();
    }
}

// ---------------- launch ----------------

extern "C" void kernel_launch(void* const* d_in, const int* in_sizes, int n_in,
                              void* d_out, int out_size, void* d_ws, size_t ws_size,
                              hipStream_t stream) {
    const float* x       = (const float*)d_in[0];
    const int*   ei      = (const int*)d_in[1];
    const int*   batch   = (const int*)d_in[2];
    const float* pre_w   = (const float*)d_in[3];
    const float* pre_b   = (const float*)d_in[4];
    const float* bp1     = (const float*)d_in[5];
    const float* bng     = (const float*)d_in[6];
    const float* bnb     = (const float*)d_in[7];
    const float* bw1     = (const float*)d_in[8];
    const float* bb1     = (const float*)d_in[9];
    const float* bp2     = (const float*)d_in[10];
    const float* bw2     = (const float*)d_in[11];
    const float* bb2     = (const float*)d_in[12];
    const float* pgamma  = (const float*)d_in[13];
    const float* pbeta   = (const float*)d_in[14];
    const float* fc1w    = (const float*)d_in[15];
    const float* fc1b    = (const float*)d_in[16];
    const float* pprelu  = (const float*)d_in[17];
    const float* fc2w    = (const float*)d_in[18];
    const float* fc2b    = (const float*)d_in[19];

    const int* src = ei;
    const int* dst = ei + NE;

    // fp16 tables first (sizes keep 8B alignment throughout)
    __half* hA16 = (__half*)d_ws;                      // [NN,64]
    __half* u116 = hA16 + (size_t)NN * 64;             // [NN,128]
    __half* t16  = u116 + (size_t)NN * 128;            // [NN,64]
    float* dinv  = (float*)(t16 + (size_t)NN * 64);    // [NN]
    float* arow  = dinv + NN;                          // [NN]
    float* stats = arow + NN;                          // [3*128] (zeroed)
    float* pooledg = stats + 3 * 128;                  // [64*64]
    float* headsc  = pooledg + 64 * 64;                // [128]
    int2*  csr_ent = (int2*)(headsc + 128);            // [NE]
    int*   row_off = (int*)(csr_ent + NE);             // [NN+1]
    int*   cursor  = row_off + NN + 1;                 // [NN]
    int*   deg     = cursor + NN;                      // [NN] (zeroed)
    int*   bsum    = deg + NN;                         // [NSB]
    int*   boff    = bsum + NSB;                       // [NSB]

    hipMemsetAsync(stats, 0, (size_t)3 * 128 * 4, stream);
    hipMemsetAsync(deg, 0, (size_t)NN * 4, stream);

    deg_count_kernel<<<(NE + 255) / 256, 256, 0, stream>>>(dst, deg);
    block_sum_kernel<<<NSB, 256, 0, stream>>>(deg, bsum);
    bsum_scan_kernel<<<1, 256, 0, stream>>>(bsum, boff);
    csr_setup_kernel<<<NSB, 256, 0, stream>>>(deg, boff, row_off, cursor, dinv);
    scatter_csr_kernel<<<(NE + 255) / 256, 256, 0, stream>>>(src, dst, dinv, cursor, csr_ent);
    arow_kernel<<<(NN + 255) / 256, 256, 0, stream>>>(row_off, csr_ent, dinv, arow);

    // pre-linear: hA16 = x @ pre_w + pre_b   [NN,64], A is f32
    gemm_kernel<64, 64, 128, 0, true><<<(NN + 127) / 128, 256, 0, stream>>>(
        x, nullptr, pre_w, hA16, pre_b, nullptr, nullptr, nullptr, nullptr, nullptr);

    for (int i = 0; i < 3; ++i) {
        const float* a1 = bp1 + i;
        const float* a2 = bp2 + i;
        const float* gm = bng + i * 64;
        const float* bt = bnb + i * 64;
        const float* w1 = bw1 + (size_t)i * 64 * 128;
        const float* b1 = bb1 + i * 128;
        const float* w2 = bw2 + (size_t)i * 128 * 64;
        const float* b2 = bb2 + i * 64;
        float* st = stats + i * 128;

        // stats of prelu(hA16)
        bn_stats_kernel<<<256, 256, 0, stream>>>(hA16, a1, st);
        // t16 = A_hat @ prelu(hA16)   (prelu fused into gather loads)
        gather_kernel<true, false><<<(NN + 15) / 16, 256, 0, stream>>>(
            row_off, csr_ent, dinv, nullptr, a1, hA16, t16);
        // u116 = (sc*t16 + sh*arow) @ w1 + b1   (BN affine commuted past aggregation)
        gemm_kernel<64, 128, 64, 1, false><<<(NN + 63) / 64, 256, 0, stream>>>(
            nullptr, t16, w1, u116, b1, nullptr, st, gm, bt, arow);
        // t16 = prelu(u116) @ w2
        gemm_kernel<128, 64, 128, 2, false><<<(NN + 127) / 128, 256, 0, stream>>>(
            nullptr, u116, w2, t16, nullptr, a2, nullptr, nullptr, nullptr, nullptr);
        // hA16 = A_hat @ t16 + b2
        gather_kernel<false, true><<<(NN + 15) / 16, 256, 0, stream>>>(
            row_off, csr_ent, dinv, b2, nullptr, t16, hA16);
    }

    pool_seg_kernel<<<NG, 256, 0, stream>>>(hA16, batch, pooledg);
    head_stats_kernel<<<1, 64, 0, stream>>>(pooledg, pgamma, pbeta, headsc);
    head_fc_kernel<<<NG, 256, 0, stream>>>(pooledg, headsc, fc1w, fc1b, pprelu,
                                           fc2w, fc2b, (float*)d_out);
}

// Round 7
// 433.677 us; speedup vs baseline: 15.5712x; 1.0255x over previous
//
#include <hip/hip_runtime.h>
#include <hip/hip_fp16.h>

#define NN 50000
#define NE 800000
#define NG 64
#define NC 10
#define BN_EPS 1e-5f
#define NSB 196   // ceil(NN/256)

typedef __attribute__((ext_vector_type(2))) _Float16 h2v;

__device__ __forceinline__ float2 up2(unsigned u) {
    __half2 h = *reinterpret_cast<__half2*>(&u);
    return __half22float2(h);
}
__device__ __forceinline__ unsigned pk2(float a, float b) {
    __half2 h = __floats2half2_rn(a, b);
    return *reinterpret_cast<unsigned*>(&h);
}
__device__ __forceinline__ float fdot2u(unsigned a, unsigned b, float c) {
    return __builtin_amdgcn_fdot2(__builtin_bit_cast(h2v, a), __builtin_bit_cast(h2v, b), c, false);
}

// ---------------- CSR build ----------------

__global__ void deg_count_kernel(const int* __restrict__ dst, int* __restrict__ deg) {
    int e = blockIdx.x * blockDim.x + threadIdx.x;
    if (e < NE) atomicAdd(&deg[dst[e]], 1);
}

__global__ __launch_bounds__(256) void block_sum_kernel(const int* __restrict__ deg,
                                                        int* __restrict__ bsum) {
    int b = blockIdx.x, t = threadIdx.x;
    int n = b * 256 + t;
    int v = (n < NN) ? deg[n] : 0;
    __shared__ int red[256];
    red[t] = v;
    __syncthreads();
    for (int off = 128; off > 0; off >>= 1) {
        if (t < off) red[t] += red[t + off];
        __syncthreads();
    }
    if (t == 0) bsum[b] = red[0];
}

__global__ __launch_bounds__(256) void bsum_scan_kernel(const int* __restrict__ bsum,
                                                        int* __restrict__ boff) {
    __shared__ int s[256];
    int t = threadIdx.x;
    int v = (t < NSB) ? bsum[t] : 0;
    s[t] = v;
    __syncthreads();
    for (int off = 1; off < 256; off <<= 1) {
        int cur = s[t];
        int add = (t >= off) ? s[t - off] : 0;
        __syncthreads();
        s[t] = cur + add;
        __syncthreads();
    }
    if (t < NSB) boff[t] = s[t] - v;
}

__global__ __launch_bounds__(256) void csr_setup_kernel(const int* __restrict__ deg,
                                                        const int* __restrict__ boff,
                                                        int* __restrict__ row_off,
                                                        int* __restrict__ cursor,
                                                        float* __restrict__ dinv,
                                                        float* __restrict__ rdeg) {
    int b = blockIdx.x, t = threadIdx.x;
    int n = b * 256 + t;
    int v = (n < NN) ? deg[n] : 0;
    __shared__ int s[256];
    s[t] = v;
    __syncthreads();
    for (int off = 1; off < 256; off <<= 1) {
        int cur = s[t];
        int add = (t >= off) ? s[t - off] : 0;
        __syncthreads();
        s[t] = cur + add;
        __syncthreads();
    }
    int excl = s[t] - v + boff[b];
    if (n < NN) {
        row_off[n] = excl;
        cursor[n] = excl;
        float d = (float)v + 1.0f;
        dinv[n] = rsqrtf(d);
        rdeg[n] = sqrtf(d);
    }
    if (n == NN - 1) row_off[NN] = NE;
}

__global__ void scatter_csr_kernel(const int* __restrict__ src, const int* __restrict__ dst,
                                   int* __restrict__ cursor, int* __restrict__ csr_src) {
    int e = blockIdx.x * blockDim.x + threadIdx.x;
    if (e >= NE) return;
    int s = src[e];
    int d = dst[e];
    int pos = atomicAdd(&cursor[d], 1);
    csr_src[pos] = s;
}

// arow[n] = dinv[n] * (dinv[n] + sum_e dinv[src_e])  (= row sum of normalized adjacency)
__global__ void arow_kernel(const int* __restrict__ row_off, const int* __restrict__ csr_src,
                            const float* __restrict__ dinv, float* __restrict__ arow) {
    int n = blockIdx.x * 256 + threadIdx.x;
    if (n >= NN) return;
    float dv = dinv[n];
    float s = dv;
    int e0 = row_off[n], e1 = row_off[n + 1];
    for (int i = e0; i < e1; ++i) s += dinv[csr_src[i]];
    arow[n] = dv * s;
}

// ---------------- BN stats over prelu(h_true) where h_true = rdeg * hs ----------------

__global__ __launch_bounds__(256) void bn_stats_kernel(const __half* __restrict__ h,
                                                       const float* __restrict__ rdeg,
                                                       const float* __restrict__ alpha_p,
                                                       float* __restrict__ stats) {
    float alpha = alpha_p[0];
    int tid = threadIdx.x;
    int c4 = (tid & 15) * 4;
    int rg = tid >> 4;
    float sx = 0, sy = 0, sz = 0, sw = 0;
    float qx = 0, qy = 0, qz = 0, qw = 0;
    for (int n = blockIdx.x * 16 + rg; n < NN; n += gridDim.x * 16) {
        float rd = rdeg[n];
        uint2 u = *(const uint2*)&h[(size_t)n * 64 + c4];
        float2 lo = up2(u.x), hi = up2(u.y);
        float a = lo.x >= 0.f ? lo.x : alpha * lo.x;
        float b = lo.y >= 0.f ? lo.y : alpha * lo.y;
        float c = hi.x >= 0.f ? hi.x : alpha * hi.x;
        float d = hi.y >= 0.f ? hi.y : alpha * hi.y;
        a *= rd; b *= rd; c *= rd; d *= rd;
        sx += a; sy += b; sz += c; sw += d;
        qx += a * a; qy += b * b; qz += c * c; qw += d * d;
    }
    __shared__ float ls[256 * 8];
    float* p = &ls[tid * 8];
    p[0] = sx; p[1] = sy; p[2] = sz; p[3] = sw;
    p[4] = qx; p[5] = qy; p[6] = qz; p[7] = qw;
    __syncthreads();
    if (tid < 128) {
        int cidx = tid >> 3;
        int j = tid & 7;
        float acc = 0.f;
        for (int r = 0; r < 16; ++r) acc += ls[(r * 16 + cidx) * 8 + j];
        int ch = cidx * 4 + (j & 3);
        if (j < 4) atomicAdd(&stats[ch], acc);
        else       atomicAdd(&stats[64 + ch], acc);
    }
}

// ---------------- CSR gather, unweighted sum of prescaled rows ----------------
// sum = f(hs[r]) + sum_e f(hs[src_e]);  f = prelu if PRELU (commutes with dinv>0 scaling)
// OUT 0: dv*sum + bias (true scale)   OUT 1: dv*(dv*sum + bias) (prescaled)   OUT 2: dv*sum

template <bool PRELU, int OUT>
__global__ __launch_bounds__(256) void gather_kernel(const int* __restrict__ row_off,
                                                     const int* __restrict__ csr_src,
                                                     const float* __restrict__ dinv,
                                                     const float* __restrict__ bias,
                                                     const float* __restrict__ alpha_p,
                                                     const __half* __restrict__ hh,
                                                     __half* __restrict__ outp) {
    int tid = threadIdx.x;
    int r = blockIdx.x * 16 + (tid >> 4);
    int c = (tid & 15) * 4;
    if (r >= NN) return;
    float alpha = 0.f;
    if constexpr (PRELU) alpha = alpha_p[0];
    uint2 u0 = *(const uint2*)&hh[(size_t)r * 64 + c];
    float2 slo = up2(u0.x), shi = up2(u0.y);
    float ax = slo.x, ay = slo.y, az = shi.x, aw = shi.y;
    if constexpr (PRELU) {
        ax = ax >= 0.f ? ax : alpha * ax;
        ay = ay >= 0.f ? ay : alpha * ay;
        az = az >= 0.f ? az : alpha * az;
        aw = aw >= 0.f ? aw : alpha * aw;
    }
    int beg = row_off[r];
    int end = row_off[r + 1];
    int i = beg;
    for (; i + 3 < end; i += 4) {
        int s0 = csr_src[i], s1 = csr_src[i + 1], s2 = csr_src[i + 2], s3 = csr_src[i + 3];
        uint2 v0 = *(const uint2*)&hh[(size_t)s0 * 64 + c];
        uint2 v1 = *(const uint2*)&hh[(size_t)s1 * 64 + c];
        uint2 v2 = *(const uint2*)&hh[(size_t)s2 * 64 + c];
        uint2 v3 = *(const uint2*)&hh[(size_t)s3 * 64 + c];
        float2 a0 = up2(v0.x), b0 = up2(v0.y);
        float2 a1 = up2(v1.x), b1 = up2(v1.y);
        float2 a2 = up2(v2.x), b2 = up2(v2.y);
        float2 a3 = up2(v3.x), b3 = up2(v3.y);
        if constexpr (PRELU) {
            a0.x = a0.x >= 0.f ? a0.x : alpha * a0.x;  a0.y = a0.y >= 0.f ? a0.y : alpha * a0.y;
            b0.x = b0.x >= 0.f ? b0.x : alpha * b0.x;  b0.y = b0.y >= 0.f ? b0.y : alpha * b0.y;
            a1.x = a1.x >= 0.f ? a1.x : alpha * a1.x;  a1.y = a1.y >= 0.f ? a1.y : alpha * a1.y;
            b1.x = b1.x >= 0.f ? b1.x : alpha * b1.x;  b1.y = b1.y >= 0.f ? b1.y : alpha * b1.y;
            a2.x = a2.x >= 0.f ? a2.x : alpha * a2.x;  a2.y = a2.y >= 0.f ? a2.y : alpha * a2.y;
            b2.x = b2.x >= 0.f ? b2.x : alpha * b2.x;  b2.y = b2.y >= 0.f ? b2.y : alpha * b2.y;
            a3.x = a3.x >= 0.f ? a3.x : alpha * a3.x;  a3.y = a3.y >= 0.f ? a3.y : alpha * a3.y;
            b3.x = b3.x >= 0.f ? b3.x : alpha * b3.x;  b3.y = b3.y >= 0.f ? b3.y : alpha * b3.y;
        }
        ax += (a0.x + a1.x) + (a2.x + a3.x);
        ay += (a0.y + a1.y) + (a2.y + a3.y);
        az += (b0.x + b1.x) + (b2.x + b3.x);
        aw += (b0.y + b1.y) + (b2.y + b3.y);
    }
    for (; i < end; ++i) {
        int s0 = csr_src[i];
        uint2 v0 = *(const uint2*)&hh[(size_t)s0 * 64 + c];
        float2 a0 = up2(v0.x), b0 = up2(v0.y);
        if constexpr (PRELU) {
            a0.x = a0.x >= 0.f ? a0.x : alpha * a0.x;  a0.y = a0.y >= 0.f ? a0.y : alpha * a0.y;
            b0.x = b0.x >= 0.f ? b0.x : alpha * b0.x;  b0.y = b0.y >= 0.f ? b0.y : alpha * b0.y;
        }
        ax += a0.x; ay += a0.y; az += b0.x; aw += b0.y;
    }
    float dv = dinv[r];
    float ox, oy, oz, ow;
    if constexpr (OUT == 2) {
        ox = dv * ax; oy = dv * ay; oz = dv * az; ow = dv * aw;
    } else {
        float4 b = *(const float4*)&bias[c];
        ox = dv * ax + b.x; oy = dv * ay + b.y; oz = dv * az + b.z; ow = dv * aw + b.w;
        if constexpr (OUT == 1) {
            ox *= dv; oy *= dv; oz *= dv; ow *= dv;
        }
    }
    uint2 o;
    o.x = pk2(ox, oy);
    o.y = pk2(oz, ow);
    *(uint2*)&outp[(size_t)r * 64 + c] = o;
}

// ---------------- fp16-dot2 register-tiled GEMM: out16[N,M] = f(A[N,K]) @ W[K,M] (+bias) ----------------
// MODE 0: identity + bias.  MODE 1: (sc*a + sh*arow) + bias.  MODE 2: prelu, no bias.
// SCALEOUT: multiply output row by dinv[row].  4 rows x 8 cols per thread; W,A as half2 along K.

template <int K, int M, int BM, int MODE, bool AF32, bool SCALEOUT>
__global__ __launch_bounds__(256) void gemm_kernel(const float* __restrict__ Af,
                                                   const __half* __restrict__ Ahg,
                                                   const float* __restrict__ W,
                                                   __half* __restrict__ outp,
                                                   const float* __restrict__ bias,
                                                   const float* __restrict__ alpha_p,
                                                   const float* __restrict__ stats,
                                                   const float* __restrict__ gamma,
                                                   const float* __restrict__ beta,
                                                   const float* __restrict__ arow,
                                                   const float* __restrict__ dinv) {
    constexpr int CG = M / 8;
    constexpr int RG = 256 / CG;
    static_assert(BM == 4 * RG, "4 rows per thread");
    constexpr int KP = K / 2;
    constexpr int AP = KP + 2;   // +2 uints pad: keeps 8B align, breaks row-bank aliasing
    __shared__ unsigned Wh[KP * M];
    __shared__ unsigned Ahs[BM][AP];
    __shared__ float scS[64], shS[64];
    int tid = threadIdx.x;
    for (int i = tid; i < KP * M; i += 256) {
        int kp = i / M, j = i % M;
        Wh[i] = pk2(W[(2 * kp) * M + j], W[(2 * kp + 1) * M + j]);
    }
    float alpha = 0.f;
    if constexpr (MODE == 2) alpha = alpha_p[0];
    if constexpr (MODE == 1) {
        if (tid < 64) {
            float mean = stats[tid] * (1.0f / NN);
            float var  = stats[64 + tid] * (1.0f / NN) - mean * mean;
            float sc = gamma[tid] * rsqrtf(var + BN_EPS);
            scS[tid] = sc;
            shS[tid] = beta[tid] - mean * sc;
        }
    }
    __syncthreads();
    int r0 = blockIdx.x * BM;
    for (int i = tid; i < BM * (K / 4); i += 256) {
        int row = i / (K / 4);
        int k4 = (i % (K / 4)) * 4;
        int rr = r0 + row;
        if (rr > NN - 1) rr = NN - 1;
        float4 v;
        if constexpr (AF32) {
            v = *(const float4*)&Af[(size_t)rr * K + k4];
        } else {
            uint2 u = *(const uint2*)&Ahg[(size_t)rr * K + k4];
            float2 lo = up2(u.x), hi = up2(u.y);
            v.x = lo.x; v.y = lo.y; v.z = hi.x; v.w = hi.y;
        }
        if constexpr (MODE == 1) {
            float av = arow[rr];
            v.x = v.x * scS[k4 + 0] + shS[k4 + 0] * av;
            v.y = v.y * scS[k4 + 1] + shS[k4 + 1] * av;
            v.z = v.z * scS[k4 + 2] + shS[k4 + 2] * av;
            v.w = v.w * scS[k4 + 3] + shS[k4 + 3] * av;
        }
        if constexpr (MODE == 2) {
            v.x = v.x >= 0.f ? v.x : alpha * v.x;
            v.y = v.y >= 0.f ? v.y : alpha * v.y;
            v.z = v.z >= 0.f ? v.z : alpha * v.z;
            v.w = v.w >= 0.f ? v.w : alpha * v.w;
        }
        uint2 o;
        o.x = pk2(v.x, v.y);
        o.y = pk2(v.z, v.w);
        *(uint2*)&Ahs[row][k4 >> 1] = o;
    }
    __syncthreads();
    int cg = tid % CG, rg = tid / CG;
    int c = cg * 8;
    float acc[4][8];
#pragma unroll
    for (int r = 0; r < 4; ++r)
#pragma unroll
        for (int j = 0; j < 8; ++j) acc[r][j] = 0.f;
#pragma unroll 4
    for (int kp = 0; kp < KP; kp += 2) {
        uint2 a2[4];
#pragma unroll
        for (int r = 0; r < 4; ++r) a2[r] = *(const uint2*)&Ahs[rg + r * RG][kp];
#pragma unroll
        for (int kk = 0; kk < 2; ++kk) {
            const unsigned* wp = &Wh[(kp + kk) * M + c];
            uint4 w0 = *(const uint4*)wp;
            uint4 w1 = *(const uint4*)(wp + 4);
#pragma unroll
            for (int r = 0; r < 4; ++r) {
                unsigned av = kk ? a2[r].y : a2[r].x;
                acc[r][0] = fdot2u(av, w0.x, acc[r][0]);
                acc[r][1] = fdot2u(av, w0.y, acc[r][1]);
                acc[r][2] = fdot2u(av, w0.z, acc[r][2]);
                acc[r][3] = fdot2u(av, w0.w, acc[r][3]);
                acc[r][4] = fdot2u(av, w1.x, acc[r][4]);
                acc[r][5] = fdot2u(av, w1.y, acc[r][5]);
                acc[r][6] = fdot2u(av, w1.z, acc[r][6]);
                acc[r][7] = fdot2u(av, w1.w, acc[r][7]);
            }
        }
    }
    float bl[8];
#pragma unroll
    for (int j = 0; j < 8; ++j) bl[j] = 0.f;
    if constexpr (MODE == 0 || MODE == 1) {
        float4 b0 = *(const float4*)&bias[c];
        float4 b1 = *(const float4*)&bias[c + 4];
        bl[0] = b0.x; bl[1] = b0.y; bl[2] = b0.z; bl[3] = b0.w;
        bl[4] = b1.x; bl[5] = b1.y; bl[6] = b1.z; bl[7] = b1.w;
    }
#pragma unroll
    for (int r = 0; r < 4; ++r) {
        int row = r0 + rg + r * RG;
        if (row < NN) {
            float sc = 1.0f;
            if constexpr (SCALEOUT) sc = dinv[row];
            uint4 o;
            o.x = pk2((acc[r][0] + bl[0]) * sc, (acc[r][1] + bl[1]) * sc);
            o.y = pk2((acc[r][2] + bl[2]) * sc, (acc[r][3] + bl[3]) * sc);
            o.z = pk2((acc[r][4] + bl[4]) * sc, (acc[r][5] + bl[5]) * sc);
            o.w = pk2((acc[r][6] + bl[6]) * sc, (acc[r][7] + bl[7]) * sc);
            *(uint4*)&outp[(size_t)row * M + c] = o;
        }
    }
}

// ---------------- pool: one block per graph (batch sorted), fp16 in, f32 out ----------------

__global__ __launch_bounds__(256) void pool_seg_kernel(const __half* __restrict__ h,
                                                       const int* __restrict__ batch,
                                                       float* __restrict__ pooled) {
    int g = blockIdx.x;
    __shared__ int sbeg, send;
    int tid = threadIdx.x;
    if (tid == 0) {
        int lo = 0, hi = NN;
        while (lo < hi) { int mid = (lo + hi) >> 1; if (batch[mid] < g) lo = mid + 1; else hi = mid; }
        sbeg = lo;
        lo = 0; hi = NN;
        while (lo < hi) { int mid = (lo + hi) >> 1; if (batch[mid] < g + 1) lo = mid + 1; else hi = mid; }
        send = lo;
    }
    __syncthreads();
    int beg = sbeg, end = send;
    int c4 = (tid & 15) * 4;
    int rg = tid >> 4;
    float sx = 0, sy = 0, sz = 0, sw = 0;
    for (int n = beg + rg; n < end; n += 16) {
        uint2 u = *(const uint2*)&h[(size_t)n * 64 + c4];
        float2 lo = up2(u.x), hi = up2(u.y);
        sx += lo.x; sy += lo.y; sz += hi.x; sw += hi.y;
    }
    __shared__ float red[256 * 4];
    float* p = &red[tid * 4];
    p[0] = sx; p[1] = sy; p[2] = sz; p[3] = sw;
    __syncthreads();
    if (tid < 64) {
        int cg = tid >> 2;
        int j = tid & 3;
        float acc = 0.f;
        for (int r = 0; r < 16; ++r) acc += red[(r * 16 + cg) * 4 + j];
        float cnt = fmaxf((float)(end - beg), 1.0f);
        pooled[g * 64 + cg * 4 + j] = acc / cnt;
    }
}

// ---------------- head ----------------

__global__ __launch_bounds__(64) void head_stats_kernel(const float* __restrict__ pooled,
                                                        const float* __restrict__ gamma,
                                                        const float* __restrict__ beta,
                                                        float* __restrict__ headsc) {
    int ch = threadIdx.x;
    float s = 0.f, q = 0.f;
    for (int g = 0; g < 64; ++g) {
        float v = pooled[g * 64 + ch];
        s += v; q += v * v;
    }
    float mean = s * (1.0f / 64.0f);
    float var = q * (1.0f / 64.0f) - mean * mean;
    float sc = gamma[ch] * rsqrtf(var + BN_EPS);
    headsc[ch] = sc;
    headsc[64 + ch] = beta[ch] - mean * sc;
}

__global__ __launch_bounds__(256) void head_fc_kernel(const float* __restrict__ pooled,
                                                      const float* __restrict__ headsc,
                                                      const float* __restrict__ fc1w,
                                                      const float* __restrict__ fc1b,
                                                      const float* __restrict__ prelu_p,
                                                      const float* __restrict__ fc2w,
                                                      const float* __restrict__ fc2b,
                                                      float* __restrict__ out) {
    int g = blockIdx.x;
    int tid = threadIdx.x;
    __shared__ float pr[64];
    __shared__ float red[256];
    if (tid < 64) pr[tid] = pooled[g * 64 + tid] * headsc[tid] + headsc[64 + tid];
    __syncthreads();
    float alpha = prelu_p[0];
    float o1 = fc1b[tid];
    for (int k = 0; k < 64; ++k) o1 += pr[k] * fc1w[k * 256 + tid];
    o1 = o1 >= 0.f ? o1 : alpha * o1;
    for (int c = 0; c < NC; ++c) {
        red[tid] = o1 * fc2w[tid * NC + c];
        __syncthreads();
        for (int off = 128; off > 0; off >>= 1) {
            if (tid < off) red[tid] += red[tid + off];
            __syncthreads();
        }
        if (tid == 0) out[g * NC + c] = red[0] + fc2b[c];
        __syncthreads();
    }
}

// ---------------- launch ----------------

extern "C" void kernel_launch(void* const* d_in, const int* in_sizes, int n_in,
                              void* d_out, int out_size, void* d_ws, size_t ws_size,
                              hipStream_t stream) {
    const float* x       = (const float*)d_in[0];
    const int*   ei      = (const int*)d_in[1];
    const int*   batch   = (const int*)d_in[2];
    const float* pre_w   = (const float*)d_in[3];
    const float* pre_b   = (const float*)d_in[4];
    const float* bp1     = (const float*)d_in[5];
    const float* bng     = (const float*)d_in[6];
    const float* bnb     = (const float*)d_in[7];
    const float* bw1     = (const float*)d_in[8];
    const float* bb1     = (const float*)d_in[9];
    const float* bp2     = (const float*)d_in[10];
    const float* bw2     = (const float*)d_in[11];
    const float* bb2     = (const float*)d_in[12];
    const float* pgamma  = (const float*)d_in[13];
    const float* pbeta   = (const float*)d_in[14];
    const float* fc1w    = (const float*)d_in[15];
    const float* fc1b    = (const float*)d_in[16];
    const float* pprelu  = (const float*)d_in[17];
    const float* fc2w    = (const float*)d_in[18];
    const float* fc2b    = (const float*)d_in[19];

    const int* src = ei;
    const int* dst = ei + NE;

    __half* hA16 = (__half*)d_ws;                      // [NN,64]  prescaled (hs)
    __half* u116 = hA16 + (size_t)NN * 64;             // [NN,128]
    __half* t16  = u116 + (size_t)NN * 128;            // [NN,64]
    float* dinv  = (float*)(t16 + (size_t)NN * 64);    // [NN]
    float* rdeg  = dinv + NN;                          // [NN]
    float* arow  = rdeg + NN;                          // [NN]
    float* stats = arow + NN;                          // [3*128] (zeroed)
    float* pooledg = stats + 3 * 128;                  // [64*64]
    float* headsc  = pooledg + 64 * 64;                // [128]
    int*   csr_src = (int*)(headsc + 128);             // [NE]
    int*   row_off = csr_src + NE;                     // [NN+1]
    int*   cursor  = row_off + NN + 1;                 // [NN]
    int*   deg     = cursor + NN;                      // [NN] (zeroed)
    int*   bsum    = deg + NN;                         // [NSB]
    int*   boff    = bsum + NSB;                       // [NSB]

    hipMemsetAsync(stats, 0, (size_t)3 * 128 * 4, stream);
    hipMemsetAsync(deg, 0, (size_t)NN * 4, stream);

    deg_count_kernel<<<(NE + 255) / 256, 256, 0, stream>>>(dst, deg);
    block_sum_kernel<<<NSB, 256, 0, stream>>>(deg, bsum);
    bsum_scan_kernel<<<1, 256, 0, stream>>>(bsum, boff);
    csr_setup_kernel<<<NSB, 256, 0, stream>>>(deg, boff, row_off, cursor, dinv, rdeg);
    scatter_csr_kernel<<<(NE + 255) / 256, 256, 0, stream>>>(src, dst, cursor, csr_src);
    arow_kernel<<<(NN + 255) / 256, 256, 0, stream>>>(row_off, csr_src, dinv, arow);

    // pre-linear: hA16 = dinv * (x @ pre_w + pre_b)   [NN,64]
    gemm_kernel<64, 64, 128, 0, true, true><<<(NN + 127) / 128, 256, 0, stream>>>(
        x, nullptr, pre_w, hA16, pre_b, nullptr, nullptr, nullptr, nullptr, nullptr, dinv);

    for (int i = 0; i < 3; ++i) {
        const float* a1 = bp1 + i;
        const float* a2 = bp2 + i;
        const float* gm = bng + i * 64;
        const float* bt = bnb + i * 64;
        const float* w1 = bw1 + (size_t)i * 64 * 128;
        const float* b1 = bb1 + i * 128;
        const float* w2 = bw2 + (size_t)i * 128 * 64;
        const float* b2 = bb2 + i * 64;
        float* st = stats + i * 128;

        bn_stats_kernel<<<256, 256, 0, stream>>>(hA16, rdeg, a1, st);
        // t16 = A_hat @ prelu(h)  (true scale; unweighted sum of prescaled rows)
        gather_kernel<true, 2><<<(NN + 15) / 16, 256, 0, stream>>>(
            row_off, csr_src, dinv, nullptr, a1, hA16, t16);
        // u116 = (sc*t16 + sh*arow) @ w1 + b1
        gemm_kernel<64, 128, 64, 1, false, false><<<(NN + 63) / 64, 256, 0, stream>>>(
            nullptr, t16, w1, u116, b1, nullptr, st, gm, bt, arow, nullptr);
        // t16 = dinv * (prelu(u116) @ w2)   (prescaled for next gather)
        gemm_kernel<128, 64, 128, 2, false, true><<<(NN + 127) / 128, 256, 0, stream>>>(
            nullptr, u116, w2, t16, nullptr, a2, nullptr, nullptr, nullptr, nullptr, dinv);
        // hA16 = A_hat @ t16 + b2  (prescaled except last block)
        if (i < 2) {
            gather_kernel<false, 1><<<(NN + 15) / 16, 256, 0, stream>>>(
                row_off, csr_src, dinv, b2, nullptr, t16, hA16);
        } else {
            gather_kernel<false, 0><<<(NN + 15) / 16, 256, 0, stream>>>(
                row_off, csr_src, dinv, b2, nullptr, t16, hA16);
        }
    }

    pool_seg_kernel<<<NG, 256, 0, stream>>>(hA16, batch, pooledg);
    head_stats_kernel<<<1, 64, 0, stream>>>(pooledg, pgamma, pbeta, headsc);
    head_fc_kernel<<<NG, 256, 0, stream>>>(pooledg, headsc, fc1w, fc1b, pprelu,
                                           fc2w, fc2b, (float*)d_out);
}

// Round 8
// 424.419 us; speedup vs baseline: 15.9109x; 1.0218x over previous
//
#include <hip/hip_runtime.h>
#include <hip/hip_fp16.h>

#define NN 50000
#define NE 800000
#define NG 64
#define NC 10
#define BN_EPS 1e-5f
#define NSB 196   // ceil(NN/256)

typedef __attribute__((ext_vector_type(2))) _Float16 h2v;

__device__ __forceinline__ float2 up2(unsigned u) {
    __half2 h = *reinterpret_cast<__half2*>(&u);
    return __half22float2(h);
}
__device__ __forceinline__ unsigned pk2(float a, float b) {
    __half2 h = __floats2half2_rn(a, b);
    return *reinterpret_cast<unsigned*>(&h);
}
__device__ __forceinline__ float fdot2u(unsigned a, unsigned b, float c) {
    return __builtin_amdgcn_fdot2(__builtin_bit_cast(h2v, a), __builtin_bit_cast(h2v, b), c, false);
}

// ---------------- CSR build ----------------

// pass 1: count degree AND record each edge's slot within its bucket
__global__ void deg_count_kernel(const int* __restrict__ dst, int* __restrict__ deg,
                                 unsigned short* __restrict__ pos16) {
    int e = blockIdx.x * blockDim.x + threadIdx.x;
    if (e < NE) {
        int d = __builtin_nontemporal_load(&dst[e]);
        unsigned short p = (unsigned short)atomicAdd(&deg[d], 1);
        __builtin_nontemporal_store(p, &pos16[e]);
    }
}

__global__ __launch_bounds__(256) void block_sum_kernel(const int* __restrict__ deg,
                                                        int* __restrict__ bsum) {
    int b = blockIdx.x, t = threadIdx.x;
    int n = b * 256 + t;
    int v = (n < NN) ? deg[n] : 0;
    __shared__ int red[256];
    red[t] = v;
    __syncthreads();
    for (int off = 128; off > 0; off >>= 1) {
        if (t < off) red[t] += red[t + off];
        __syncthreads();
    }
    if (t == 0) bsum[b] = red[0];
}

__global__ __launch_bounds__(256) void bsum_scan_kernel(const int* __restrict__ bsum,
                                                        int* __restrict__ boff) {
    __shared__ int s[256];
    int t = threadIdx.x;
    int v = (t < NSB) ? bsum[t] : 0;
    s[t] = v;
    __syncthreads();
    for (int off = 1; off < 256; off <<= 1) {
        int cur = s[t];
        int add = (t >= off) ? s[t - off] : 0;
        __syncthreads();
        s[t] = cur + add;
        __syncthreads();
    }
    if (t < NSB) boff[t] = s[t] - v;
}

__global__ __launch_bounds__(256) void csr_setup_kernel(const int* __restrict__ deg,
                                                        const int* __restrict__ boff,
                                                        int* __restrict__ row_off,
                                                        float* __restrict__ dinv,
                                                        float* __restrict__ rdeg) {
    int b = blockIdx.x, t = threadIdx.x;
    int n = b * 256 + t;
    int v = (n < NN) ? deg[n] : 0;
    __shared__ int s[256];
    s[t] = v;
    __syncthreads();
    for (int off = 1; off < 256; off <<= 1) {
        int cur = s[t];
        int add = (t >= off) ? s[t - off] : 0;
        __syncthreads();
        s[t] = cur + add;
        __syncthreads();
    }
    int excl = s[t] - v + boff[b];
    if (n < NN) {
        row_off[n] = excl;
        float d = (float)v + 1.0f;
        dinv[n] = rsqrtf(d);
        rdeg[n] = sqrtf(d);
    }
    if (n == NN - 1) row_off[NN] = NE;
}

// pass 2: atomic-free placement; streams bypass L2 so dirty scatter lines stay resident
__global__ void scatter_csr_kernel(const int* __restrict__ src, const int* __restrict__ dst,
                                   const unsigned short* __restrict__ pos16,
                                   const int* __restrict__ row_off,
                                   int* __restrict__ csr_src) {
    int e = blockIdx.x * blockDim.x + threadIdx.x;
    if (e >= NE) return;
    int s = __builtin_nontemporal_load(&src[e]);
    int d = __builtin_nontemporal_load(&dst[e]);
    int p = (int)__builtin_nontemporal_load(&pos16[e]);
    csr_src[row_off[d] + p] = s;
}

// arow[n] = dinv[n] * (dinv[n] + sum_e dinv[src_e])
__global__ void arow_kernel(const int* __restrict__ row_off, const int* __restrict__ csr_src,
                            const float* __restrict__ dinv, float* __restrict__ arow) {
    int n = blockIdx.x * 256 + threadIdx.x;
    if (n >= NN) return;
    float dv = dinv[n];
    float s = dv;
    int e0 = row_off[n], e1 = row_off[n + 1];
    for (int i = e0; i < e1; ++i) s += dinv[csr_src[i]];
    arow[n] = dv * s;
}

// ---------------- BN stats over prelu(h_true) where h_true = rdeg * hs ----------------

__global__ __launch_bounds__(256) void bn_stats_kernel(const __half* __restrict__ h,
                                                       const float* __restrict__ rdeg,
                                                       const float* __restrict__ alpha_p,
                                                       float* __restrict__ stats) {
    float alpha = alpha_p[0];
    int tid = threadIdx.x;
    int c4 = (tid & 15) * 4;
    int rg = tid >> 4;
    float sx = 0, sy = 0, sz = 0, sw = 0;
    float qx = 0, qy = 0, qz = 0, qw = 0;
    for (int n = blockIdx.x * 16 + rg; n < NN; n += gridDim.x * 16) {
        float rd = rdeg[n];
        uint2 u = *(const uint2*)&h[(size_t)n * 64 + c4];
        float2 lo = up2(u.x), hi = up2(u.y);
        float a = lo.x >= 0.f ? lo.x : alpha * lo.x;
        float b = lo.y >= 0.f ? lo.y : alpha * lo.y;
        float c = hi.x >= 0.f ? hi.x : alpha * hi.x;
        float d = hi.y >= 0.f ? hi.y : alpha * hi.y;
        a *= rd; b *= rd; c *= rd; d *= rd;
        sx += a; sy += b; sz += c; sw += d;
        qx += a * a; qy += b * b; qz += c * c; qw += d * d;
    }
    __shared__ float ls[256 * 8];
    float* p = &ls[tid * 8];
    p[0] = sx; p[1] = sy; p[2] = sz; p[3] = sw;
    p[4] = qx; p[5] = qy; p[6] = qz; p[7] = qw;
    __syncthreads();
    if (tid < 128) {
        int cidx = tid >> 3;
        int j = tid & 7;
        float acc = 0.f;
        for (int r = 0; r < 16; ++r) acc += ls[(r * 16 + cidx) * 8 + j];
        int ch = cidx * 4 + (j & 3);
        if (j < 4) atomicAdd(&stats[ch], acc);
        else       atomicAdd(&stats[64 + ch], acc);
    }
}

// ---------------- CSR gather, channel-half blocked (32 ch per pass, L2-resident footprint) ----------------
// 32 rows/block, 8 lanes/row, 8B/lane = one 64B line per edge.
// sum = f(hs[r]) + sum_e f(hs[src_e]);  f = prelu if PRELU
// OUT 0: dv*sum + bias   OUT 1: dv*(dv*sum + bias)   OUT 2: dv*sum

template <bool PRELU, int OUT>
__global__ __launch_bounds__(256) void gather_kernel(const int* __restrict__ row_off,
                                                     const int* __restrict__ csr_src,
                                                     const float* __restrict__ dinv,
                                                     const float* __restrict__ bias,
                                                     const float* __restrict__ alpha_p,
                                                     const __half* __restrict__ hh,
                                                     __half* __restrict__ outp) {
    int tid = threadIdx.x;
    int r = blockIdx.x * 32 + (tid >> 3);
    int c = blockIdx.y * 32 + (tid & 7) * 4;
    if (r >= NN) return;
    float alpha = 0.f;
    if constexpr (PRELU) alpha = alpha_p[0];
    uint2 u0 = *(const uint2*)&hh[(size_t)r * 64 + c];
    float2 slo = up2(u0.x), shi = up2(u0.y);
    float ax = slo.x, ay = slo.y, az = shi.x, aw = shi.y;
    if constexpr (PRELU) {
        ax = ax >= 0.f ? ax : alpha * ax;
        ay = ay >= 0.f ? ay : alpha * ay;
        az = az >= 0.f ? az : alpha * az;
        aw = aw >= 0.f ? aw : alpha * aw;
    }
    int beg = row_off[r];
    int end = row_off[r + 1];
    int i = beg;
    for (; i + 3 < end; i += 4) {
        int s0 = csr_src[i], s1 = csr_src[i + 1], s2 = csr_src[i + 2], s3 = csr_src[i + 3];
        uint2 v0 = *(const uint2*)&hh[(size_t)s0 * 64 + c];
        uint2 v1 = *(const uint2*)&hh[(size_t)s1 * 64 + c];
        uint2 v2 = *(const uint2*)&hh[(size_t)s2 * 64 + c];
        uint2 v3 = *(const uint2*)&hh[(size_t)s3 * 64 + c];
        float2 a0 = up2(v0.x), b0 = up2(v0.y);
        float2 a1 = up2(v1.x), b1 = up2(v1.y);
        float2 a2 = up2(v2.x), b2 = up2(v2.y);
        float2 a3 = up2(v3.x), b3 = up2(v3.y);
        if constexpr (PRELU) {
            a0.x = a0.x >= 0.f ? a0.x : alpha * a0.x;  a0.y = a0.y >= 0.f ? a0.y : alpha * a0.y;
            b0.x = b0.x >= 0.f ? b0.x : alpha * b0.x;  b0.y = b0.y >= 0.f ? b0.y : alpha * b0.y;
            a1.x = a1.x >= 0.f ? a1.x : alpha * a1.x;  a1.y = a1.y >= 0.f ? a1.y : alpha * a1.y;
            b1.x = b1.x >= 0.f ? b1.x : alpha * b1.x;  b1.y = b1.y >= 0.f ? b1.y : alpha * b1.y;
            a2.x = a2.x >= 0.f ? a2.x : alpha * a2.x;  a2.y = a2.y >= 0.f ? a2.y : alpha * a2.y;
            b2.x = b2.x >= 0.f ? b2.x : alpha * b2.x;  b2.y = b2.y >= 0.f ? b2.y : alpha * b2.y;
            a3.x = a3.x >= 0.f ? a3.x : alpha * a3.x;  a3.y = a3.y >= 0.f ? a3.y : alpha * a3.y;
            b3.x = b3.x >= 0.f ? b3.x : alpha * b3.x;  b3.y = b3.y >= 0.f ? b3.y : alpha * b3.y;
        }
        ax += (a0.x + a1.x) + (a2.x + a3.x);
        ay += (a0.y + a1.y) + (a2.y + a3.y);
        az += (b0.x + b1.x) + (b2.x + b3.x);
        aw += (b0.y + b1.y) + (b2.y + b3.y);
    }
    for (; i < end; ++i) {
        int s0 = csr_src[i];
        uint2 v0 = *(const uint2*)&hh[(size_t)s0 * 64 + c];
        float2 a0 = up2(v0.x), b0 = up2(v0.y);
        if constexpr (PRELU) {
            a0.x = a0.x >= 0.f ? a0.x : alpha * a0.x;  a0.y = a0.y >= 0.f ? a0.y : alpha * a0.y;
            b0.x = b0.x >= 0.f ? b0.x : alpha * b0.x;  b0.y = b0.y >= 0.f ? b0.y : alpha * b0.y;
        }
        ax += a0.x; ay += a0.y; az += b0.x; aw += b0.y;
    }
    float dv = dinv[r];
    float ox, oy, oz, ow;
    if constexpr (OUT == 2) {
        ox = dv * ax; oy = dv * ay; oz = dv * az; ow = dv * aw;
    } else {
        float4 b = *(const float4*)&bias[c];
        ox = dv * ax + b.x; oy = dv * ay + b.y; oz = dv * az + b.z; ow = dv * aw + b.w;
        if constexpr (OUT == 1) {
            ox *= dv; oy *= dv; oz *= dv; ow *= dv;
        }
    }
    uint2 o;
    o.x = pk2(ox, oy);
    o.y = pk2(oz, ow);
    *(uint2*)&outp[(size_t)r * 64 + c] = o;
}

// ---------------- pre-linear GEMM (f32 A): out16 = dinv * (x @ W + bias) ----------------

__global__ __launch_bounds__(256) void gemm_pre_kernel(const float* __restrict__ Af,
                                                       const float* __restrict__ W,
                                                       __half* __restrict__ outp,
                                                       const float* __restrict__ bias,
                                                       const float* __restrict__ dinv) {
    constexpr int K = 64, M = 64, BM = 128;
    constexpr int CG = M / 8;        // 8
    constexpr int RG = 256 / CG;     // 32
    constexpr int KP = K / 2;
    __shared__ unsigned Wh[KP * M];
    __shared__ unsigned Ahs[BM][KP + 4];
    int tid = threadIdx.x;
    for (int i = tid; i < KP * M; i += 256) {
        int kp = i / M, j = i % M;
        Wh[i] = pk2(W[(2 * kp) * M + j], W[(2 * kp + 1) * M + j]);
    }
    int r0 = blockIdx.x * BM;
    for (int i = tid; i < BM * (K / 4); i += 256) {
        int row = i / (K / 4);
        int k4 = (i % (K / 4)) * 4;
        int rr = r0 + row;
        if (rr > NN - 1) rr = NN - 1;
        float4 v = *(const float4*)&Af[(size_t)rr * K + k4];
        uint2 o;
        o.x = pk2(v.x, v.y);
        o.y = pk2(v.z, v.w);
        *(uint2*)&Ahs[row][k4 >> 1] = o;
    }
    __syncthreads();
    int cg = tid % CG, rg = tid / CG;
    int c = cg * 8;
    float acc[4][8];
#pragma unroll
    for (int r = 0; r < 4; ++r)
#pragma unroll
        for (int j = 0; j < 8; ++j) acc[r][j] = 0.f;
#pragma unroll 4
    for (int kp = 0; kp < KP; kp += 2) {
        uint2 a2[4];
#pragma unroll
        for (int r = 0; r < 4; ++r) a2[r] = *(const uint2*)&Ahs[rg + r * RG][kp];
#pragma unroll
        for (int kk = 0; kk < 2; ++kk) {
            const unsigned* wp = &Wh[(kp + kk) * M + c];
            uint4 w0 = *(const uint4*)wp;
            uint4 w1 = *(const uint4*)(wp + 4);
#pragma unroll
            for (int r = 0; r < 4; ++r) {
                unsigned av = kk ? a2[r].y : a2[r].x;
                acc[r][0] = fdot2u(av, w0.x, acc[r][0]);
                acc[r][1] = fdot2u(av, w0.y, acc[r][1]);
                acc[r][2] = fdot2u(av, w0.z, acc[r][2]);
                acc[r][3] = fdot2u(av, w0.w, acc[r][3]);
                acc[r][4] = fdot2u(av, w1.x, acc[r][4]);
                acc[r][5] = fdot2u(av, w1.y, acc[r][5]);
                acc[r][6] = fdot2u(av, w1.z, acc[r][6]);
                acc[r][7] = fdot2u(av, w1.w, acc[r][7]);
            }
        }
    }
    float4 b0 = *(const float4*)&bias[c];
    float4 b1 = *(const float4*)&bias[c + 4];
#pragma unroll
    for (int r = 0; r < 4; ++r) {
        int row = r0 + rg + r * RG;
        if (row < NN) {
            float sc = dinv[row];
            uint4 o;
            o.x = pk2((acc[r][0] + b0.x) * sc, (acc[r][1] + b0.y) * sc);
            o.y = pk2((acc[r][2] + b0.z) * sc, (acc[r][3] + b0.w) * sc);
            o.z = pk2((acc[r][4] + b1.x) * sc, (acc[r][5] + b1.y) * sc);
            o.w = pk2((acc[r][6] + b1.z) * sc, (acc[r][7] + b1.w) * sc);
            *(uint4*)&outp[(size_t)row * M + c] = o;
        }
    }
}

// ---------------- fused block MLP: t <- dinv * ( prelu( (sc*t + sh*arow) @ W1 + b1 ) @ W2 ) ----------------
// In-place on t16 (each block reads/writes only its own 64 rows).

__global__ __launch_bounds__(256) void gemm12_kernel(__half* __restrict__ t,
                                                     const float* __restrict__ W1,
                                                     const float* __restrict__ b1,
                                                     const float* __restrict__ W2,
                                                     const float* __restrict__ alpha2_p,
                                                     const float* __restrict__ stats,
                                                     const float* __restrict__ gamma,
                                                     const float* __restrict__ beta,
                                                     const float* __restrict__ arow,
                                                     const float* __restrict__ dinv) {
    constexpr int BM = 64;
    __shared__ unsigned W1h[32 * 128];     // [kp][j]
    __shared__ unsigned W2h[64 * 64];      // [kp][j]
    __shared__ unsigned Ahs[BM][36];       // [row][kp], 32 + 4 pad
    __shared__ unsigned Uh[BM][68];        // [row][kp], 64 + 4 pad
    __shared__ float scS[64], shS[64];
    int tid = threadIdx.x;
    for (int i = tid; i < 32 * 128; i += 256) {
        int kp = i >> 7, j = i & 127;
        W1h[i] = pk2(W1[(2 * kp) * 128 + j], W1[(2 * kp + 1) * 128 + j]);
    }
    for (int i = tid; i < 64 * 64; i += 256) {
        int kp = i >> 6, j = i & 63;
        W2h[i] = pk2(W2[(2 * kp) * 64 + j], W2[(2 * kp + 1) * 64 + j]);
    }
    if (tid < 64) {
        float mean = stats[tid] * (1.0f / NN);
        float var  = stats[64 + tid] * (1.0f / NN) - mean * mean;
        float sc = gamma[tid] * rsqrtf(var + BN_EPS);
        scS[tid] = sc;
        shS[tid] = beta[tid] - mean * sc;
    }
    __syncthreads();
    int r0 = blockIdx.x * BM;
    // stage A with BN-commuted transform
    for (int i = tid; i < BM * 16; i += 256) {
        int row = i >> 4;
        int k4 = (i & 15) * 4;
        int rr = r0 + row;
        if (rr > NN - 1) rr = NN - 1;
        uint2 u = *(const uint2*)&t[(size_t)rr * 64 + k4];
        float2 lo = up2(u.x), hi = up2(u.y);
        float av = arow[rr];
        float vx = lo.x * scS[k4 + 0] + shS[k4 + 0] * av;
        float vy = lo.y * scS[k4 + 1] + shS[k4 + 1] * av;
        float vz = hi.x * scS[k4 + 2] + shS[k4 + 2] * av;
        float vw = hi.y * scS[k4 + 3] + shS[k4 + 3] * av;
        uint2 o;
        o.x = pk2(vx, vy);
        o.y = pk2(vz, vw);
        *(uint2*)&Ahs[row][k4 >> 1] = o;
    }
    __syncthreads();
    // phase 2: U = prelu(A @ W1 + b1)   [64 x 128]
    {
        int cg = tid & 15;     // 16 col groups x 8 cols
        int rg = tid >> 4;     // 16 row groups x 4 rows
        int c = cg * 8;
        float acc[4][8];
#pragma unroll
        for (int r = 0; r < 4; ++r)
#pragma unroll
            for (int j = 0; j < 8; ++j) acc[r][j] = 0.f;
#pragma unroll 4
        for (int kp = 0; kp < 32; kp += 2) {
            uint2 a2[4];
#pragma unroll
            for (int r = 0; r < 4; ++r) a2[r] = *(const uint2*)&Ahs[rg + r * 16][kp];
#pragma unroll
            for (int kk = 0; kk < 2; ++kk) {
                const unsigned* wp = &W1h[(kp + kk) * 128 + c];
                uint4 w0 = *(const uint4*)wp;
                uint4 w1 = *(const uint4*)(wp + 4);
#pragma unroll
                for (int r = 0; r < 4; ++r) {
                    unsigned av = kk ? a2[r].y : a2[r].x;
                    acc[r][0] = fdot2u(av, w0.x, acc[r][0]);
                    acc[r][1] = fdot2u(av, w0.y, acc[r][1]);
                    acc[r][2] = fdot2u(av, w0.z, acc[r][2]);
                    acc[r][3] = fdot2u(av, w0.w, acc[r][3]);
                    acc[r][4] = fdot2u(av, w1.x, acc[r][4]);
                    acc[r][5] = fdot2u(av, w1.y, acc[r][5]);
                    acc[r][6] = fdot2u(av, w1.z, acc[r][6]);
                    acc[r][7] = fdot2u(av, w1.w, acc[r][7]);
                }
            }
        }
        float alpha = alpha2_p[0];
        float4 bb0 = *(const float4*)&b1[c];
        float4 bb1 = *(const float4*)&b1[c + 4];
        float bl[8] = {bb0.x, bb0.y, bb0.z, bb0.w, bb1.x, bb1.y, bb1.z, bb1.w};
#pragma unroll
        for (int r = 0; r < 4; ++r) {
            int row = rg + r * 16;
            float o[8];
#pragma unroll
            for (int j = 0; j < 8; ++j) {
                float v = acc[r][j] + bl[j];
                o[j] = v >= 0.f ? v : alpha * v;
            }
            uint4 w;
            w.x = pk2(o[0], o[1]);
            w.y = pk2(o[2], o[3]);
            w.z = pk2(o[4], o[5]);
            w.w = pk2(o[6], o[7]);
            *(uint4*)&Uh[row][c >> 1] = w;
        }
    }
    __syncthreads();
    // phase 3: t = dinv * (U @ W2)   [64 x 64]
    {
        int cg2 = tid & 7;     // 8 col groups x 8 cols
        int rg2 = tid >> 3;    // 32 row groups x 2 rows
        int c2 = cg2 * 8;
        float acc[2][8];
#pragma unroll
        for (int r = 0; r < 2; ++r)
#pragma unroll
            for (int j = 0; j < 8; ++j) acc[r][j] = 0.f;
#pragma unroll 4
        for (int kp = 0; kp < 64; kp += 2) {
            uint2 a2[2];
#pragma unroll
            for (int r = 0; r < 2; ++r) a2[r] = *(const uint2*)&Uh[rg2 + r * 32][kp];
#pragma unroll
            for (int kk = 0; kk < 2; ++kk) {
                const unsigned* wp = &W2h[(kp + kk) * 64 + c2];
                uint4 w0 = *(const uint4*)wp;
                uint4 w1 = *(const uint4*)(wp + 4);
#pragma unroll
                for (int r = 0; r < 2; ++r) {
                    unsigned av = kk ? a2[r].y : a2[r].x;
                    acc[r][0] = fdot2u(av, w0.x, acc[r][0]);
                    acc[r][1] = fdot2u(av, w0.y, acc[r][1]);
                    acc[r][2] = fdot2u(av, w0.z, acc[r][2]);
                    acc[r][3] = fdot2u(av, w0.w, acc[r][3]);
                    acc[r][4] = fdot2u(av, w1.x, acc[r][4]);
                    acc[r][5] = fdot2u(av, w1.y, acc[r][5]);
                    acc[r][6] = fdot2u(av, w1.z, acc[r][6]);
                    acc[r][7] = fdot2u(av, w1.w, acc[r][7]);
                }
            }
        }
#pragma unroll
        for (int r = 0; r < 2; ++r) {
            int row = r0 + rg2 + r * 32;
            if (row < NN) {
                float sc = dinv[row];
                uint4 o;
                o.x = pk2(acc[r][0] * sc, acc[r][1] * sc);
                o.y = pk2(acc[r][2] * sc, acc[r][3] * sc);
                o.z = pk2(acc[r][4] * sc, acc[r][5] * sc);
                o.w = pk2(acc[r][6] * sc, acc[r][7] * sc);
                *(uint4*)&t[(size_t)row * 64 + c2] = o;
            }
        }
    }
}

// ---------------- pool: one block per graph (batch sorted), fp16 in, f32 out ----------------

__global__ __launch_bounds__(256) void pool_seg_kernel(const __half* __restrict__ h,
                                                       const int* __restrict__ batch,
                                                       float* __restrict__ pooled) {
    int g = blockIdx.x;
    __shared__ int sbeg, send;
    int tid = threadIdx.x;
    if (tid == 0) {
        int lo = 0, hi = NN;
        while (lo < hi) { int mid = (lo + hi) >> 1; if (batch[mid] < g) lo = mid + 1; else hi = mid; }
        sbeg = lo;
        lo = 0; hi = NN;
        while (lo < hi) { int mid = (lo + hi) >> 1; if (batch[mid] < g + 1) lo = mid + 1; else hi = mid; }
        send = lo;
    }
    __syncthreads();
    int beg = sbeg, end = send;
    int c4 = (tid & 15) * 4;
    int rg = tid >> 4;
    float sx = 0, sy = 0, sz = 0, sw = 0;
    for (int n = beg + rg; n < end; n += 16) {
        uint2 u = *(const uint2*)&h[(size_t)n * 64 + c4];
        float2 lo = up2(u.x), hi = up2(u.y);
        sx += lo.x; sy += lo.y; sz += hi.x; sw += hi.y;
    }
    __shared__ float red[256 * 4];
    float* p = &red[tid * 4];
    p[0] = sx; p[1] = sy; p[2] = sz; p[3] = sw;
    __syncthreads();
    if (tid < 64) {
        int cg = tid >> 2;
        int j = tid & 3;
        float acc = 0.f;
        for (int r = 0; r < 16; ++r) acc += red[(r * 16 + cg) * 4 + j];
        float cnt = fmaxf((float)(end - beg), 1.0f);
        pooled[g * 64 + cg * 4 + j] = acc / cnt;
    }
}

// ---------------- head ----------------

__global__ __launch_bounds__(64) void head_stats_kernel(const float* __restrict__ pooled,
                                                        const float* __restrict__ gamma,
                                                        const float* __restrict__ beta,
                                                        float* __restrict__ headsc) {
    int ch = threadIdx.x;
    float s = 0.f, q = 0.f;
    for (int g = 0; g < 64; ++g) {
        float v = pooled[g * 64 + ch];
        s += v; q += v * v;
    }
    float mean = s * (1.0f / 64.0f);
    float var = q * (1.0f / 64.0f) - mean * mean;
    float sc = gamma[ch] * rsqrtf(var + BN_EPS);
    headsc[ch] = sc;
    headsc[64 + ch] = beta[ch] - mean * sc;
}

__global__ __launch_bounds__(256) void head_fc_kernel(const float* __restrict__ pooled,
                                                      const float* __restrict__ headsc,
                                                      const float* __restrict__ fc1w,
                                                      const float* __restrict__ fc1b,
                                                      const float* __restrict__ prelu_p,
                                                      const float* __restrict__ fc2w,
                                                      const float* __restrict__ fc2b,
                                                      float* __restrict__ out) {
    int g = blockIdx.x;
    int tid = threadIdx.x;
    __shared__ float pr[64];
    __shared__ float red[256];
    if (tid < 64) pr[tid] = pooled[g * 64 + tid] * headsc[tid] + headsc[64 + tid];
    __syncthreads();
    float alpha = prelu_p[0];
    float o1 = fc1b[tid];
    for (int k = 0; k < 64; ++k) o1 += pr[k] * fc1w[k * 256 + tid];
    o1 = o1 >= 0.f ? o1 : alpha * o1;
    for (int c = 0; c < NC; ++c) {
        red[tid] = o1 * fc2w[tid * NC + c];
        __syncthreads();
        for (int off = 128; off > 0; off >>= 1) {
            if (tid < off) red[tid] += red[tid + off];
            __syncthreads();
        }
        if (tid == 0) out[g * NC + c] = red[0] + fc2b[c];
        __syncthreads();
    }
}

// ---------------- launch ----------------

extern "C" void kernel_launch(void* const* d_in, const int* in_sizes, int n_in,
                              void* d_out, int out_size, void* d_ws, size_t ws_size,
                              hipStream_t stream) {
    const float* x       = (const float*)d_in[0];
    const int*   ei      = (const int*)d_in[1];
    const int*   batch   = (const int*)d_in[2];
    const float* pre_w   = (const float*)d_in[3];
    const float* pre_b   = (const float*)d_in[4];
    const float* bp1     = (const float*)d_in[5];
    const float* bng     = (const float*)d_in[6];
    const float* bnb     = (const float*)d_in[7];
    const float* bw1     = (const float*)d_in[8];
    const float* bb1     = (const float*)d_in[9];
    const float* bp2     = (const float*)d_in[10];
    const float* bw2     = (const float*)d_in[11];
    const float* bb2     = (const float*)d_in[12];
    const float* pgamma  = (const float*)d_in[13];
    const float* pbeta   = (const float*)d_in[14];
    const float* fc1w    = (const float*)d_in[15];
    const float* fc1b    = (const float*)d_in[16];
    const float* pprelu  = (const float*)d_in[17];
    const float* fc2w    = (const float*)d_in[18];
    const float* fc2b    = (const float*)d_in[19];

    const int* src = ei;
    const int* dst = ei + NE;

    __half* hA16 = (__half*)d_ws;                      // [NN,64] prescaled (hs)
    __half* t16  = hA16 + (size_t)NN * 64;             // [NN,64]
    float* dinv  = (float*)(t16 + (size_t)NN * 64);    // [NN]
    float* rdeg  = dinv + NN;                          // [NN]
    float* arow  = rdeg + NN;                          // [NN]
    float* stats = arow + NN;                          // [3*128] (zeroed)
    float* pooledg = stats + 3 * 128;                  // [64*64]
    float* headsc  = pooledg + 64 * 64;                // [128]
    int*   csr_src = (int*)(headsc + 128);             // [NE]
    int*   row_off = csr_src + NE;                     // [NN+1]
    int*   deg     = row_off + NN + 1;                 // [NN] (zeroed)
    int*   bsum    = deg + NN;                         // [NSB]
    int*   boff    = bsum + NSB;                       // [NSB]
    unsigned short* pos16 = (unsigned short*)(boff + NSB);   // [NE]

    hipMemsetAsync(stats, 0, (size_t)3 * 128 * 4, stream);
    hipMemsetAsync(deg, 0, (size_t)NN * 4, stream);

    deg_count_kernel<<<(NE + 255) / 256, 256, 0, stream>>>(dst, deg, pos16);
    block_sum_kernel<<<NSB, 256, 0, stream>>>(deg, bsum);
    bsum_scan_kernel<<<1, 256, 0, stream>>>(bsum, boff);
    csr_setup_kernel<<<NSB, 256, 0, stream>>>(deg, boff, row_off, dinv, rdeg);
    scatter_csr_kernel<<<(NE + 255) / 256, 256, 0, stream>>>(src, dst, pos16, row_off, csr_src);
    arow_kernel<<<(NN + 255) / 256, 256, 0, stream>>>(row_off, csr_src, dinv, arow);

    // pre-linear: hA16 = dinv * (x @ pre_w + pre_b)
    gemm_pre_kernel<<<(NN + 127) / 128, 256, 0, stream>>>(x, pre_w, hA16, pre_b, dinv);

    dim3 ggrid((NN + 31) / 32, 2);
    for (int i = 0; i < 3; ++i) {
        const float* a1 = bp1 + i;
        const float* a2 = bp2 + i;
        const float* gm = bng + i * 64;
        const float* bt = bnb + i * 64;
        const float* w1 = bw1 + (size_t)i * 64 * 128;
        const float* b1 = bb1 + i * 128;
        const float* w2 = bw2 + (size_t)i * 128 * 64;
        const float* b2 = bb2 + i * 64;
        float* st = stats + i * 128;

        bn_stats_kernel<<<256, 256, 0, stream>>>(hA16, rdeg, a1, st);
        // t16 = A_hat @ prelu(h)  (true scale)
        gather_kernel<true, 2><<<ggrid, 256, 0, stream>>>(
            row_off, csr_src, dinv, nullptr, a1, hA16, t16);
        // t16 <- dinv * ( prelu( BN'(t16) @ w1 + b1 ) @ w2 )   (fused, in place)
        gemm12_kernel<<<(NN + 63) / 64, 256, 0, stream>>>(
            t16, w1, b1, w2, a2, st, gm, bt, arow, dinv);
        // hA16 = A_hat @ t16 + b2  (prescaled except last block)
        if (i < 2) {
            gather_kernel<false, 1><<<ggrid, 256, 0, stream>>>(
                row_off, csr_src, dinv, b2, nullptr, t16, hA16);
        } else {
            gather_kernel<false, 0><<<ggrid, 256, 0, stream>>>(
                row_off, csr_src, dinv, b2, nullptr, t16, hA16);
        }
    }

    pool_seg_kernel<<<NG, 256, 0, stream>>>(hA16, batch, pooledg);
    head_stats_kernel<<<1, 64, 0, stream>>>(pooledg, pgamma, pbeta, headsc);
    head_fc_kernel<<<NG, 256, 0, stream>>>(pooledg, headsc, fc1w, fc1b, pprelu,
                                           fc2w, fc2b, (float*)d_out);
}

// Round 9
// 402.529 us; speedup vs baseline: 16.7761x; 1.0544x over previous
//
#include <hip/hip_runtime.h>
#include <hip/hip_fp16.h>

#define NN 50000
#define NE 800000
#define NG 64
#define NC 10
#define BN_EPS 1e-5f
#define NSB 196   // ceil(NN/256)

typedef __attribute__((ext_vector_type(2))) _Float16 h2v;
typedef __attribute__((ext_vector_type(8))) _Float16 f16x8;
typedef __attribute__((ext_vector_type(4))) float f32x4;

__device__ __forceinline__ float2 up2(unsigned u) {
    __half2 h = *reinterpret_cast<__half2*>(&u);
    return __half22float2(h);
}
__device__ __forceinline__ unsigned pk2(float a, float b) {
    __half2 h = __floats2half2_rn(a, b);
    return *reinterpret_cast<unsigned*>(&h);
}
__device__ __forceinline__ float fdot2u(unsigned a, unsigned b, float c) {
    return __builtin_amdgcn_fdot2(__builtin_bit_cast(h2v, a), __builtin_bit_cast(h2v, b), c, false);
}

// ---------------- CSR build ----------------

__global__ void deg_count_kernel(const int* __restrict__ dst, int* __restrict__ deg,
                                 unsigned short* __restrict__ pos16) {
    int e = blockIdx.x * blockDim.x + threadIdx.x;
    if (e < NE) {
        int d = __builtin_nontemporal_load(&dst[e]);
        unsigned short p = (unsigned short)atomicAdd(&deg[d], 1);
        __builtin_nontemporal_store(p, &pos16[e]);
    }
}

__global__ __launch_bounds__(256) void block_sum_kernel(const int* __restrict__ deg,
                                                        int* __restrict__ bsum) {
    int b = blockIdx.x, t = threadIdx.x;
    int n = b * 256 + t;
    int v = (n < NN) ? deg[n] : 0;
    __shared__ int red[256];
    red[t] = v;
    __syncthreads();
    for (int off = 128; off > 0; off >>= 1) {
        if (t < off) red[t] += red[t + off];
        __syncthreads();
    }
    if (t == 0) bsum[b] = red[0];
}

__global__ __launch_bounds__(256) void bsum_scan_kernel(const int* __restrict__ bsum,
                                                        int* __restrict__ boff) {
    __shared__ int s[256];
    int t = threadIdx.x;
    int v = (t < NSB) ? bsum[t] : 0;
    s[t] = v;
    __syncthreads();
    for (int off = 1; off < 256; off <<= 1) {
        int cur = s[t];
        int add = (t >= off) ? s[t - off] : 0;
        __syncthreads();
        s[t] = cur + add;
        __syncthreads();
    }
    if (t < NSB) boff[t] = s[t] - v;
}

__global__ __launch_bounds__(256) void csr_setup_kernel(const int* __restrict__ deg,
                                                        const int* __restrict__ boff,
                                                        int* __restrict__ row_off,
                                                        float* __restrict__ dinv,
                                                        float* __restrict__ rdeg) {
    int b = blockIdx.x, t = threadIdx.x;
    int n = b * 256 + t;
    int v = (n < NN) ? deg[n] : 0;
    __shared__ int s[256];
    s[t] = v;
    __syncthreads();
    for (int off = 1; off < 256; off <<= 1) {
        int cur = s[t];
        int add = (t >= off) ? s[t - off] : 0;
        __syncthreads();
        s[t] = cur + add;
        __syncthreads();
    }
    int excl = s[t] - v + boff[b];
    if (n < NN) {
        row_off[n] = excl;
        float d = (float)v + 1.0f;
        dinv[n] = rsqrtf(d);
        rdeg[n] = sqrtf(d);
    }
    if (n == NN - 1) row_off[NN] = NE;
}

__global__ void scatter_csr_kernel(const int* __restrict__ src, const int* __restrict__ dst,
                                   const unsigned short* __restrict__ pos16,
                                   const int* __restrict__ row_off,
                                   int* __restrict__ csr_src) {
    int e = blockIdx.x * blockDim.x + threadIdx.x;
    if (e >= NE) return;
    int s = __builtin_nontemporal_load(&src[e]);
    int d = __builtin_nontemporal_load(&dst[e]);
    int p = (int)__builtin_nontemporal_load(&pos16[e]);
    csr_src[row_off[d] + p] = s;
}

// arow[n] = dinv[n] * (dinv[n] + sum_e dinv[src_e])
__global__ void arow_kernel(const int* __restrict__ row_off, const int* __restrict__ csr_src,
                            const float* __restrict__ dinv, float* __restrict__ arow) {
    int n = blockIdx.x * 256 + threadIdx.x;
    if (n >= NN) return;
    float dv = dinv[n];
    float s = dv;
    int e0 = row_off[n], e1 = row_off[n + 1];
    for (int i = e0; i < e1; ++i) s += dinv[csr_src[i]];
    arow[n] = dv * s;
}

// ---------------- BN stats over prelu(h_true) where h_true = rdeg * hs ----------------

__global__ __launch_bounds__(256) void bn_stats_kernel(const __half* __restrict__ h,
                                                       const float* __restrict__ rdeg,
                                                       const float* __restrict__ alpha_p,
                                                       float* __restrict__ stats) {
    float alpha = alpha_p[0];
    int tid = threadIdx.x;
    int c4 = (tid & 15) * 4;
    int rg = tid >> 4;
    float sx = 0, sy = 0, sz = 0, sw = 0;
    float qx = 0, qy = 0, qz = 0, qw = 0;
    for (int n = blockIdx.x * 16 + rg; n < NN; n += gridDim.x * 16) {
        float rd = rdeg[n];
        uint2 u = *(const uint2*)&h[(size_t)n * 64 + c4];
        float2 lo = up2(u.x), hi = up2(u.y);
        float a = lo.x >= 0.f ? lo.x : alpha * lo.x;
        float b = lo.y >= 0.f ? lo.y : alpha * lo.y;
        float c = hi.x >= 0.f ? hi.x : alpha * hi.x;
        float d = hi.y >= 0.f ? hi.y : alpha * hi.y;
        a *= rd; b *= rd; c *= rd; d *= rd;
        sx += a; sy += b; sz += c; sw += d;
        qx += a * a; qy += b * b; qz += c * c; qw += d * d;
    }
    __shared__ float ls[256 * 8];
    float* p = &ls[tid * 8];
    p[0] = sx; p[1] = sy; p[2] = sz; p[3] = sw;
    p[4] = qx; p[5] = qy; p[6] = qz; p[7] = qw;
    __syncthreads();
    if (tid < 128) {
        int cidx = tid >> 3;
        int j = tid & 7;
        float acc = 0.f;
        for (int r = 0; r < 16; ++r) acc += ls[(r * 16 + cidx) * 8 + j];
        int ch = cidx * 4 + (j & 3);
        if (j < 4) atomicAdd(&stats[ch], acc);
        else       atomicAdd(&stats[64 + ch], acc);
    }
}

// ---------------- CSR gather, channel-half blocked ----------------
// OUT 0: dv*sum + bias   OUT 1: dv*(dv*sum + bias)   OUT 2: dv*sum

template <bool PRELU, int OUT>
__global__ __launch_bounds__(256) void gather_kernel(const int* __restrict__ row_off,
                                                     const int* __restrict__ csr_src,
                                                     const float* __restrict__ dinv,
                                                     const float* __restrict__ bias,
                                                     const float* __restrict__ alpha_p,
                                                     const __half* __restrict__ hh,
                                                     __half* __restrict__ outp) {
    int tid = threadIdx.x;
    int r = blockIdx.x * 32 + (tid >> 3);
    int c = blockIdx.y * 32 + (tid & 7) * 4;
    if (r >= NN) return;
    float alpha = 0.f;
    if constexpr (PRELU) alpha = alpha_p[0];
    uint2 u0 = *(const uint2*)&hh[(size_t)r * 64 + c];
    float2 slo = up2(u0.x), shi = up2(u0.y);
    float ax = slo.x, ay = slo.y, az = shi.x, aw = shi.y;
    if constexpr (PRELU) {
        ax = ax >= 0.f ? ax : alpha * ax;
        ay = ay >= 0.f ? ay : alpha * ay;
        az = az >= 0.f ? az : alpha * az;
        aw = aw >= 0.f ? aw : alpha * aw;
    }
    int beg = row_off[r];
    int end = row_off[r + 1];
    int i = beg;
    for (; i + 3 < end; i += 4) {
        int s0 = csr_src[i], s1 = csr_src[i + 1], s2 = csr_src[i + 2], s3 = csr_src[i + 3];
        uint2 v0 = *(const uint2*)&hh[(size_t)s0 * 64 + c];
        uint2 v1 = *(const uint2*)&hh[(size_t)s1 * 64 + c];
        uint2 v2 = *(const uint2*)&hh[(size_t)s2 * 64 + c];
        uint2 v3 = *(const uint2*)&hh[(size_t)s3 * 64 + c];
        float2 a0 = up2(v0.x), b0 = up2(v0.y);
        float2 a1 = up2(v1.x), b1 = up2(v1.y);
        float2 a2 = up2(v2.x), b2 = up2(v2.y);
        float2 a3 = up2(v3.x), b3 = up2(v3.y);
        if constexpr (PRELU) {
            a0.x = a0.x >= 0.f ? a0.x : alpha * a0.x;  a0.y = a0.y >= 0.f ? a0.y : alpha * a0.y;
            b0.x = b0.x >= 0.f ? b0.x : alpha * b0.x;  b0.y = b0.y >= 0.f ? b0.y : alpha * b0.y;
            a1.x = a1.x >= 0.f ? a1.x : alpha * a1.x;  a1.y = a1.y >= 0.f ? a1.y : alpha * a1.y;
            b1.x = b1.x >= 0.f ? b1.x : alpha * b1.x;  b1.y = b1.y >= 0.f ? b1.y : alpha * b1.y;
            a2.x = a2.x >= 0.f ? a2.x : alpha * a2.x;  a2.y = a2.y >= 0.f ? a2.y : alpha * a2.y;
            b2.x = b2.x >= 0.f ? b2.x : alpha * b2.x;  b2.y = b2.y >= 0.f ? b2.y : alpha * b2.y;
            a3.x = a3.x >= 0.f ? a3.x : alpha * a3.x;  a3.y = a3.y >= 0.f ? a3.y : alpha * a3.y;
            b3.x = b3.x >= 0.f ? b3.x : alpha * b3.x;  b3.y = b3.y >= 0.f ? b3.y : alpha * b3.y;
        }
        ax += (a0.x + a1.x) + (a2.x + a3.x);
        ay += (a0.y + a1.y) + (a2.y + a3.y);
        az += (b0.x + b1.x) + (b2.x + b3.x);
        aw += (b0.y + b1.y) + (b2.y + b3.y);
    }
    for (; i < end; ++i) {
        int s0 = csr_src[i];
        uint2 v0 = *(const uint2*)&hh[(size_t)s0 * 64 + c];
        float2 a0 = up2(v0.x), b0 = up2(v0.y);
        if constexpr (PRELU) {
            a0.x = a0.x >= 0.f ? a0.x : alpha * a0.x;  a0.y = a0.y >= 0.f ? a0.y : alpha * a0.y;
            b0.x = b0.x >= 0.f ? b0.x : alpha * b0.x;  b0.y = b0.y >= 0.f ? b0.y : alpha * b0.y;
        }
        ax += a0.x; ay += a0.y; az += b0.x; aw += b0.y;
    }
    float dv = dinv[r];
    float ox, oy, oz, ow;
    if constexpr (OUT == 2) {
        ox = dv * ax; oy = dv * ay; oz = dv * az; ow = dv * aw;
    } else {
        float4 b = *(const float4*)&bias[c];
        ox = dv * ax + b.x; oy = dv * ay + b.y; oz = dv * az + b.z; ow = dv * aw + b.w;
        if constexpr (OUT == 1) {
            ox *= dv; oy *= dv; oz *= dv; ow *= dv;
        }
    }
    uint2 o;
    o.x = pk2(ox, oy);
    o.y = pk2(oz, ow);
    *(uint2*)&outp[(size_t)r * 64 + c] = o;
}

// ---------------- pre-linear GEMM (f32 A): out16 = dinv * (x @ W + bias) ----------------

__global__ __launch_bounds__(256) void gemm_pre_kernel(const float* __restrict__ Af,
                                                       const float* __restrict__ W,
                                                       __half* __restrict__ outp,
                                                       const float* __restrict__ bias,
                                                       const float* __restrict__ dinv) {
    constexpr int K = 64, M = 64, BM = 128;
    constexpr int CG = M / 8;
    constexpr int RG = 256 / CG;
    constexpr int KP = K / 2;
    __shared__ unsigned Wh[KP * M];
    __shared__ unsigned Ahs[BM][KP + 4];
    int tid = threadIdx.x;
    for (int i = tid; i < KP * M; i += 256) {
        int kp = i / M, j = i % M;
        Wh[i] = pk2(W[(2 * kp) * M + j], W[(2 * kp + 1) * M + j]);
    }
    int r0 = blockIdx.x * BM;
    for (int i = tid; i < BM * (K / 4); i += 256) {
        int row = i / (K / 4);
        int k4 = (i % (K / 4)) * 4;
        int rr = r0 + row;
        if (rr > NN - 1) rr = NN - 1;
        float4 v = *(const float4*)&Af[(size_t)rr * K + k4];
        uint2 o;
        o.x = pk2(v.x, v.y);
        o.y = pk2(v.z, v.w);
        *(uint2*)&Ahs[row][k4 >> 1] = o;
    }
    __syncthreads();
    int cg = tid % CG, rg = tid / CG;
    int c = cg * 8;
    float acc[4][8];
#pragma unroll
    for (int r = 0; r < 4; ++r)
#pragma unroll
        for (int j = 0; j < 8; ++j) acc[r][j] = 0.f;
#pragma unroll 4
    for (int kp = 0; kp < KP; kp += 2) {
        uint2 a2[4];
#pragma unroll
        for (int r = 0; r < 4; ++r) a2[r] = *(const uint2*)&Ahs[rg + r * RG][kp];
#pragma unroll
        for (int kk = 0; kk < 2; ++kk) {
            const unsigned* wp = &Wh[(kp + kk) * M + c];
            uint4 w0 = *(const uint4*)wp;
            uint4 w1 = *(const uint4*)(wp + 4);
#pragma unroll
            for (int r = 0; r < 4; ++r) {
                unsigned av = kk ? a2[r].y : a2[r].x;
                acc[r][0] = fdot2u(av, w0.x, acc[r][0]);
                acc[r][1] = fdot2u(av, w0.y, acc[r][1]);
                acc[r][2] = fdot2u(av, w0.z, acc[r][2]);
                acc[r][3] = fdot2u(av, w0.w, acc[r][3]);
                acc[r][4] = fdot2u(av, w1.x, acc[r][4]);
                acc[r][5] = fdot2u(av, w1.y, acc[r][5]);
                acc[r][6] = fdot2u(av, w1.z, acc[r][6]);
                acc[r][7] = fdot2u(av, w1.w, acc[r][7]);
            }
        }
    }
    float4 b0 = *(const float4*)&bias[c];
    float4 b1 = *(const float4*)&bias[c + 4];
#pragma unroll
    for (int r = 0; r < 4; ++r) {
        int row = r0 + rg + r * RG;
        if (row < NN) {
            float sc = dinv[row];
            uint4 o;
            o.x = pk2((acc[r][0] + b0.x) * sc, (acc[r][1] + b0.y) * sc);
            o.y = pk2((acc[r][2] + b0.z) * sc, (acc[r][3] + b0.w) * sc);
            o.z = pk2((acc[r][4] + b1.x) * sc, (acc[r][5] + b1.y) * sc);
            o.w = pk2((acc[r][6] + b1.z) * sc, (acc[r][7] + b1.w) * sc);
            *(uint4*)&outp[(size_t)row * M + c] = o;
        }
    }
}

// ---------------- MFMA GEMM 1: u[N,128] = BN'(t[N,64]) @ W1 + b1 ----------------
// A-frag: row = l&15, k = (l>>4)*8 + j (contiguous 8).  B-frag: same with W^T.
// D: col = l&15, row = (l>>4)*4 + reg.   [verified layout, learn_hip m89/m97]

__global__ __launch_bounds__(256) void mfma_gemm1_kernel(const __half* __restrict__ t,
                                                         const float* __restrict__ W1,
                                                         const float* __restrict__ b1,
                                                         __half* __restrict__ u,
                                                         const float* __restrict__ stats,
                                                         const float* __restrict__ gamma,
                                                         const float* __restrict__ beta,
                                                         const float* __restrict__ arow) {
    __shared__ _Float16 At[128][72];   // 64 + 8 pad (row stride 144B ≡ 4 banks → 2-way, free)
    __shared__ _Float16 Wt[128][72];   // Wt[col][k]
    __shared__ float scS[64], shS[64];
    int tid = threadIdx.x;
    if (tid < 64) {
        float mean = stats[tid] * (1.0f / NN);
        float var  = stats[64 + tid] * (1.0f / NN) - mean * mean;
        float sc = gamma[tid] * rsqrtf(var + BN_EPS);
        scS[tid] = sc;
        shS[tid] = beta[tid] - mean * sc;
    }
    // stage W1^T as fp16 pairs
    for (int i = tid; i < 128 * 32; i += 256) {
        int j = i & 127;
        int k2 = i >> 7;
        *(unsigned*)&Wt[j][2 * k2] = pk2(W1[(2 * k2) * 128 + j], W1[(2 * k2 + 1) * 128 + j]);
    }
    __syncthreads();
    int r0 = blockIdx.x * 128;
    for (int i = tid; i < 128 * 16; i += 256) {
        int row = i >> 4;
        int k4 = (i & 15) * 4;
        int rr = r0 + row;
        if (rr > NN - 1) rr = NN - 1;
        uint2 uu = *(const uint2*)&t[(size_t)rr * 64 + k4];
        float2 lo = up2(uu.x), hi = up2(uu.y);
        float av = arow[rr];
        float vx = lo.x * scS[k4 + 0] + shS[k4 + 0] * av;
        float vy = lo.y * scS[k4 + 1] + shS[k4 + 1] * av;
        float vz = hi.x * scS[k4 + 2] + shS[k4 + 2] * av;
        float vw = hi.y * scS[k4 + 3] + shS[k4 + 3] * av;
        *(unsigned*)&At[row][k4]     = pk2(vx, vy);
        *(unsigned*)&At[row][k4 + 2] = pk2(vz, vw);
    }
    __syncthreads();
    int w = tid >> 6;
    int l = tid & 63;
    int lr = l & 15;
    int lk = (l >> 4) * 8;
    f32x4 acc[2][8];
#pragma unroll
    for (int rt = 0; rt < 2; ++rt)
#pragma unroll
        for (int ct = 0; ct < 8; ++ct) acc[rt][ct] = (f32x4){0.f, 0.f, 0.f, 0.f};
#pragma unroll
    for (int k0 = 0; k0 < 64; k0 += 32) {
        f16x8 a0 = *(const f16x8*)&At[w * 32 + lr][k0 + lk];
        f16x8 a1 = *(const f16x8*)&At[w * 32 + 16 + lr][k0 + lk];
#pragma unroll
        for (int ct = 0; ct < 8; ++ct) {
            f16x8 b = *(const f16x8*)&Wt[ct * 16 + lr][k0 + lk];
            acc[0][ct] = __builtin_amdgcn_mfma_f32_16x16x32_f16(a0, b, acc[0][ct], 0, 0, 0);
            acc[1][ct] = __builtin_amdgcn_mfma_f32_16x16x32_f16(a1, b, acc[1][ct], 0, 0, 0);
        }
    }
    int rowbase = r0 + w * 32 + (l >> 4) * 4;
#pragma unroll
    for (int rt = 0; rt < 2; ++rt) {
#pragma unroll
        for (int ct = 0; ct < 8; ++ct) {
            int col = ct * 16 + lr;
            float bb = b1[col];
#pragma unroll
            for (int r = 0; r < 4; ++r) {
                int row = rowbase + rt * 16 + r;
                if (row < NN) u[(size_t)row * 128 + col] = __float2half(acc[rt][ct][r] + bb);
            }
        }
    }
}

// ---------------- MFMA GEMM 2: t[N,64] = dinv * (prelu(u[N,128]) @ W2) ----------------

__global__ __launch_bounds__(256) void mfma_gemm2_kernel(const __half* __restrict__ u,
                                                         const float* __restrict__ W2,
                                                         const float* __restrict__ alpha_p,
                                                         const float* __restrict__ dinv,
                                                         __half* __restrict__ t) {
    __shared__ _Float16 Ut[64][136];   // 128 + 8 pad
    __shared__ _Float16 Wt[64][136];   // Wt[col][k]
    int tid = threadIdx.x;
    float alpha = alpha_p[0];
    for (int i = tid; i < 64 * 64; i += 256) {
        int j = i & 63;
        int k2 = i >> 6;
        *(unsigned*)&Wt[j][2 * k2] = pk2(W2[(2 * k2) * 64 + j], W2[(2 * k2 + 1) * 64 + j]);
    }
    int r0 = blockIdx.x * 64;
    for (int i = tid; i < 64 * 32; i += 256) {
        int row = i >> 5;
        int k4 = (i & 31) * 4;
        int rr = r0 + row;
        if (rr > NN - 1) rr = NN - 1;
        uint2 uu = *(const uint2*)&u[(size_t)rr * 128 + k4];
        float2 lo = up2(uu.x), hi = up2(uu.y);
        float vx = lo.x >= 0.f ? lo.x : alpha * lo.x;
        float vy = lo.y >= 0.f ? lo.y : alpha * lo.y;
        float vz = hi.x >= 0.f ? hi.x : alpha * hi.x;
        float vw = hi.y >= 0.f ? hi.y : alpha * hi.y;
        *(unsigned*)&Ut[row][k4]     = pk2(vx, vy);
        *(unsigned*)&Ut[row][k4 + 2] = pk2(vz, vw);
    }
    __syncthreads();
    int w = tid >> 6;
    int l = tid & 63;
    int lr = l & 15;
    int lk = (l >> 4) * 8;
    f32x4 acc[4];
#pragma unroll
    for (int ct = 0; ct < 4; ++ct) acc[ct] = (f32x4){0.f, 0.f, 0.f, 0.f};
#pragma unroll
    for (int k0 = 0; k0 < 128; k0 += 32) {
        f16x8 a = *(const f16x8*)&Ut[w * 16 + lr][k0 + lk];
#pragma unroll
        for (int ct = 0; ct < 4; ++ct) {
            f16x8 b = *(const f16x8*)&Wt[ct * 16 + lr][k0 + lk];
            acc[ct] = __builtin_amdgcn_mfma_f32_16x16x32_f16(a, b, acc[ct], 0, 0, 0);
        }
    }
    int rowbase = r0 + w * 16 + (l >> 4) * 4;
#pragma unroll
    for (int ct = 0; ct < 4; ++ct) {
        int col = ct * 16 + lr;
#pragma unroll
        for (int r = 0; r < 4; ++r) {
            int row = rowbase + r;
            if (row < NN) t[(size_t)row * 64 + col] = __float2half(acc[ct][r] * dinv[row]);
        }
    }
}

// ---------------- pool: one block per graph (batch sorted), fp16 in, f32 out ----------------

__global__ __launch_bounds__(256) void pool_seg_kernel(const __half* __restrict__ h,
                                                       const int* __restrict__ batch,
                                                       float* __restrict__ pooled) {
    int g = blockIdx.x;
    __shared__ int sbeg, send;
    int tid = threadIdx.x;
    if (tid == 0) {
        int lo = 0, hi = NN;
        while (lo < hi) { int mid = (lo + hi) >> 1; if (batch[mid] < g) lo = mid + 1; else hi = mid; }
        sbeg = lo;
        lo = 0; hi = NN;
        while (lo < hi) { int mid = (lo + hi) >> 1; if (batch[mid] < g + 1) lo = mid + 1; else hi = mid; }
        send = lo;
    }
    __syncthreads();
    int beg = sbeg, end = send;
    int c4 = (tid & 15) * 4;
    int rg = tid >> 4;
    float sx = 0, sy = 0, sz = 0, sw = 0;
    for (int n = beg + rg; n < end; n += 16) {
        uint2 u = *(const uint2*)&h[(size_t)n * 64 + c4];
        float2 lo = up2(u.x), hi = up2(u.y);
        sx += lo.x; sy += lo.y; sz += hi.x; sw += hi.y;
    }
    __shared__ float red[256 * 4];
    float* p = &red[tid * 4];
    p[0] = sx; p[1] = sy; p[2] = sz; p[3] = sw;
    __syncthreads();
    if (tid < 64) {
        int cg = tid >> 2;
        int j = tid & 3;
        float acc = 0.f;
        for (int r = 0; r < 16; ++r) acc += red[(r * 16 + cg) * 4 + j];
        float cnt = fmaxf((float)(end - beg), 1.0f);
        pooled[g * 64 + cg * 4 + j] = acc / cnt;
    }
}

// ---------------- head ----------------

__global__ __launch_bounds__(64) void head_stats_kernel(const float* __restrict__ pooled,
                                                        const float* __restrict__ gamma,
                                                        const float* __restrict__ beta,
                                                        float* __restrict__ headsc) {
    int ch = threadIdx.x;
    float s = 0.f, q = 0.f;
    for (int g = 0; g < 64; ++g) {
        float v = pooled[g * 64 + ch];
        s += v; q += v * v;
    }
    float mean = s * (1.0f / 64.0f);
    float var = q * (1.0f / 64.0f) - mean * mean;
    float sc = gamma[ch] * rsqrtf(var + BN_EPS);
    headsc[ch] = sc;
    headsc[64 + ch] = beta[ch] - mean * sc;
}

__global__ __launch_bounds__(256) void head_fc_kernel(const float* __restrict__ pooled,
                                                      const float* __restrict__ headsc,
                                                      const float* __restrict__ fc1w,
                                                      const float* __restrict__ fc1b,
                                                      const float* __restrict__ prelu_p,
                                                      const float* __restrict__ fc2w,
                                                      const float* __restrict__ fc2b,
                                                      float* __restrict__ out) {
    int g = blockIdx.x;
    int tid = threadIdx.x;
    __shared__ float pr[64];
    __shared__ float red[256];
    if (tid < 64) pr[tid] = pooled[g * 64 + tid] * headsc[tid] + headsc[64 + tid];
    __syncthreads();
    float alpha = prelu_p[0];
    float o1 = fc1b[tid];
    for (int k = 0; k < 64; ++k) o1 += pr[k] * fc1w[k * 256 + tid];
    o1 = o1 >= 0.f ? o1 : alpha * o1;
    for (int c = 0; c < NC; ++c) {
        red[tid] = o1 * fc2w[tid * NC + c];
        __syncthreads();
        for (int off = 128; off > 0; off >>= 1) {
            if (tid < off) red[tid] += red[tid + off];
            __syncthreads();
        }
        if (tid == 0) out[g * NC + c] = red[0] + fc2b[c];
        __syncthreads();
    }
}

// ---------------- launch ----------------

extern "C" void kernel_launch(void* const* d_in, const int* in_sizes, int n_in,
                              void* d_out, int out_size, void* d_ws, size_t ws_size,
                              hipStream_t stream) {
    const float* x       = (const float*)d_in[0];
    const int*   ei      = (const int*)d_in[1];
    const int*   batch   = (const int*)d_in[2];
    const float* pre_w   = (const float*)d_in[3];
    const float* pre_b   = (const float*)d_in[4];
    const float* bp1     = (const float*)d_in[5];
    const float* bng     = (const float*)d_in[6];
    const float* bnb     = (const float*)d_in[7];
    const float* bw1     = (const float*)d_in[8];
    const float* bb1     = (const float*)d_in[9];
    const float* bp2     = (const float*)d_in[10];
    const float* bw2     = (const float*)d_in[11];
    const float* bb2     = (const float*)d_in[12];
    const float* pgamma  = (const float*)d_in[13];
    const float* pbeta   = (const float*)d_in[14];
    const float* fc1w    = (const float*)d_in[15];
    const float* fc1b    = (const float*)d_in[16];
    const float* pprelu  = (const float*)d_in[17];
    const float* fc2w    = (const float*)d_in[18];
    const float* fc2b    = (const float*)d_in[19];

    const int* src = ei;
    const int* dst = ei + NE;

    __half* hA16 = (__half*)d_ws;                      // [NN,64] prescaled (hs)
    __half* t16  = hA16 + (size_t)NN * 64;             // [NN,64]
    __half* u16  = t16 + (size_t)NN * 64;              // [NN,128]
    float* dinv  = (float*)(u16 + (size_t)NN * 128);   // [NN]
    float* rdeg  = dinv + NN;                          // [NN]
    float* arow  = rdeg + NN;                          // [NN]
    float* stats = arow + NN;                          // [3*128] (zeroed)
    float* pooledg = stats + 3 * 128;                  // [64*64]
    float* headsc  = pooledg + 64 * 64;                // [128]
    int*   csr_src = (int*)(headsc + 128);             // [NE]
    int*   row_off = csr_src + NE;                     // [NN+1]
    int*   deg     = row_off + NN + 1;                 // [NN] (zeroed)
    int*   bsum    = deg + NN;                         // [NSB]
    int*   boff    = bsum + NSB;                       // [NSB]
    unsigned short* pos16 = (unsigned short*)(boff + NSB);   // [NE]

    hipMemsetAsync(stats, 0, (size_t)3 * 128 * 4, stream);
    hipMemsetAsync(deg, 0, (size_t)NN * 4, stream);

    deg_count_kernel<<<(NE + 255) / 256, 256, 0, stream>>>(dst, deg, pos16);
    block_sum_kernel<<<NSB, 256, 0, stream>>>(deg, bsum);
    bsum_scan_kernel<<<1, 256, 0, stream>>>(bsum, boff);
    csr_setup_kernel<<<NSB, 256, 0, stream>>>(deg, boff, row_off, dinv, rdeg);
    scatter_csr_kernel<<<(NE + 255) / 256, 256, 0, stream>>>(src, dst, pos16, row_off, csr_src);
    arow_kernel<<<(NN + 255) / 256, 256, 0, stream>>>(row_off, csr_src, dinv, arow);

    // pre-linear: hA16 = dinv * (x @ pre_w + pre_b)
    gemm_pre_kernel<<<(NN + 127) / 128, 256, 0, stream>>>(x, pre_w, hA16, pre_b, dinv);

    dim3 ggrid((NN + 31) / 32, 2);
    for (int i = 0; i < 3; ++i) {
        const float* a1 = bp1 + i;
        const float* a2 = bp2 + i;
        const float* gm = bng + i * 64;
        const float* bt = bnb + i * 64;
        const float* w1 = bw1 + (size_t)i * 64 * 128;
        const float* b1 = bb1 + i * 128;
        const float* w2 = bw2 + (size_t)i * 128 * 64;
        const float* b2 = bb2 + i * 64;
        float* st = stats + i * 128;

        bn_stats_kernel<<<256, 256, 0, stream>>>(hA16, rdeg, a1, st);
        // t16 = A_hat @ prelu(h)  (true scale)
        gather_kernel<true, 2><<<ggrid, 256, 0, stream>>>(
            row_off, csr_src, dinv, nullptr, a1, hA16, t16);
        // u16 = BN'(t16) @ w1 + b1   (MFMA)
        mfma_gemm1_kernel<<<(NN + 127) / 128, 256, 0, stream>>>(
            t16, w1, b1, u16, st, gm, bt, arow);
        // t16 = dinv * (prelu(u16) @ w2)   (MFMA)
        mfma_gemm2_kernel<<<(NN + 63) / 64, 256, 0, stream>>>(
            u16, w2, a2, dinv, t16);
        // hA16 = A_hat @ t16 + b2  (prescaled except last block)
        if (i < 2) {
            gather_kernel<false, 1><<<ggrid, 256, 0, stream>>>(
                row_off, csr_src, dinv, b2, nullptr, t16, hA16);
        } else {
            gather_kernel<false, 0><<<ggrid, 256, 0, stream>>>(
                row_off, csr_src, dinv, b2, nullptr, t16, hA16);
        }
    }

    pool_seg_kernel<<<NG, 256, 0, stream>>>(hA16, batch, pooledg);
    head_stats_kernel<<<1, 64, 0, stream>>>(pooledg, pgamma, pbeta, headsc);
    head_fc_kernel<<<NG, 256, 0, stream>>>(pooledg, headsc, fc1w, fc1b, pprelu,
                                           fc2w, fc2b, (float*)d_out);
}